// Round 1
// baseline (752.363 us; speedup 1.0000x reference)
//
#include <hip/hip_runtime.h>
#include <cfloat>

#pragma clang fp contract(off)

#define NCLS 80
#define PDIM 85
#define NA   8400
#define NB   16
#define NT   128
#define NTOP 10
#define SLOT 11   // LDS stride per thread-list (gcd(11,32)=1 -> only free 2-way aliasing)

__device__ __forceinline__ float sigm(float x){ return 1.0f/(1.0f+expf(-x)); }

__device__ __forceinline__ float bce(float x, float t){
  return fmaxf(x,0.0f) - x*t + log1pf(expf(-fabsf(x)));
}

__device__ __forceinline__ float pair_iou(float tx1,float ty1,float tx2,float ty2,
                                          float px1,float py1,float px2,float py2){
  float w = fminf(tx2,px2) - fmaxf(tx1,px1);
  float h = fminf(ty2,py2) - fmaxf(ty1,py1);
  w = fmaxf(w,0.0f); h = fmaxf(h,0.0f);
  float inter = w*h;
  float at = fmaxf(tx2-tx1,0.0f)*fmaxf(ty2-ty1,0.0f);
  float ap = fmaxf(px2-px1,0.0f)*fmaxf(py2-py1,0.0f);
  return inter/(at+ap-inter+1e-8f);
}

// Must be bit-identical between k1 (top-k) and k2 (argmin) -> contract(off) file-wide.
__device__ __forceinline__ float cost_fn(float S,float sobj,float clslogit,
                                         float iou,bool ibc,bool ib){
  float sc = sigm(clslogit);
  float p  = sqrtf(sobj*sc);
  float lp = fmaxf(logf(p), -100.0f);
  float l1 = fmaxf(log1pf(-p), -100.0f);
  float clsc = -(S + (lp - l1));
  float iouc = -logf(iou + 1e-8f);
  float c = clsc + 3.0f*iouc;
  c = c + (ibc ? 0.0f : 100000.0f);
  c = c + (ib  ? 0.0f : 1000000000.0f);
  return c;
}

// ---------------- Kernel 0: per-anchor precompute (S, in_box) ----------------
__global__ __launch_bounds__(256) void k0_precompute(
    const float* __restrict__ pred, const float* __restrict__ target,
    const float* __restrict__ grid, const float* __restrict__ stridev,
    float* __restrict__ S, int* __restrict__ inbox)
{
  __shared__ float tb[NT][4];
  const int nchunk = (NA + 255)/256;
  int i     = blockIdx.x / nchunk;
  int chunk = blockIdx.x % nchunk;
  int a     = chunk*256 + threadIdx.x;

  for (int idx = threadIdx.x; idx < NT*4; idx += 256){
    int t = idx >> 2, c = idx & 3;
    tb[t][c] = target[(i*NT + t)*6 + 2 + c];
  }
  __syncthreads();
  if (a >= NA) return;

  float xg = grid[2*a], yg = grid[2*a+1], sv = stridev[a];
  float xc = (xg + 0.5f)*sv, yc = (yg + 0.5f)*sv;
  bool ib = false;
  for (int t = 0; t < NT; ++t){
    float x1=tb[t][0], y1=tb[t][1], x2=tb[t][2], y2=tb[t][3];
    bool inb = (xc-x1>0.0f)&&(yc-y1>0.0f)&&(x2-xc>0.0f)&&(y2-yc>0.0f);
    float txc=(x1+x2)*0.5f, tyc=(y1+y2)*0.5f;
    bool inc = fmaxf(fabsf(xc-txc),fabsf(yc-tyc)) < 2.5f*sv;
    ib = ib || inb || inc;
  }
  int gid = i*NA + a;
  inbox[gid] = ib ? 1 : 0;

  const float* pr = pred + (size_t)gid*PDIM;
  float sobj = sigm(pr[4]);
  float ssum = 0.0f;
  for (int c = 0; c < NCLS; ++c){
    float sc = sigm(pr[5+c]);
    float p  = sqrtf(sobj*sc);
    ssum += fmaxf(log1pf(-p), -100.0f);
  }
  S[gid] = ssum;
}

// ------------- Kernel 1: per (image,target) top-k + match scatter ------------
__global__ __launch_bounds__(256) void k1_pertarget(
    const float* __restrict__ pred, const float* __restrict__ target,
    const float* __restrict__ grid, const float* __restrict__ stridev,
    const float* __restrict__ S, const int* __restrict__ inbox,
    float* __restrict__ rowmax, unsigned long long* __restrict__ mask)
{
  __shared__ float iouL[256*SLOT];
  __shared__ float cstL[256*SLOT];
  __shared__ int   idxL[256*SLOT];
  __shared__ int   sh_dynk;

  int i   = blockIdx.x / NT;
  int t   = blockIdx.x % NT;
  int tid = threadIdx.x;

  const float* tg = target + (i*NT + t)*6;
  int   cid = (int)tg[1];
  float tx1 = tg[2], ty1 = tg[3], tx2 = tg[4], ty2 = tg[5];
  float txc = (tx1+tx2)*0.5f, tyc = (ty1+ty2)*0.5f;

  int base = tid*SLOT;
  #pragma unroll
  for (int j=0;j<NTOP;++j){ iouL[base+j] = -1.0f; cstL[base+j] = FLT_MAX; idxL[base+j] = 0x7fffffff; }

  for (int a = tid; a < NA; a += 256){
    int gid = i*NA + a;
    bool ib = inbox[gid] != 0;
    const float* pr = pred + (size_t)gid*PDIM;
    float px1=pr[0], py1=pr[1], px2=pr[2], py2=pr[3];
    float iou = 0.0f;
    if (ib) iou = pair_iou(tx1,ty1,tx2,ty2,px1,py1,px2,py2);

    // top-10 iou, sorted descending (ties interchangeable: only sum/max used)
    if (iou > iouL[base+NTOP-1]){
      int j = NTOP-1;
      while (j > 0 && iouL[base+j-1] < iou){ iouL[base+j] = iouL[base+j-1]; --j; }
      iouL[base+j] = iou;
    }

    float sobj = sigm(pr[4]);
    float xg = grid[2*a], yg = grid[2*a+1], sv = stridev[a];
    float xc = (xg+0.5f)*sv, yc = (yg+0.5f)*sv;
    bool inb = (xc-tx1>0.0f)&&(yc-ty1>0.0f)&&(tx2-xc>0.0f)&&(ty2-yc>0.0f);
    bool inc = fmaxf(fabsf(xc-txc),fabsf(yc-tyc)) < 2.5f*sv;
    float c = cost_fn(S[gid], sobj, pr[5+cid], iou, inb&&inc, ib);

    // top-10 min cost, tie-break lower index (jax.lax.top_k semantics)
    float c9 = cstL[base+NTOP-1]; int i9 = idxL[base+NTOP-1];
    if (c < c9 || (c == c9 && a < i9)){
      int j = NTOP-1;
      while (j > 0){
        float cp = cstL[base+j-1]; int ip = idxL[base+j-1];
        if (c < cp || (c == cp && a < ip)){ cstL[base+j]=cp; idxL[base+j]=ip; --j; }
        else break;
      }
      cstL[base+j] = c; idxL[base+j] = a;
    }
  }
  __syncthreads();

  // tree merge of 256 sorted lists -> list 0
  for (int s2 = 128; s2 >= 1; s2 >>= 1){
    if (tid < s2){
      int bA = tid*SLOT, bB = (tid+s2)*SLOT;
      float ti[NTOP], tc[NTOP]; int tx[NTOP];
      int ia=0, ib2=0;
      #pragma unroll
      for (int k=0;k<NTOP;++k){
        float va=iouL[bA+ia], vb=iouL[bB+ib2];
        if (va >= vb){ ti[k]=va; ++ia; } else { ti[k]=vb; ++ib2; }
      }
      ia=0; ib2=0;
      #pragma unroll
      for (int k=0;k<NTOP;++k){
        float ca=cstL[bA+ia], cb=cstL[bB+ib2];
        int   xa=idxL[bA+ia], xb=idxL[bB+ib2];
        bool takeA = (ca < cb) || (ca == cb && xa <= xb);
        if (takeA){ tc[k]=ca; tx[k]=xa; ++ia; } else { tc[k]=cb; tx[k]=xb; ++ib2; }
      }
      #pragma unroll
      for (int k=0;k<NTOP;++k){ iouL[bA+k]=ti[k]; cstL[bA+k]=tc[k]; idxL[bA+k]=tx[k]; }
    }
    __syncthreads();
  }

  if (tid == 0){
    rowmax[i*NT + t] = iouL[0];
    float ssum = 0.0f;
    #pragma unroll
    for (int k=0;k<NTOP;++k) ssum += iouL[k];   // descending order, like jnp sum of top_k
    int dk = (int)ssum;                          // trunc toward 0 == astype(int32)
    if (dk < 1) dk = 1;
    sh_dynk = dk;
  }
  __syncthreads();
  if (tid < NTOP){
    int a = idxL[tid];
    if (tid < sh_dynk && a < NA && inbox[i*NA + a] != 0){
      atomicOr(&mask[(size_t)(i*NA + a)*2 + (t>>6)], 1ull << (t & 63));
    }
  }
}

// ---------- Kernel 2: per-anchor resolution + loss partial sums --------------
__global__ __launch_bounds__(256) void k2_peranchor(
    const float* __restrict__ pred, const float* __restrict__ target,
    const float* __restrict__ grid, const float* __restrict__ stridev,
    const float* __restrict__ S, const int* __restrict__ inbox,
    const float* __restrict__ rowmax, const unsigned long long* __restrict__ mask,
    float* __restrict__ acc)
{
  __shared__ float tb[NT][4];
  __shared__ int   tcid[NT];
  __shared__ float trm[NT];
  __shared__ float red[4][4];

  const int nchunk = (NA + 255)/256;
  int i     = blockIdx.x / nchunk;
  int chunk = blockIdx.x % nchunk;
  int a     = chunk*256 + threadIdx.x;

  for (int idx = threadIdx.x; idx < NT; idx += 256){
    const float* tg = target + (i*NT + idx)*6;
    tcid[idx] = (int)tg[1];
    tb[idx][0]=tg[2]; tb[idx][1]=tg[3]; tb[idx][2]=tg[4]; tb[idx][3]=tg[5];
    trm[idx] = rowmax[i*NT + idx];
  }
  __syncthreads();

  float m=0.0f, vbox=0.0f, vobj=0.0f, vcls=0.0f;
  if (a < NA){
    int gid = i*NA + a;
    bool ib = inbox[gid] != 0;
    const float* pr = pred + (size_t)gid*PDIM;
    float px1=pr[0], py1=pr[1], px2=pr[2], py2=pr[3];
    float objlg = pr[4];

    float obj_t = 0.0f;
    if (ib){
      float best = 0.0f;
      for (int t=0;t<NT;++t){
        float iou = pair_iou(tb[t][0],tb[t][1],tb[t][2],tb[t][3],px1,py1,px2,py2);
        best = fmaxf(best, iou/(trm[t]+1e-8f));
      }
      obj_t = fminf(fmaxf(best,0.0f),1.0f);
    }

    unsigned long long m0 = mask[(size_t)gid*2], m1 = mask[(size_t)gid*2+1];
    int cnt = __popcll(m0) + __popcll(m1);
    int tp = 0; bool mpv = false;
    if (cnt > 1){
      // conflict: column = one-hot at argmin cost (first occurrence)
      float sobj = sigm(objlg);
      float Sg = S[gid];
      float xg = grid[2*a], yg = grid[2*a+1], sv = stridev[a];
      float xc = (xg+0.5f)*sv, yc = (yg+0.5f)*sv;
      float bestc = FLT_MAX;
      for (int t=0;t<NT;++t){
        float x1=tb[t][0], y1=tb[t][1], x2=tb[t][2], y2=tb[t][3];
        float iou = ib ? pair_iou(x1,y1,x2,y2,px1,py1,px2,py2) : 0.0f;
        bool inb = (xc-x1>0.0f)&&(yc-y1>0.0f)&&(x2-xc>0.0f)&&(y2-yc>0.0f);
        float txc=(x1+x2)*0.5f, tyc=(y1+y2)*0.5f;
        bool inc = fmaxf(fabsf(xc-txc),fabsf(yc-tyc)) < 2.5f*sv;
        float c = cost_fn(Sg, sobj, pr[5+tcid[t]], iou, inb&&inc, ib);
        if (c < bestc){ bestc = c; tp = t; }
      }
      mpv = true;
    } else if (cnt == 1){
      tp = m0 ? (__ffsll((unsigned long long)m0)-1) : (64 + __ffsll((unsigned long long)m1)-1);
      mpv = true;
    }

    vobj = bce(objlg, obj_t);
    if (mpv){
      m = 1.0f;
      float x1=tb[tp][0], y1=tb[tp][1], x2=tb[tp][2], y2=tb[tp][3];
      // CIoU
      float w = fmaxf(fminf(px2,x2)-fmaxf(px1,x1),0.0f);
      float h = fmaxf(fminf(py2,y2)-fmaxf(py1,y1),0.0f);
      float inter = w*h;
      float wp=px2-px1, hp=py2-py1, wt=x2-x1, ht=y2-y1;
      float iou = inter/(wp*hp + wt*ht - inter + 1e-8f);
      float cw = fmaxf(px2,x2)-fminf(px1,x1);
      float ch = fmaxf(py2,y2)-fminf(py1,y1);
      float c2 = cw*cw + ch*ch + 1e-8f;
      float dx = (px1+px2)-(x1+x2), dy = (py1+py2)-(y1+y2);
      float rho2 = (dx*dx + dy*dy)/4.0f;
      float da = atanf(wt/(ht+1e-8f)) - atanf(wp/(hp+1e-8f));
      float v  = 0.4052847345693511f * da * da;   // 4/pi^2
      float alpha = v/(1.0f - iou + v + 1e-8f);
      float ciou = iou - rho2/c2 - alpha*v;
      vbox = 1.0f - ciou;

      int cc = tcid[tp];
      float sum = 0.0f;
      for (int c=0;c<NCLS;++c){
        sum += bce(pr[5+c], (c==cc)?1.0f:0.0f);
      }
      vcls = sum * (1.0f/(float)NCLS);
    }
  }

  // block reduction: wave shuffle then LDS across 4 waves
  #pragma unroll
  for (int off=32; off>0; off>>=1){
    m    += __shfl_down(m, off);
    vbox += __shfl_down(vbox, off);
    vobj += __shfl_down(vobj, off);
    vcls += __shfl_down(vcls, off);
  }
  int wave = threadIdx.x >> 6, lane = threadIdx.x & 63;
  if (lane == 0){ red[wave][0]=m; red[wave][1]=vbox; red[wave][2]=vobj; red[wave][3]=vcls; }
  __syncthreads();
  if (threadIdx.x == 0){
    float a0=0,a1=0,a2=0,a3=0;
    for (int wv=0; wv<4; ++wv){ a0+=red[wv][0]; a1+=red[wv][1]; a2+=red[wv][2]; a3+=red[wv][3]; }
    atomicAdd(&acc[0], a0); atomicAdd(&acc[1], a1);
    atomicAdd(&acc[2], a2); atomicAdd(&acc[3], a3);
  }
}

// ---------------- Kernel 3: finalize ----------------
__global__ void k3_final(const float* __restrict__ acc, float* __restrict__ out){
  float n    = fmaxf(acc[0], 1.0f);
  float lbox = 0.05f * acc[1] / n;
  float lobj = acc[2] / (float)(NB*NA);
  float lcls = 0.5f  * acc[3] / n;
  out[0] = lbox + lobj + lcls;
  out[1] = lbox; out[2] = lobj; out[3] = lcls;
}

extern "C" void kernel_launch(void* const* d_in, const int* in_sizes, int n_in,
                              void* d_out, int out_size, void* d_ws, size_t ws_size,
                              hipStream_t stream) {
  const float* pred    = (const float*)d_in[0];
  const float* target  = (const float*)d_in[1];
  const float* grid    = (const float*)d_in[2];
  const float* stridev = (const float*)d_in[3];
  float* out = (float*)d_out;

  char* ws = (char*)d_ws;
  const size_t BA = (size_t)NB*NA;                       // 134400
  float* S      = (float*)ws;                            // BA floats
  int*   inbox  = (int*)(ws + BA*4);                     // BA ints
  float* rowmax = (float*)(ws + BA*8);                   // NB*NT floats
  unsigned long long* mask =
      (unsigned long long*)(ws + BA*8 + (size_t)NB*NT*4);// BA*2 u64 (8-aligned: 1083392)
  float* acc    = (float*)(ws + BA*8 + (size_t)NB*NT*4 + BA*16); // 4 floats
  const size_t total = BA*8 + (size_t)NB*NT*4 + BA*16 + 16;

  hipMemsetAsync(d_ws, 0, total, stream);                // zeros mask + acc (ws is poisoned)

  const int nchunk = (NA + 255)/256;                     // 33
  k0_precompute<<<NB*nchunk, 256, 0, stream>>>(pred, target, grid, stridev, S, inbox);
  k1_pertarget <<<NB*NT,    256, 0, stream>>>(pred, target, grid, stridev, S, inbox, rowmax, mask);
  k2_peranchor <<<NB*nchunk, 256, 0, stream>>>(pred, target, grid, stridev, S, inbox, rowmax, mask, acc);
  k3_final     <<<1, 1, 0, stream>>>(acc, out);
}

// Round 2
// 489.213 us; speedup vs baseline: 1.5379x; 1.5379x over previous
//
#include <hip/hip_runtime.h>
#include <cfloat>

#pragma clang fp contract(off)

#define NCLS 80
#define PDIM 85
#define NA   8400
#define NB   16
#define NT   128
#define NTOP 10
#define SLOT 11      // LDS stride for merge lists (odd -> free 2-way bank aliasing)
#define APB  64      // anchors per k0 block
#define BPI  132     // ceil(NA/APB)

__device__ __forceinline__ float sigm(float x){ return 1.0f/(1.0f+expf(-x)); }

__device__ __forceinline__ float bce(float x, float t){
  return fmaxf(x,0.0f) - x*t + log1pf(expf(-fabsf(x)));
}

__device__ __forceinline__ float pair_iou(float tx1,float ty1,float tx2,float ty2,
                                          float px1,float py1,float px2,float py2){
  float w = fminf(tx2,px2) - fmaxf(tx1,px1);
  float h = fminf(ty2,py2) - fmaxf(ty1,py1);
  w = fmaxf(w,0.0f); h = fmaxf(h,0.0f);
  float inter = w*h;
  float at = fmaxf(tx2-tx1,0.0f)*fmaxf(ty2-ty1,0.0f);
  float ap = fmaxf(px2-px1,0.0f)*fmaxf(py2-py1,0.0f);
  return inter/(at+ap-inter+1e-8f);
}

// dval = fmax(log(p),-100) - fmax(log1p(-p),-100), p = sqrt(sobj*sigm(lg)).
// Must be bit-identical wherever computed (k0 table vs k1/k2 fallback).
__device__ __forceinline__ float dval_fn(float sobj, float lg){
  float sc = sigm(lg);
  float p  = sqrtf(sobj*sc);
  float lp = fmaxf(logf(p), -100.0f);
  float l1 = fmaxf(log1pf(-p), -100.0f);
  return lp - l1;
}

// cost given precomputed pieces; statement order fixed (contract off, no fast-math)
__device__ __forceinline__ float cost_from(float S, float dval, float iou, bool ibc, bool ib){
  float iouc = -logf(iou + 1e-8f);
  float clsc = -(S + dval);
  float c = clsc + 3.0f*iouc;
  c = c + (ibc ? 0.0f : 100000.0f);
  c = c + (ib  ? 0.0f : 1000000000.0f);
  return c;
}

// ---------------- Kernel 0: transpose + per-anchor precompute ----------------
__global__ __launch_bounds__(256) void k0_precompute(
    const float* __restrict__ pred, const float* __restrict__ target,
    const float* __restrict__ grid, const float* __restrict__ stridev,
    float4* __restrict__ pbox4, float4* __restrict__ meta4,
    float* __restrict__ obja, float* __restrict__ sobja,
    int* __restrict__ inbox, float* __restrict__ D, int use_d)
{
  __shared__ float tile[APB*PDIM];   // [a][c], stride 85 (odd -> conflict-free)
  __shared__ float l1b[APB*81];      // [a][c], stride 81
  __shared__ float tb[NT][4];

  int i  = blockIdx.x / BPI;
  int b  = blockIdx.x % BPI;
  int c0 = b*APB;
  int n  = NA - c0; if (n > APB) n = APB;
  int tid = threadIdx.x;

  const float* src = pred + ((size_t)i*NA + c0)*PDIM;
  int tot = n*PDIM;
  for (int idx = tid; idx < tot; idx += 256) tile[idx] = src[idx];
  for (int idx = tid; idx < NT*4; idx += 256){
    int t = idx >> 2, c = idx & 3;
    tb[t][c] = target[(i*NT + t)*6 + 2 + c];
  }
  __syncthreads();

  // phase 2: classes (4 wave-groups x 20 classes each), anchors across lanes
  int al = tid & 63, cg = tid >> 6;
  if (al < n){
    int gid = i*NA + c0 + al;
    float sobj = sigm(tile[al*PDIM+4]);
    #pragma unroll 4
    for (int k = 0; k < 20; ++k){
      int c = cg*20 + k;
      float dv;
      {
        float sc = sigm(tile[al*PDIM+5+c]);
        float p  = sqrtf(sobj*sc);
        float lp = fmaxf(logf(p), -100.0f);
        float l1 = fmaxf(log1pf(-p), -100.0f);
        l1b[al*81+c] = l1;
        dv = lp - l1;
      }
      if (use_d) D[(size_t)c*((size_t)NB*NA) + gid] = dv;
    }
  }
  __syncthreads();

  // phase 3: per-anchor scalars (64 lanes)
  if (tid < n){
    int a = tid;
    int gid = i*NA + c0 + a;
    float s = 0.0f;
    for (int c = 0; c < 80; ++c) s += l1b[a*81+c];   // same order as reference sum

    float x1 = tile[a*PDIM+0], y1 = tile[a*PDIM+1];
    float x2 = tile[a*PDIM+2], y2 = tile[a*PDIM+3];
    float ol = tile[a*PDIM+4];
    pbox4[gid] = make_float4(x1,y1,x2,y2);
    obja[gid]  = ol;
    sobja[gid] = sigm(ol);

    int ga = c0 + a;
    float xg = grid[2*ga], yg = grid[2*ga+1], sv = stridev[ga];
    float xc = (xg + 0.5f)*sv, yc = (yg + 0.5f)*sv;
    float rc = 2.5f*sv;
    meta4[gid] = make_float4(xc, yc, rc, s);

    bool ib = false;
    for (int t = 0; t < NT; ++t){
      float tx1=tb[t][0], ty1=tb[t][1], tx2=tb[t][2], ty2=tb[t][3];
      bool inb = (xc-tx1>0.0f)&&(yc-ty1>0.0f)&&(tx2-xc>0.0f)&&(ty2-yc>0.0f);
      float txc=(tx1+tx2)*0.5f, tyc=(ty1+ty2)*0.5f;
      bool inc = fmaxf(fabsf(xc-txc),fabsf(yc-tyc)) < rc;
      ib = ib || inb || inc;
    }
    inbox[gid] = ib ? 1 : 0;
  }
}

// ------------- Kernel 1: per (image,target) top-k + match scatter ------------
__global__ __launch_bounds__(256) void k1_pertarget(
    const float4* __restrict__ pbox4, const float4* __restrict__ meta4,
    const int* __restrict__ inbox, const float* __restrict__ D, int use_d,
    const float* __restrict__ sobja, const float* __restrict__ pred,
    const float* __restrict__ target,
    float* __restrict__ rowmax, unsigned long long* __restrict__ mask)
{
  __shared__ float fbuf[256*SLOT];
  __shared__ int   ibuf[256*SLOT];
  __shared__ int   sh_dynk;

  int i   = blockIdx.x / NT;
  int t   = blockIdx.x % NT;
  int tid = threadIdx.x;
  const size_t BA = (size_t)NB*NA;

  const float* tg = target + (i*NT + t)*6;
  int   cid = (int)tg[1];
  float tx1 = tg[2], ty1 = tg[3], tx2 = tg[4], ty2 = tg[5];
  float txc = (tx1+tx2)*0.5f, tyc = (ty1+ty2)*0.5f;
  const float* Dc = use_d ? (D + (size_t)cid*BA) : nullptr;

  // register top-k lists
  float riou[NTOP]; float rcst[NTOP]; int ridx[NTOP];
  #pragma unroll
  for (int j=0;j<NTOP;++j){ riou[j]=0.0f; rcst[j]=FLT_MAX; ridx[j]=0x7fffffff; }

  int iNA = i*NA;
  for (int a = tid; a < NA; a += 256){
    int gid = iNA + a;
    bool ib = inbox[gid] != 0;
    float4 pb = pbox4[gid];
    float4 mt = meta4[gid];
    float iou = 0.0f;
    if (ib) iou = pair_iou(tx1,ty1,tx2,ty2, pb.x,pb.y,pb.z,pb.w);

    // branchless sorted insert (desc); zeros never enter (strict >)
    if (iou > riou[NTOP-1]){
      #pragma unroll
      for (int j = NTOP-1; j >= 1; --j){
        bool gj  = iou > riou[j];
        bool gj1 = iou > riou[j-1];
        riou[j] = gj ? (gj1 ? riou[j-1] : iou) : riou[j];
      }
      riou[0] = (iou > riou[0]) ? iou : riou[0];
    }

    float dv = use_d ? Dc[gid] : dval_fn(sobja[gid], pred[(size_t)gid*PDIM + 5 + cid]);
    bool inb = (mt.x-tx1>0.0f)&&(mt.y-ty1>0.0f)&&(tx2-mt.x>0.0f)&&(ty2-mt.y>0.0f);
    bool inc = fmaxf(fabsf(mt.x-txc),fabsf(mt.y-tyc)) < mt.z;
    float c = cost_from(mt.w, dv, iou, inb&&inc, ib);

    // branchless sorted insert (asc, tie-break lower index)
    bool ent = (c < rcst[NTOP-1]) || (c == rcst[NTOP-1] && a < ridx[NTOP-1]);
    if (ent){
      #pragma unroll
      for (int j = NTOP-1; j >= 1; --j){
        bool bj  = (c < rcst[j])   || (c == rcst[j]   && a < ridx[j]);
        bool bj1 = (c < rcst[j-1]) || (c == rcst[j-1] && a < ridx[j-1]);
        float nc = bj ? (bj1 ? rcst[j-1] : c) : rcst[j];
        int   ni = bj ? (bj1 ? ridx[j-1] : a) : ridx[j];
        rcst[j] = nc; ridx[j] = ni;
      }
      bool b0 = (c < rcst[0]) || (c == rcst[0] && a < ridx[0]);
      rcst[0] = b0 ? c : rcst[0];
      ridx[0] = b0 ? a : ridx[0];
    }
  }

  // ---- phase A: merge iou lists ----
  {
    int base = tid*SLOT;
    #pragma unroll
    for (int j=0;j<NTOP;++j) fbuf[base+j] = riou[j];
  }
  __syncthreads();
  for (int s2 = 128; s2 >= 1; s2 >>= 1){
    if (tid < s2){
      int bA = tid*SLOT, bB = (tid+s2)*SLOT;
      float ti[NTOP];
      int ia=0, ib2=0;
      #pragma unroll
      for (int k=0;k<NTOP;++k){
        float va=fbuf[bA+ia], vb=fbuf[bB+ib2];
        if (va >= vb){ ti[k]=va; ++ia; } else { ti[k]=vb; ++ib2; }
      }
      #pragma unroll
      for (int k=0;k<NTOP;++k) fbuf[bA+k]=ti[k];
    }
    __syncthreads();
  }
  if (tid == 0){
    rowmax[i*NT + t] = fbuf[0];
    float ssum = 0.0f;
    #pragma unroll
    for (int k=0;k<NTOP;++k) ssum += fbuf[k];
    int dk = (int)ssum;
    if (dk < 1) dk = 1;
    sh_dynk = dk;
  }
  __syncthreads();

  // ---- phase B: merge cost lists ----
  {
    int base = tid*SLOT;
    #pragma unroll
    for (int j=0;j<NTOP;++j){ fbuf[base+j] = rcst[j]; ibuf[base+j] = ridx[j]; }
  }
  __syncthreads();
  for (int s2 = 128; s2 >= 1; s2 >>= 1){
    if (tid < s2){
      int bA = tid*SLOT, bB = (tid+s2)*SLOT;
      float tc[NTOP]; int tx[NTOP];
      int ia=0, ib2=0;
      #pragma unroll
      for (int k=0;k<NTOP;++k){
        float ca=fbuf[bA+ia], cb=fbuf[bB+ib2];
        int   xa=ibuf[bA+ia], xb=ibuf[bB+ib2];
        bool takeA = (ca < cb) || (ca == cb && xa <= xb);
        if (takeA){ tc[k]=ca; tx[k]=xa; ++ia; } else { tc[k]=cb; tx[k]=xb; ++ib2; }
      }
      #pragma unroll
      for (int k=0;k<NTOP;++k){ fbuf[bA+k]=tc[k]; ibuf[bA+k]=tx[k]; }
    }
    __syncthreads();
  }

  if (tid < NTOP){
    int a = ibuf[tid];
    if (tid < sh_dynk && a < NA && inbox[iNA + a] != 0){
      atomicOr(&mask[(size_t)(iNA + a)*2 + (t>>6)], 1ull << (t & 63));
    }
  }
}

// ---------- Kernel 2: per-anchor resolution + loss partial sums --------------
__global__ __launch_bounds__(256) void k2_peranchor(
    const float* __restrict__ pred,
    const float4* __restrict__ pbox4, const float4* __restrict__ meta4,
    const float* __restrict__ obja, const float* __restrict__ sobja,
    const int* __restrict__ inbox, const float* __restrict__ D, int use_d,
    const float* __restrict__ target,
    const float* __restrict__ rowmax, const unsigned long long* __restrict__ mask,
    float* __restrict__ acc)
{
  __shared__ float tb[NT][4];
  __shared__ int   tcid[NT];
  __shared__ float trm[NT];
  __shared__ float red[4][4];

  const int nchunk = (NA + 255)/256;
  int i     = blockIdx.x / nchunk;
  int chunk = blockIdx.x % nchunk;
  int a     = chunk*256 + threadIdx.x;
  const size_t BA = (size_t)NB*NA;

  for (int idx = threadIdx.x; idx < NT; idx += 256){
    const float* tg = target + (i*NT + idx)*6;
    tcid[idx] = (int)tg[1];
    tb[idx][0]=tg[2]; tb[idx][1]=tg[3]; tb[idx][2]=tg[4]; tb[idx][3]=tg[5];
    trm[idx] = rowmax[i*NT + idx];
  }
  __syncthreads();

  float m=0.0f, vbox=0.0f, vobj=0.0f, vcls=0.0f;
  if (a < NA){
    int gid = i*NA + a;
    bool ib = inbox[gid] != 0;
    float4 pb = pbox4[gid];
    float4 mt = meta4[gid];
    float px1=pb.x, py1=pb.y, px2=pb.z, py2=pb.w;
    float objlg = obja[gid];

    float obj_t = 0.0f;
    if (ib){
      float best = 0.0f;
      for (int t=0;t<NT;++t){
        float iou = pair_iou(tb[t][0],tb[t][1],tb[t][2],tb[t][3],px1,py1,px2,py2);
        best = fmaxf(best, iou/(trm[t]+1e-8f));
      }
      obj_t = fminf(fmaxf(best,0.0f),1.0f);
    }

    unsigned long long m0 = mask[(size_t)gid*2], m1 = mask[(size_t)gid*2+1];
    int cnt = __popcll(m0) + __popcll(m1);
    int tp = 0; bool mpv = false;
    if (cnt > 1){
      float sobj = sobja[gid];
      float bestc = FLT_MAX;
      for (int t=0;t<NT;++t){
        float x1=tb[t][0], y1=tb[t][1], x2=tb[t][2], y2=tb[t][3];
        float iou = ib ? pair_iou(x1,y1,x2,y2,px1,py1,px2,py2) : 0.0f;
        bool inb = (mt.x-x1>0.0f)&&(mt.y-y1>0.0f)&&(x2-mt.x>0.0f)&&(y2-mt.y>0.0f);
        float txc=(x1+x2)*0.5f, tyc=(y1+y2)*0.5f;
        bool inc = fmaxf(fabsf(mt.x-txc),fabsf(mt.y-tyc)) < mt.z;
        float dv = use_d ? D[(size_t)tcid[t]*BA + gid]
                         : dval_fn(sobj, pred[(size_t)gid*PDIM + 5 + tcid[t]]);
        float c = cost_from(mt.w, dv, iou, inb&&inc, ib);
        if (c < bestc){ bestc = c; tp = t; }
      }
      mpv = true;
    } else if (cnt == 1){
      tp = m0 ? (__ffsll((unsigned long long)m0)-1) : (64 + __ffsll((unsigned long long)m1)-1);
      mpv = true;
    }

    vobj = bce(objlg, obj_t);
    if (mpv){
      m = 1.0f;
      float x1=tb[tp][0], y1=tb[tp][1], x2=tb[tp][2], y2=tb[tp][3];
      float w = fmaxf(fminf(px2,x2)-fmaxf(px1,x1),0.0f);
      float h = fmaxf(fminf(py2,y2)-fmaxf(py1,y1),0.0f);
      float inter = w*h;
      float wp=px2-px1, hp=py2-py1, wt=x2-x1, ht=y2-y1;
      float iou = inter/(wp*hp + wt*ht - inter + 1e-8f);
      float cw = fmaxf(px2,x2)-fminf(px1,x1);
      float ch = fmaxf(py2,y2)-fminf(py1,y1);
      float c2 = cw*cw + ch*ch + 1e-8f;
      float dx = (px1+px2)-(x1+x2), dy = (py1+py2)-(y1+y2);
      float rho2 = (dx*dx + dy*dy)/4.0f;
      float da = atanf(wt/(ht+1e-8f)) - atanf(wp/(hp+1e-8f));
      float v  = 0.4052847345693511f * da * da;   // 4/pi^2
      float alpha = v/(1.0f - iou + v + 1e-8f);
      float ciou = iou - rho2/c2 - alpha*v;
      vbox = 1.0f - ciou;

      int cc = tcid[tp];
      const float* pr = pred + (size_t)gid*PDIM;
      float sum = 0.0f;
      for (int c=0;c<NCLS;++c){
        sum += bce(pr[5+c], (c==cc)?1.0f:0.0f);
      }
      vcls = sum * (1.0f/(float)NCLS);
    }
  }

  #pragma unroll
  for (int off=32; off>0; off>>=1){
    m    += __shfl_down(m, off);
    vbox += __shfl_down(vbox, off);
    vobj += __shfl_down(vobj, off);
    vcls += __shfl_down(vcls, off);
  }
  int wave = threadIdx.x >> 6, lane = threadIdx.x & 63;
  if (lane == 0){ red[wave][0]=m; red[wave][1]=vbox; red[wave][2]=vobj; red[wave][3]=vcls; }
  __syncthreads();
  if (threadIdx.x == 0){
    float a0=0,a1=0,a2=0,a3=0;
    for (int wv=0; wv<4; ++wv){ a0+=red[wv][0]; a1+=red[wv][1]; a2+=red[wv][2]; a3+=red[wv][3]; }
    atomicAdd(&acc[0], a0); atomicAdd(&acc[1], a1);
    atomicAdd(&acc[2], a2); atomicAdd(&acc[3], a3);
  }
}

// ---------------- Kernel 3: finalize ----------------
__global__ void k3_final(const float* __restrict__ acc, float* __restrict__ out){
  float n    = fmaxf(acc[0], 1.0f);
  float lbox = 0.05f * acc[1] / n;
  float lobj = acc[2] / (float)(NB*NA);
  float lcls = 0.5f  * acc[3] / n;
  out[0] = lbox + lobj + lcls;
  out[1] = lbox; out[2] = lobj; out[3] = lcls;
}

extern "C" void kernel_launch(void* const* d_in, const int* in_sizes, int n_in,
                              void* d_out, int out_size, void* d_ws, size_t ws_size,
                              hipStream_t stream) {
  const float* pred    = (const float*)d_in[0];
  const float* target  = (const float*)d_in[1];
  const float* grid    = (const float*)d_in[2];
  const float* stridev = (const float*)d_in[3];
  float* out = (float*)d_out;

  char* ws = (char*)d_ws;
  const size_t BA = (size_t)NB*NA;   // 134400

  size_t off = 0;
  unsigned long long* mask = (unsigned long long*)(ws + off); off += BA*16;   // 2 u64/anchor
  float* acc    = (float*)(ws + off); off += 16;
  const size_t zero_bytes = off;      // mask + acc must be zeroed
  float4* pbox4 = (float4*)(ws + off); off += BA*16;
  float4* meta4 = (float4*)(ws + off); off += BA*16;
  float* obja   = (float*)(ws + off); off += BA*4;
  float* sobja  = (float*)(ws + off); off += BA*4;
  int*   inbox  = (int*)  (ws + off); off += BA*4;
  float* rowmax = (float*)(ws + off); off += (size_t)NB*NT*4;
  float* D      = (float*)(ws + off);
  const size_t need_d = off + (size_t)NCLS*BA*4;
  int use_d = (ws_size >= need_d) ? 1 : 0;

  hipMemsetAsync(d_ws, 0, zero_bytes, stream);

  const int nchunk = (NA + 255)/256;   // 33
  k0_precompute<<<NB*BPI, 256, 0, stream>>>(pred, target, grid, stridev,
                                            pbox4, meta4, obja, sobja, inbox, D, use_d);
  k1_pertarget <<<NB*NT,  256, 0, stream>>>(pbox4, meta4, inbox, D, use_d,
                                            sobja, pred, target, rowmax, mask);
  k2_peranchor <<<NB*nchunk, 256, 0, stream>>>(pred, pbox4, meta4, obja, sobja,
                                               inbox, D, use_d, target, rowmax, mask, acc);
  k3_final     <<<1, 1, 0, stream>>>(acc, out);
}

// Round 3
// 365.021 us; speedup vs baseline: 2.0611x; 1.3402x over previous
//
#include <hip/hip_runtime.h>
#include <cfloat>

#pragma clang fp contract(off)

#define NCLS 80
#define PDIM 85
#define NA   8400
#define NB   16
#define NT   128
#define NTOP 10
#define SLOT 11      // LDS stride for merge lists (odd -> free 2-way bank aliasing)
#define APB  64      // anchors per k0/k2 block
#define BPI  132     // ceil(NA/64)

__device__ __forceinline__ float sigm(float x){ return 1.0f/(1.0f+expf(-x)); }

__device__ __forceinline__ float bce(float x, float t){
  return fmaxf(x,0.0f) - x*t + log1pf(expf(-fabsf(x)));
}

__device__ __forceinline__ float pair_iou(float tx1,float ty1,float tx2,float ty2,
                                          float px1,float py1,float px2,float py2){
  float w = fminf(tx2,px2) - fmaxf(tx1,px1);
  float h = fminf(ty2,py2) - fmaxf(ty1,py1);
  w = fmaxf(w,0.0f); h = fmaxf(h,0.0f);
  float inter = w*h;
  float at = fmaxf(tx2-tx1,0.0f)*fmaxf(ty2-ty1,0.0f);
  float ap = fmaxf(px2-px1,0.0f)*fmaxf(py2-py1,0.0f);
  return inter/(at+ap-inter+1e-8f);
}

// dval = fmax(log(p),-100) - fmax(log1p(-p),-100), p = sqrt(sobj*sigm(lg)).
__device__ __forceinline__ float dval_fn(float sobj, float lg){
  float sc = sigm(lg);
  float p  = sqrtf(sobj*sc);
  float lp = fmaxf(logf(p), -100.0f);
  float l1 = fmaxf(log1pf(-p), -100.0f);
  return lp - l1;
}

// Selection-critical: identical in k1 top-k and k2 argmin (contract off file-wide).
__device__ __forceinline__ float cost_from(float S, float dval, float iou, bool ibc, bool ib){
  float iouc = -logf(iou + 1e-8f);
  float clsc = -(S + dval);
  float c = clsc + 3.0f*iouc;
  c = c + (ibc ? 0.0f : 100000.0f);
  c = c + (ib  ? 0.0f : 1000000000.0f);
  return c;
}

// ---------------- Kernel 0: transpose + per-anchor precompute ----------------
__global__ __launch_bounds__(256) void k0_precompute(
    const float* __restrict__ pred, const float* __restrict__ target,
    const float* __restrict__ grid, const float* __restrict__ stridev,
    float4* __restrict__ pbox4, float4* __restrict__ meta4,
    float* __restrict__ obja, float* __restrict__ sobja,
    float* __restrict__ S0a, float* __restrict__ D, int use_d)
{
  __shared__ float tile[APB*PDIM];   // [a][c], stride 85; cols 5..84 overwritten w/ bce(x,0)
  __shared__ float l1b[APB*81];      // [a][c], stride 81
  __shared__ float tb[NT][4];

  int i  = blockIdx.x / BPI;
  int b  = blockIdx.x % BPI;
  int c0 = b*APB;
  int n  = NA - c0; if (n > APB) n = APB;
  int tid = threadIdx.x;

  const float* src = pred + ((size_t)i*NA + c0)*PDIM;
  int tot = n*PDIM;
  for (int idx = tid; idx < tot; idx += 256) tile[idx] = src[idx];
  for (int idx = tid; idx < NT*4; idx += 256){
    int t = idx >> 2, c = idx & 3;
    tb[t][c] = target[(i*NT + t)*6 + 2 + c];
  }
  __syncthreads();

  // phase 2: classes (4 wave-groups x 20 classes), anchors across lanes
  int al = tid & 63, cg = tid >> 6;
  if (al < n){
    int gid = i*NA + c0 + al;
    float sobj = sigm(tile[al*PDIM+4]);
    #pragma unroll 4
    for (int k = 0; k < 20; ++k){
      int c = cg*20 + k;
      float x  = tile[al*PDIM+5+c];
      float sc = sigm(x);
      float p  = sqrtf(sobj*sc);
      float lp = fmaxf(logf(p), -100.0f);
      float l1 = fmaxf(log1pf(-p), -100.0f);
      l1b[al*81+c] = l1;
      if (use_d) D[(size_t)c*((size_t)NB*NA) + gid] = lp - l1;
      // bce(x, 0) — identical formula/order to reference with t=0
      tile[al*PDIM+5+c] = fmaxf(x,0.0f) + log1pf(expf(-fabsf(x)));
    }
  }
  __syncthreads();

  // phase 3: per-anchor scalars (first 64 lanes)
  if (tid < n){
    int a = tid;
    int gid = i*NA + c0 + a;
    float s = 0.0f, s0 = 0.0f;
    for (int c = 0; c < 80; ++c){            // in class order, like reference sums
      s  += l1b[a*81+c];
      s0 += tile[a*PDIM+5+c];
    }

    float x1 = tile[a*PDIM+0], y1 = tile[a*PDIM+1];
    float x2 = tile[a*PDIM+2], y2 = tile[a*PDIM+3];
    float ol = tile[a*PDIM+4];
    pbox4[gid] = make_float4(x1,y1,x2,y2);
    obja[gid]  = ol;
    sobja[gid] = sigm(ol);
    S0a[gid]   = s0;

    int ga = c0 + a;
    float xg = grid[2*ga], yg = grid[2*ga+1], sv = stridev[ga];
    float xc = (xg + 0.5f)*sv, yc = (yg + 0.5f)*sv;
    float rc = 2.5f*sv;

    bool ib = false;
    for (int t = 0; t < NT; ++t){
      float tx1=tb[t][0], ty1=tb[t][1], tx2=tb[t][2], ty2=tb[t][3];
      bool inb = (xc-tx1>0.0f)&&(yc-ty1>0.0f)&&(tx2-xc>0.0f)&&(ty2-yc>0.0f);
      float txc=(tx1+tx2)*0.5f, tyc=(ty1+ty2)*0.5f;
      bool inc = fmaxf(fabsf(xc-txc),fabsf(yc-tyc)) < rc;
      ib = ib || inb || inc;
    }
    meta4[gid] = make_float4(xc, yc, ib ? rc : -rc, s);  // sign(z) = in_box
  }
}

// ------------- Kernel 1: per (image,target) top-k + match scatter ------------
__global__ __launch_bounds__(256) void k1_pertarget(
    const float4* __restrict__ pbox4, const float4* __restrict__ meta4,
    const float* __restrict__ D, int use_d,
    const float* __restrict__ sobja, const float* __restrict__ pred,
    const float* __restrict__ target,
    float* __restrict__ rowmax, unsigned long long* __restrict__ mask)
{
  __shared__ float fbuf[256*SLOT];
  __shared__ int   ibuf[256*SLOT];
  __shared__ int   sh_dynk;

  int i   = blockIdx.x / NT;
  int t   = blockIdx.x % NT;
  int tid = threadIdx.x;
  const size_t BA = (size_t)NB*NA;

  const float* tg = target + (i*NT + t)*6;
  int   cid = (int)tg[1];
  float tx1 = tg[2], ty1 = tg[3], tx2 = tg[4], ty2 = tg[5];
  float txc = (tx1+tx2)*0.5f, tyc = (ty1+ty2)*0.5f;
  const float* Dc = use_d ? (D + (size_t)cid*BA) : nullptr;

  float riou[NTOP]; float rcst[NTOP]; int ridx[NTOP];
  #pragma unroll
  for (int j=0;j<NTOP;++j){ riou[j]=0.0f; rcst[j]=FLT_MAX; ridx[j]=0x7fffffff; }

  int iNA = i*NA;
  int a = tid;
  // prime prefetch registers (tid < 256 <= NA always valid)
  float4 pb = pbox4[iNA+a];
  float4 mt = meta4[iNA+a];
  float  dv = use_d ? Dc[iNA+a] : 0.0f;

  while (a < NA){
    int a2 = a + 256;
    int ld = (a2 < NA) ? a2 : a;
    float4 pb_n = pbox4[iNA+ld];
    float4 mt_n = meta4[iNA+ld];
    float  dv_n = use_d ? Dc[iNA+ld] : 0.0f;

    bool ib = mt.z > 0.0f;
    float rc = fabsf(mt.z);
    float iou = 0.0f;
    if (ib) iou = pair_iou(tx1,ty1,tx2,ty2, pb.x,pb.y,pb.z,pb.w);

    if (iou > riou[NTOP-1]){
      #pragma unroll
      for (int j = NTOP-1; j >= 1; --j){
        bool gj  = iou > riou[j];
        bool gj1 = iou > riou[j-1];
        riou[j] = gj ? (gj1 ? riou[j-1] : iou) : riou[j];
      }
      riou[0] = (iou > riou[0]) ? iou : riou[0];
    }

    float dvv = use_d ? dv : dval_fn(sobja[iNA+a], pred[(size_t)(iNA+a)*PDIM + 5 + cid]);
    bool inb = (mt.x-tx1>0.0f)&&(mt.y-ty1>0.0f)&&(tx2-mt.x>0.0f)&&(ty2-mt.y>0.0f);
    bool inc = fmaxf(fabsf(mt.x-txc),fabsf(mt.y-tyc)) < rc;
    float c = cost_from(mt.w, dvv, iou, inb&&inc, ib);

    bool ent = (c < rcst[NTOP-1]) || (c == rcst[NTOP-1] && a < ridx[NTOP-1]);
    if (ent){
      #pragma unroll
      for (int j = NTOP-1; j >= 1; --j){
        bool bj  = (c < rcst[j])   || (c == rcst[j]   && a < ridx[j]);
        bool bj1 = (c < rcst[j-1]) || (c == rcst[j-1] && a < ridx[j-1]);
        float nc = bj ? (bj1 ? rcst[j-1] : c) : rcst[j];
        int   ni = bj ? (bj1 ? ridx[j-1] : a) : ridx[j];
        rcst[j] = nc; ridx[j] = ni;
      }
      bool b0 = (c < rcst[0]) || (c == rcst[0] && a < ridx[0]);
      rcst[0] = b0 ? c : rcst[0];
      ridx[0] = b0 ? a : ridx[0];
    }

    pb = pb_n; mt = mt_n; dv = dv_n; a = a2;
  }

  // ---- phase A: merge iou lists ----
  {
    int base = tid*SLOT;
    #pragma unroll
    for (int j=0;j<NTOP;++j) fbuf[base+j] = riou[j];
  }
  __syncthreads();
  for (int s2 = 128; s2 >= 1; s2 >>= 1){
    if (tid < s2){
      int bA = tid*SLOT, bB = (tid+s2)*SLOT;
      float ti[NTOP];
      int ia=0, ib2=0;
      #pragma unroll
      for (int k=0;k<NTOP;++k){
        float va=fbuf[bA+ia], vb=fbuf[bB+ib2];
        if (va >= vb){ ti[k]=va; ++ia; } else { ti[k]=vb; ++ib2; }
      }
      #pragma unroll
      for (int k=0;k<NTOP;++k) fbuf[bA+k]=ti[k];
    }
    __syncthreads();
  }
  if (tid == 0){
    rowmax[i*NT + t] = fbuf[0];
    float ssum = 0.0f;
    #pragma unroll
    for (int k=0;k<NTOP;++k) ssum += fbuf[k];
    int dk = (int)ssum;
    if (dk < 1) dk = 1;
    sh_dynk = dk;
  }
  __syncthreads();

  // ---- phase B: merge cost lists ----
  {
    int base = tid*SLOT;
    #pragma unroll
    for (int j=0;j<NTOP;++j){ fbuf[base+j] = rcst[j]; ibuf[base+j] = ridx[j]; }
  }
  __syncthreads();
  for (int s2 = 128; s2 >= 1; s2 >>= 1){
    if (tid < s2){
      int bA = tid*SLOT, bB = (tid+s2)*SLOT;
      float tc[NTOP]; int tx[NTOP];
      int ia=0, ib2=0;
      #pragma unroll
      for (int k=0;k<NTOP;++k){
        float ca=fbuf[bA+ia], cb=fbuf[bB+ib2];
        int   xa=ibuf[bA+ia], xb=ibuf[bB+ib2];
        bool takeA = (ca < cb) || (ca == cb && xa <= xb);
        if (takeA){ tc[k]=ca; tx[k]=xa; ++ia; } else { tc[k]=cb; tx[k]=xb; ++ib2; }
      }
      #pragma unroll
      for (int k=0;k<NTOP;++k){ fbuf[bA+k]=tc[k]; ibuf[bA+k]=tx[k]; }
    }
    __syncthreads();
  }

  if (tid < NTOP){
    int a1 = ibuf[tid];
    if (tid < sh_dynk && a1 < NA && meta4[iNA + a1].z > 0.0f){
      atomicOr(&mask[(size_t)(iNA + a1)*2 + (t>>6)], 1ull << (t & 63));
    }
  }
}

// ---------- Kernel 2: per-anchor resolution + loss partial sums --------------
// 64 anchors/block, 4 target-slices of 32 across the 4 waves.
__global__ __launch_bounds__(256) void k2_peranchor(
    const float* __restrict__ pred,
    const float4* __restrict__ pbox4, const float4* __restrict__ meta4,
    const float* __restrict__ obja, const float* __restrict__ sobja,
    const float* __restrict__ S0a,
    const float* __restrict__ D, int use_d,
    const float* __restrict__ target,
    const float* __restrict__ rowmax, const unsigned long long* __restrict__ mask,
    float* __restrict__ acc)
{
  __shared__ float4 tb4[NT];
  __shared__ int    tcid[NT];
  __shared__ float  invm[NT];
  __shared__ float  tarea[NT];
  __shared__ float  sh_obj[4][64];
  __shared__ float  sh_c[4][64];
  __shared__ int    sh_tp[4][64];

  int i  = blockIdx.x / BPI;
  int b  = blockIdx.x % BPI;
  int c0 = b*APB;
  int q  = threadIdx.x & 63;
  int s  = threadIdx.x >> 6;
  int a  = c0 + q;
  const size_t BA = (size_t)NB*NA;

  for (int idx = threadIdx.x; idx < NT; idx += 256){
    const float* tg = target + (i*NT + idx)*6;
    tcid[idx] = (int)tg[1];
    float x1=tg[2], y1=tg[3], x2=tg[4], y2=tg[5];
    tb4[idx]   = make_float4(x1,y1,x2,y2);
    invm[idx]  = 1.0f / (rowmax[i*NT + idx] + 1e-8f);
    tarea[idx] = fmaxf(x2-x1,0.0f)*fmaxf(y2-y1,0.0f);
  }
  __syncthreads();

  bool valid = (a < NA);
  int gid = i*NA + a;
  float4 pb = valid ? pbox4[gid] : make_float4(0,0,0,0);
  float4 mt = valid ? meta4[gid] : make_float4(0,0,-1.0f,0);
  bool ib = valid && (mt.z > 0.0f);
  float rc = fabsf(mt.z);
  float px1=pb.x, py1=pb.y, px2=pb.z, py2=pb.w;
  float ap = fmaxf(px2-px1,0.0f)*fmaxf(py2-py1,0.0f);

  // slice obj_t partial max (value-only path -> fast rcp)
  float best = 0.0f;
  if (ib){
    #pragma unroll 4
    for (int t = s*32; t < s*32+32; ++t){
      float4 T = tb4[t];
      float w = fminf(T.z,px2) - fmaxf(T.x,px1);
      float h = fminf(T.w,py2) - fmaxf(T.y,py1);
      w = fmaxf(w,0.0f); h = fmaxf(h,0.0f);
      float inter = w*h;
      float den = tarea[t] + ap - inter + 1e-8f;
      float iou = inter * __builtin_amdgcn_rcpf(den);
      best = fmaxf(best, iou*invm[t]);
    }
  }
  sh_obj[s][q] = best;

  unsigned long long m0=0, m1=0;
  if (valid){ m0 = mask[(size_t)gid*2]; m1 = mask[(size_t)gid*2+1]; }
  int cnt = __popcll(m0) + __popcll(m1);

  float bc = FLT_MAX; int bt = NT;
  if (cnt > 1){
    // selection path: bit-identical cost (precise pair_iou / logf / D table)
    float sobj = use_d ? 0.0f : sobja[gid];
    float Sg = mt.w;
    for (int t = s*32; t < s*32+32; ++t){
      float4 T = tb4[t];
      float iou = ib ? pair_iou(T.x,T.y,T.z,T.w,px1,py1,px2,py2) : 0.0f;
      bool inb = (mt.x-T.x>0.0f)&&(mt.y-T.y>0.0f)&&(T.z-mt.x>0.0f)&&(T.w-mt.y>0.0f);
      float txc=(T.x+T.z)*0.5f, tyc=(T.y+T.w)*0.5f;
      bool inc = fmaxf(fabsf(mt.x-txc),fabsf(mt.y-tyc)) < rc;
      float dv = use_d ? D[(size_t)tcid[t]*BA + gid]
                       : dval_fn(sobj, pred[(size_t)gid*PDIM + 5 + tcid[t]]);
      float c = cost_from(Sg, dv, iou, inb&&inc, ib);
      if (c < bc){ bc = c; bt = t; }   // strict < -> first occurrence in slice
    }
  }
  sh_c[s][q] = bc; sh_tp[s][q] = bt;
  __syncthreads();

  if (s == 0){
    float m=0.0f, vbox=0.0f, vobj=0.0f, vcls=0.0f;
    if (valid){
      float ob = fmaxf(fmaxf(sh_obj[0][q],sh_obj[1][q]), fmaxf(sh_obj[2][q],sh_obj[3][q]));
      float obj_t = ib ? fminf(fmaxf(ob,0.0f),1.0f) : 0.0f;
      vobj = bce(obja[gid], obj_t);

      float cbest = sh_c[0][q]; int tbest = sh_tp[0][q];
      #pragma unroll
      for (int s2=1; s2<4; ++s2){
        float cs = sh_c[s2][q]; int ts = sh_tp[s2][q];
        if (cs < cbest){ cbest = cs; tbest = ts; }  // ties keep earlier slice = lower t
      }

      int tp = 0; bool mpv = false;
      if (cnt > 1){ tp = tbest; mpv = true; }
      else if (cnt == 1){
        tp = m0 ? (__ffsll(m0)-1) : (64 + __ffsll(m1)-1);
        mpv = true;
      }

      if (mpv){
        m = 1.0f;
        float4 T = tb4[tp];
        float x1=T.x, y1=T.y, x2=T.z, y2=T.w;
        float w = fmaxf(fminf(px2,x2)-fmaxf(px1,x1),0.0f);
        float h = fmaxf(fminf(py2,y2)-fmaxf(py1,y1),0.0f);
        float inter = w*h;
        float wp=px2-px1, hp=py2-py1, wt=x2-x1, ht=y2-y1;
        float iou = inter/(wp*hp + wt*ht - inter + 1e-8f);
        float cw = fmaxf(px2,x2)-fminf(px1,x1);
        float ch = fmaxf(py2,y2)-fminf(py1,y1);
        float c2 = cw*cw + ch*ch + 1e-8f;
        float dx = (px1+px2)-(x1+x2), dy = (py1+py2)-(y1+y2);
        float rho2 = (dx*dx + dy*dy)/4.0f;
        float da = atanf(wt/(ht+1e-8f)) - atanf(wp/(hp+1e-8f));
        float v  = 0.4052847345693511f * da * da;   // 4/pi^2
        float alpha = v/(1.0f - iou + v + 1e-8f);
        vbox = 1.0f - (iou - rho2/c2 - alpha*v);

        int cc = tcid[tp];
        float xcc = pred[(size_t)gid*PDIM + 5 + cc];
        vcls = (S0a[gid] - xcc) * (1.0f/80.0f);   // sum_c bce(x_c, onehot) = S0 - x_cc
      }
    }

    #pragma unroll
    for (int off=32; off>0; off>>=1){
      m    += __shfl_down(m, off);
      vbox += __shfl_down(vbox, off);
      vobj += __shfl_down(vobj, off);
      vcls += __shfl_down(vcls, off);
    }
    if (q == 0){
      int slot = (blockIdx.x & 63)*4;
      atomicAdd(&acc[slot+0], m);
      atomicAdd(&acc[slot+1], vbox);
      atomicAdd(&acc[slot+2], vobj);
      atomicAdd(&acc[slot+3], vcls);
    }
  }
}

// ---------------- Kernel 3: finalize (reduce 64 accumulator slots) -----------
__global__ void k3_final(const float* __restrict__ acc, float* __restrict__ out){
  int l = threadIdx.x;   // 64 threads
  float4 v = ((const float4*)acc)[l];
  #pragma unroll
  for (int off=32; off>0; off>>=1){
    v.x += __shfl_down(v.x, off);
    v.y += __shfl_down(v.y, off);
    v.z += __shfl_down(v.z, off);
    v.w += __shfl_down(v.w, off);
  }
  if (l == 0){
    float n    = fmaxf(v.x, 1.0f);
    float lbox = 0.05f * v.y / n;
    float lobj = v.z / (float)(NB*NA);
    float lcls = 0.5f  * v.w / n;
    out[0] = lbox + lobj + lcls;
    out[1] = lbox; out[2] = lobj; out[3] = lcls;
  }
}

extern "C" void kernel_launch(void* const* d_in, const int* in_sizes, int n_in,
                              void* d_out, int out_size, void* d_ws, size_t ws_size,
                              hipStream_t stream) {
  const float* pred    = (const float*)d_in[0];
  const float* target  = (const float*)d_in[1];
  const float* grid    = (const float*)d_in[2];
  const float* stridev = (const float*)d_in[3];
  float* out = (float*)d_out;

  char* ws = (char*)d_ws;
  const size_t BA = (size_t)NB*NA;   // 134400

  size_t off = 0;
  unsigned long long* mask = (unsigned long long*)(ws + off); off += BA*16;
  float* acc    = (float*)(ws + off); off += 64*4*4;
  const size_t zero_bytes = off;      // mask + acc slots
  float4* pbox4 = (float4*)(ws + off); off += BA*16;
  float4* meta4 = (float4*)(ws + off); off += BA*16;
  float* obja   = (float*)(ws + off); off += BA*4;
  float* sobja  = (float*)(ws + off); off += BA*4;
  float* S0a    = (float*)(ws + off); off += BA*4;
  float* rowmax = (float*)(ws + off); off += (size_t)NB*NT*4;
  float* D      = (float*)(ws + off);
  const size_t need_d = off + (size_t)NCLS*BA*4;
  int use_d = (ws_size >= need_d) ? 1 : 0;

  hipMemsetAsync(d_ws, 0, zero_bytes, stream);

  k0_precompute<<<NB*BPI, 256, 0, stream>>>(pred, target, grid, stridev,
                                            pbox4, meta4, obja, sobja, S0a, D, use_d);
  k1_pertarget <<<NB*NT,  256, 0, stream>>>(pbox4, meta4, D, use_d,
                                            sobja, pred, target, rowmax, mask);
  k2_peranchor <<<NB*BPI, 256, 0, stream>>>(pred, pbox4, meta4, obja, sobja, S0a,
                                            D, use_d, target, rowmax, mask, acc);
  k3_final     <<<1, 64, 0, stream>>>(acc, out);
}

// Round 4
// 321.042 us; speedup vs baseline: 2.3435x; 1.1370x over previous
//
#include <hip/hip_runtime.h>
#include <cfloat>

#pragma clang fp contract(off)

#define NCLS 80
#define PDIM 85
#define NA   8400
#define NB   16
#define NT   128
#define NTOP 10
#define SLOT 11      // LDS stride for merge lists (odd -> free 2-way bank aliasing)
#define APB  64      // anchors per k0/k2 block
#define BPI  132     // ceil(NA/64)

__device__ __forceinline__ float sigm(float x){ return 1.0f/(1.0f+expf(-x)); }

__device__ __forceinline__ float bce(float x, float t){
  return fmaxf(x,0.0f) - x*t + log1pf(expf(-fabsf(x)));
}

// Fast-rcp IoU. Used identically in k1 top-k and k2 argmin -> internally consistent.
__device__ __forceinline__ float pair_iou(float tx1,float ty1,float tx2,float ty2,
                                          float px1,float py1,float px2,float py2){
  float w = fminf(tx2,px2) - fmaxf(tx1,px1);
  float h = fminf(ty2,py2) - fmaxf(ty1,py1);
  w = fmaxf(w,0.0f); h = fmaxf(h,0.0f);
  float inter = w*h;
  float at = fmaxf(tx2-tx1,0.0f)*fmaxf(ty2-ty1,0.0f);
  float ap = fmaxf(px2-px1,0.0f)*fmaxf(py2-py1,0.0f);
  float den = at+ap-inter+1e-8f;
  return inter * __builtin_amdgcn_rcpf(den);
}

// dval = fmax(log(p),-100) - fmax(log1p(-p),-100), p = sqrt(sobj*sigm(lg)).
__device__ __forceinline__ float dval_fn(float sobj, float lg){
  float sc = sigm(lg);
  float p  = sqrtf(sobj*sc);
  float lp = fmaxf(logf(p), -100.0f);
  float l1 = fmaxf(log1pf(-p), -100.0f);
  return lp - l1;
}

// Selection-critical: identical in k1 top-k and k2 argmin (same inline, contract off).
// Fast v_log_f32: -ln(x) = -ln2 * log2(x).
__device__ __forceinline__ float cost_from(float S, float dval, float iou, bool ibc, bool ib){
  float iouc = -0.6931471805599453f * __builtin_amdgcn_logf(iou + 1e-8f);
  float clsc = -(S + dval);
  float c = clsc + 3.0f*iouc;
  c = c + (ibc ? 0.0f : 100000.0f);
  c = c + (ib  ? 0.0f : 1000000000.0f);
  return c;
}

// ---------------- Kernel 0: transpose + per-anchor precompute ----------------
__global__ __launch_bounds__(256) void k0_precompute(
    const float* __restrict__ pred, const float* __restrict__ target,
    const float* __restrict__ grid, const float* __restrict__ stridev,
    float4* __restrict__ pbox4, float4* __restrict__ meta4,
    float* __restrict__ obja, float* __restrict__ sobja,
    float* __restrict__ S0a, float* __restrict__ D, int use_d)
{
  __shared__ float  tile[APB*PDIM];   // [a][c], stride 85 (odd -> conflict-free)
  __shared__ float4 tb4s[NT];
  __shared__ float  ps_s[4][APB];
  __shared__ float  ps0_s[4][APB];
  __shared__ int    ib_s[4][APB];

  int i  = blockIdx.x / BPI;
  int b  = blockIdx.x % BPI;
  int c0 = b*APB;
  int n  = NA - c0; if (n > APB) n = APB;
  int tid = threadIdx.x;

  const float* src = pred + ((size_t)i*NA + c0)*PDIM;
  int tot = n*PDIM;
  for (int idx = tid; idx < tot; idx += 256) tile[idx] = src[idx];
  for (int idx = tid; idx < NT; idx += 256){
    const float* tg = target + (i*NT + idx)*6;
    tb4s[idx] = make_float4(tg[2],tg[3],tg[4],tg[5]);
  }
  __syncthreads();

  int al = tid & 63, cg = tid >> 6;
  if (al < n){
    int gid = i*NA + c0 + al;
    float sobj = sigm(tile[al*PDIM+4]);
    float ps = 0.0f, ps0 = 0.0f;
    #pragma unroll 4
    for (int k = 0; k < 20; ++k){
      int c = cg*20 + k;
      float x  = tile[al*PDIM+5+c];
      float sc = sigm(x);
      float p  = sqrtf(sobj*sc);
      float lp = fmaxf(logf(p), -100.0f);
      float l1 = fmaxf(log1pf(-p), -100.0f);
      ps  += l1;
      ps0 += fmaxf(x,0.0f) + log1pf(expf(-fabsf(x)));   // bce(x,0)
      if (use_d) D[(size_t)c*((size_t)NB*NA) + gid] = lp - l1;
    }
    ps_s[cg][al] = ps; ps0_s[cg][al] = ps0;

    // in-box partial: 32 targets per wave-group
    int ga = c0 + al;
    float xg = grid[2*ga], yg = grid[2*ga+1], sv = stridev[ga];
    float xc = (xg + 0.5f)*sv, yc = (yg + 0.5f)*sv;
    float rc = 2.5f*sv;
    bool ibp = false;
    #pragma unroll 4
    for (int t = cg*32; t < cg*32+32; ++t){
      float4 T = tb4s[t];
      bool inb = (xc-T.x>0.0f)&&(yc-T.y>0.0f)&&(T.z-xc>0.0f)&&(T.w-yc>0.0f);
      float txc=(T.x+T.z)*0.5f, tyc=(T.y+T.w)*0.5f;
      bool inc = fmaxf(fabsf(xc-txc),fabsf(yc-tyc)) < rc;
      ibp = ibp || inb || inc;
    }
    ib_s[cg][al] = ibp ? 1 : 0;
  }
  __syncthreads();

  if (tid < n){
    int a = tid;
    int gid = i*NA + c0 + a;
    float s  = ps_s[0][a]  + ps_s[1][a]  + ps_s[2][a]  + ps_s[3][a];
    float s0 = ps0_s[0][a] + ps0_s[1][a] + ps0_s[2][a] + ps0_s[3][a];
    bool ib  = (ib_s[0][a] | ib_s[1][a] | ib_s[2][a] | ib_s[3][a]) != 0;

    float x1 = tile[a*PDIM+0], y1 = tile[a*PDIM+1];
    float x2 = tile[a*PDIM+2], y2 = tile[a*PDIM+3];
    float ol = tile[a*PDIM+4];
    pbox4[gid] = make_float4(x1,y1,x2,y2);
    obja[gid]  = ol;
    sobja[gid] = sigm(ol);
    S0a[gid]   = s0;

    int ga = c0 + a;
    float xg = grid[2*ga], yg = grid[2*ga+1], sv = stridev[ga];
    float xc = (xg + 0.5f)*sv, yc = (yg + 0.5f)*sv;
    float rc = 2.5f*sv;
    meta4[gid] = make_float4(xc, yc, ib ? rc : -rc, s);  // sign(z) = in_box
  }
}

// ------------- Kernel 1: per (image,target) top-k + match scatter ------------
__global__ __launch_bounds__(256) void k1_pertarget(
    const float4* __restrict__ pbox4, const float4* __restrict__ meta4,
    const float* __restrict__ D, int use_d,
    const float* __restrict__ sobja, const float* __restrict__ pred,
    const float* __restrict__ target,
    float* __restrict__ rowmax, unsigned long long* __restrict__ mask)
{
  __shared__ float fbuf[128*SLOT];
  __shared__ int   ibuf[128*SLOT];
  __shared__ int   sh_dynk;

  int i   = blockIdx.x / NT;
  int t   = blockIdx.x % NT;
  int tid = threadIdx.x;
  const size_t BA = (size_t)NB*NA;

  const float* tg = target + (i*NT + t)*6;
  int   cid = (int)tg[1];
  float tx1 = tg[2], ty1 = tg[3], tx2 = tg[4], ty2 = tg[5];
  float txc = (tx1+tx2)*0.5f, tyc = (ty1+ty2)*0.5f;
  const float* Dc = use_d ? (D + (size_t)cid*BA) : nullptr;

  float riou[NTOP]; float rcst[NTOP]; int ridx[NTOP];
  #pragma unroll
  for (int j=0;j<NTOP;++j){ riou[j]=0.0f; rcst[j]=FLT_MAX; ridx[j]=0x7fffffff; }

  int iNA = i*NA;
  int a = tid;
  float4 pb = pbox4[iNA+a];
  float4 mt = meta4[iNA+a];
  float  dv = use_d ? Dc[iNA+a] : 0.0f;

  while (a < NA){
    int a2 = a + 256;
    int ld = (a2 < NA) ? a2 : a;
    float4 pb_n = pbox4[iNA+ld];
    float4 mt_n = meta4[iNA+ld];
    float  dv_n = use_d ? Dc[iNA+ld] : 0.0f;

    // Out-of-box anchors carry +1e9 cost: in-box entries always rank strictly
    // ahead, and out-of-box selections are removed by `matching & in_box`
    // anyway -> skip ALL cost/top-k work for them.
    if (mt.z > 0.0f){
      float iou = pair_iou(tx1,ty1,tx2,ty2, pb.x,pb.y,pb.z,pb.w);

      if (iou > riou[NTOP-1]){
        #pragma unroll
        for (int j = NTOP-1; j >= 1; --j){
          bool gj  = iou > riou[j];
          bool gj1 = iou > riou[j-1];
          riou[j] = gj ? (gj1 ? riou[j-1] : iou) : riou[j];
        }
        riou[0] = (iou > riou[0]) ? iou : riou[0];
      }

      float dvv = use_d ? dv : dval_fn(sobja[iNA+a], pred[(size_t)(iNA+a)*PDIM + 5 + cid]);
      bool inb = (mt.x-tx1>0.0f)&&(mt.y-ty1>0.0f)&&(tx2-mt.x>0.0f)&&(ty2-mt.y>0.0f);
      bool inc = fmaxf(fabsf(mt.x-txc),fabsf(mt.y-tyc)) < mt.z;
      float c = cost_from(mt.w, dvv, iou, inb&&inc, true);

      // per-thread candidates arrive in ascending index -> strict < already
      // implements jax's lower-index tie-break; no idx compare needed here.
      if (c < rcst[NTOP-1]){
        #pragma unroll
        for (int j = NTOP-1; j >= 1; --j){
          bool bj  = c < rcst[j];
          bool bj1 = c < rcst[j-1];
          float nc = bj ? (bj1 ? rcst[j-1] : c) : rcst[j];
          int   ni = bj ? (bj1 ? ridx[j-1] : a) : ridx[j];
          rcst[j] = nc; ridx[j] = ni;
        }
        bool b0 = c < rcst[0];
        rcst[0] = b0 ? c : rcst[0];
        ridx[0] = b0 ? a : ridx[0];
      }
    }

    pb = pb_n; mt = mt_n; dv = dv_n; a = a2;
  }

  // ---- phase A: iou lists. Fold 256 -> 128 in registers, then LDS tree ----
  if (tid >= 128){
    int base = (tid-128)*SLOT;
    #pragma unroll
    for (int j=0;j<NTOP;++j) fbuf[base+j] = riou[j];
  }
  __syncthreads();
  if (tid < 128){
    int bB = tid*SLOT;
    float ti[NTOP]; int ia=0, ib2=0;
    #pragma unroll
    for (int k=0;k<NTOP;++k){
      float va=riou[ia], vb=fbuf[bB+ib2];
      if (va >= vb){ ti[k]=va; ++ia; } else { ti[k]=vb; ++ib2; }
    }
    #pragma unroll
    for (int k=0;k<NTOP;++k) riou[k]=ti[k];
  }
  __syncthreads();
  if (tid < 128){
    int base = tid*SLOT;
    #pragma unroll
    for (int j=0;j<NTOP;++j) fbuf[base+j] = riou[j];
  }
  __syncthreads();
  for (int s2 = 64; s2 >= 1; s2 >>= 1){
    if (tid < s2){
      int bA = tid*SLOT, bB = (tid+s2)*SLOT;
      float ti[NTOP];
      int ia=0, ib2=0;
      #pragma unroll
      for (int k=0;k<NTOP;++k){
        float va=fbuf[bA+ia], vb=fbuf[bB+ib2];
        if (va >= vb){ ti[k]=va; ++ia; } else { ti[k]=vb; ++ib2; }
      }
      #pragma unroll
      for (int k=0;k<NTOP;++k) fbuf[bA+k]=ti[k];
    }
    __syncthreads();
  }
  if (tid == 0){
    rowmax[i*NT + t] = fbuf[0];
    float ssum = 0.0f;
    #pragma unroll
    for (int k=0;k<NTOP;++k) ssum += fbuf[k];
    int dk = (int)ssum;
    if (dk < 1) dk = 1;
    sh_dynk = dk;
  }
  __syncthreads();

  // ---- phase B: cost lists (idx tie-break across threads) ----
  if (tid >= 128){
    int base = (tid-128)*SLOT;
    #pragma unroll
    for (int j=0;j<NTOP;++j){ fbuf[base+j] = rcst[j]; ibuf[base+j] = ridx[j]; }
  }
  __syncthreads();
  if (tid < 128){
    int bB = tid*SLOT;
    float tc[NTOP]; int tx[NTOP]; int ia=0, ib2=0;
    #pragma unroll
    for (int k=0;k<NTOP;++k){
      float ca=rcst[ia], cb=fbuf[bB+ib2];
      int   xa=ridx[ia], xb=ibuf[bB+ib2];
      bool takeA = (ca < cb) || (ca == cb && xa <= xb);
      if (takeA){ tc[k]=ca; tx[k]=xa; ++ia; } else { tc[k]=cb; tx[k]=xb; ++ib2; }
    }
    #pragma unroll
    for (int k=0;k<NTOP;++k){ rcst[k]=tc[k]; ridx[k]=tx[k]; }
  }
  __syncthreads();
  if (tid < 128){
    int base = tid*SLOT;
    #pragma unroll
    for (int j=0;j<NTOP;++j){ fbuf[base+j] = rcst[j]; ibuf[base+j] = ridx[j]; }
  }
  __syncthreads();
  for (int s2 = 64; s2 >= 1; s2 >>= 1){
    if (tid < s2){
      int bA = tid*SLOT, bB = (tid+s2)*SLOT;
      float tc[NTOP]; int tx[NTOP];
      int ia=0, ib2=0;
      #pragma unroll
      for (int k=0;k<NTOP;++k){
        float ca=fbuf[bA+ia], cb=fbuf[bB+ib2];
        int   xa=ibuf[bA+ia], xb=ibuf[bB+ib2];
        bool takeA = (ca < cb) || (ca == cb && xa <= xb);
        if (takeA){ tc[k]=ca; tx[k]=xa; ++ia; } else { tc[k]=cb; tx[k]=xb; ++ib2; }
      }
      #pragma unroll
      for (int k=0;k<NTOP;++k){ fbuf[bA+k]=tc[k]; ibuf[bA+k]=tx[k]; }
    }
    __syncthreads();
  }

  if (tid < NTOP){
    int a1 = ibuf[tid];
    if (tid < sh_dynk && a1 < NA && meta4[iNA + a1].z > 0.0f){
      atomicOr(&mask[(size_t)(iNA + a1)*2 + (t>>6)], 1ull << (t & 63));
    }
  }
}

// ---------- Kernel 2: per-anchor resolution + loss partial sums --------------
__global__ __launch_bounds__(256) void k2_peranchor(
    const float* __restrict__ pred,
    const float4* __restrict__ pbox4, const float4* __restrict__ meta4,
    const float* __restrict__ obja, const float* __restrict__ sobja,
    const float* __restrict__ S0a,
    const float* __restrict__ D, int use_d,
    const float* __restrict__ target,
    const float* __restrict__ rowmax, const unsigned long long* __restrict__ mask,
    float* __restrict__ acc)
{
  __shared__ float4 tb4[NT];
  __shared__ int    tcid[NT];
  __shared__ float  invm[NT];
  __shared__ float  tarea[NT];
  __shared__ float  sh_obj[4][64];
  __shared__ float  sh_c[4][64];
  __shared__ int    sh_tp[4][64];

  int i  = blockIdx.x / BPI;
  int b  = blockIdx.x % BPI;
  int c0 = b*APB;
  int q  = threadIdx.x & 63;
  int s  = threadIdx.x >> 6;
  int a  = c0 + q;
  const size_t BA = (size_t)NB*NA;

  for (int idx = threadIdx.x; idx < NT; idx += 256){
    const float* tg = target + (i*NT + idx)*6;
    tcid[idx] = (int)tg[1];
    float x1=tg[2], y1=tg[3], x2=tg[4], y2=tg[5];
    tb4[idx]   = make_float4(x1,y1,x2,y2);
    invm[idx]  = 1.0f / (rowmax[i*NT + idx] + 1e-8f);
    tarea[idx] = fmaxf(x2-x1,0.0f)*fmaxf(y2-y1,0.0f);
  }
  __syncthreads();

  bool valid = (a < NA);
  int gid = i*NA + a;
  float4 pb = valid ? pbox4[gid] : make_float4(0,0,0,0);
  float4 mt = valid ? meta4[gid] : make_float4(0,0,-1.0f,0);
  bool ib = valid && (mt.z > 0.0f);
  float rc = fabsf(mt.z);
  float px1=pb.x, py1=pb.y, px2=pb.z, py2=pb.w;
  float ap = fmaxf(px2-px1,0.0f)*fmaxf(py2-py1,0.0f);

  float best = 0.0f;
  if (ib){
    #pragma unroll 4
    for (int t = s*32; t < s*32+32; ++t){
      float4 T = tb4[t];
      float w = fminf(T.z,px2) - fmaxf(T.x,px1);
      float h = fminf(T.w,py2) - fmaxf(T.y,py1);
      w = fmaxf(w,0.0f); h = fmaxf(h,0.0f);
      float inter = w*h;
      float den = tarea[t] + ap - inter + 1e-8f;
      float iou = inter * __builtin_amdgcn_rcpf(den);
      best = fmaxf(best, iou*invm[t]);
    }
  }
  sh_obj[s][q] = best;

  unsigned long long m0=0, m1=0;
  if (valid){ m0 = mask[(size_t)gid*2]; m1 = mask[(size_t)gid*2+1]; }
  int cnt = __popcll(m0) + __popcll(m1);

  float bc = FLT_MAX; int bt = NT;
  if (cnt > 1){
    // selection path: identical helpers as k1 -> consistent cost values
    float sobj = use_d ? 0.0f : sobja[gid];
    float Sg = mt.w;
    for (int t = s*32; t < s*32+32; ++t){
      float4 T = tb4[t];
      float iou = ib ? pair_iou(T.x,T.y,T.z,T.w,px1,py1,px2,py2) : 0.0f;
      bool inb = (mt.x-T.x>0.0f)&&(mt.y-T.y>0.0f)&&(T.z-mt.x>0.0f)&&(T.w-mt.y>0.0f);
      float txc=(T.x+T.z)*0.5f, tyc=(T.y+T.w)*0.5f;
      bool inc = fmaxf(fabsf(mt.x-txc),fabsf(mt.y-tyc)) < rc;
      float dv = use_d ? D[(size_t)tcid[t]*BA + gid]
                       : dval_fn(sobj, pred[(size_t)gid*PDIM + 5 + tcid[t]]);
      float c = cost_from(Sg, dv, iou, inb&&inc, ib);
      if (c < bc){ bc = c; bt = t; }
    }
  }
  sh_c[s][q] = bc; sh_tp[s][q] = bt;
  __syncthreads();

  if (s == 0){
    float m=0.0f, vbox=0.0f, vobj=0.0f, vcls=0.0f;
    if (valid){
      float ob = fmaxf(fmaxf(sh_obj[0][q],sh_obj[1][q]), fmaxf(sh_obj[2][q],sh_obj[3][q]));
      float obj_t = ib ? fminf(fmaxf(ob,0.0f),1.0f) : 0.0f;
      vobj = bce(obja[gid], obj_t);

      float cbest = sh_c[0][q]; int tbest = sh_tp[0][q];
      #pragma unroll
      for (int s2=1; s2<4; ++s2){
        float cs = sh_c[s2][q]; int ts = sh_tp[s2][q];
        if (cs < cbest){ cbest = cs; tbest = ts; }
      }

      int tp = 0; bool mpv = false;
      if (cnt > 1){ tp = tbest; mpv = true; }
      else if (cnt == 1){
        tp = m0 ? (__ffsll(m0)-1) : (64 + __ffsll(m1)-1);
        mpv = true;
      }

      if (mpv){
        m = 1.0f;
        float4 T = tb4[tp];
        float x1=T.x, y1=T.y, x2=T.z, y2=T.w;
        float w = fmaxf(fminf(px2,x2)-fmaxf(px1,x1),0.0f);
        float h = fmaxf(fminf(py2,y2)-fmaxf(py1,y1),0.0f);
        float inter = w*h;
        float wp=px2-px1, hp=py2-py1, wt=x2-x1, ht=y2-y1;
        float iou = inter/(wp*hp + wt*ht - inter + 1e-8f);
        float cw = fmaxf(px2,x2)-fminf(px1,x1);
        float ch = fmaxf(py2,y2)-fminf(py1,y1);
        float c2 = cw*cw + ch*ch + 1e-8f;
        float dx = (px1+px2)-(x1+x2), dy = (py1+py2)-(y1+y2);
        float rho2 = (dx*dx + dy*dy)/4.0f;
        float da = atanf(wt/(ht+1e-8f)) - atanf(wp/(hp+1e-8f));
        float v  = 0.4052847345693511f * da * da;   // 4/pi^2
        float alpha = v/(1.0f - iou + v + 1e-8f);
        vbox = 1.0f - (iou - rho2/c2 - alpha*v);

        int cc = tcid[tp];
        float xcc = pred[(size_t)gid*PDIM + 5 + cc];
        vcls = (S0a[gid] - xcc) * (1.0f/80.0f);   // sum_c bce(x_c, onehot) = S0 - x_cc
      }
    }

    #pragma unroll
    for (int off=32; off>0; off>>=1){
      m    += __shfl_down(m, off);
      vbox += __shfl_down(vbox, off);
      vobj += __shfl_down(vobj, off);
      vcls += __shfl_down(vcls, off);
    }
    if (q == 0){
      int slot = (blockIdx.x & 63)*4;
      atomicAdd(&acc[slot+0], m);
      atomicAdd(&acc[slot+1], vbox);
      atomicAdd(&acc[slot+2], vobj);
      atomicAdd(&acc[slot+3], vcls);
    }
  }
}

// ---------------- Kernel 3: finalize (reduce 64 accumulator slots) -----------
__global__ void k3_final(const float* __restrict__ acc, float* __restrict__ out){
  int l = threadIdx.x;   // 64 threads
  float4 v = ((const float4*)acc)[l];
  #pragma unroll
  for (int off=32; off>0; off>>=1){
    v.x += __shfl_down(v.x, off);
    v.y += __shfl_down(v.y, off);
    v.z += __shfl_down(v.z, off);
    v.w += __shfl_down(v.w, off);
  }
  if (l == 0){
    float n    = fmaxf(v.x, 1.0f);
    float lbox = 0.05f * v.y / n;
    float lobj = v.z / (float)(NB*NA);
    float lcls = 0.5f  * v.w / n;
    out[0] = lbox + lobj + lcls;
    out[1] = lbox; out[2] = lobj; out[3] = lcls;
  }
}

extern "C" void kernel_launch(void* const* d_in, const int* in_sizes, int n_in,
                              void* d_out, int out_size, void* d_ws, size_t ws_size,
                              hipStream_t stream) {
  const float* pred    = (const float*)d_in[0];
  const float* target  = (const float*)d_in[1];
  const float* grid    = (const float*)d_in[2];
  const float* stridev = (const float*)d_in[3];
  float* out = (float*)d_out;

  char* ws = (char*)d_ws;
  const size_t BA = (size_t)NB*NA;   // 134400

  size_t off = 0;
  unsigned long long* mask = (unsigned long long*)(ws + off); off += BA*16;
  float* acc    = (float*)(ws + off); off += 64*4*4;
  const size_t zero_bytes = off;      // mask + acc slots
  float4* pbox4 = (float4*)(ws + off); off += BA*16;
  float4* meta4 = (float4*)(ws + off); off += BA*16;
  float* obja   = (float*)(ws + off); off += BA*4;
  float* sobja  = (float*)(ws + off); off += BA*4;
  float* S0a    = (float*)(ws + off); off += BA*4;
  float* rowmax = (float*)(ws + off); off += (size_t)NB*NT*4;
  float* D      = (float*)(ws + off);
  const size_t need_d = off + (size_t)NCLS*BA*4;
  int use_d = (ws_size >= need_d) ? 1 : 0;

  hipMemsetAsync(d_ws, 0, zero_bytes, stream);

  k0_precompute<<<NB*BPI, 256, 0, stream>>>(pred, target, grid, stridev,
                                            pbox4, meta4, obja, sobja, S0a, D, use_d);
  k1_pertarget <<<NB*NT,  256, 0, stream>>>(pbox4, meta4, D, use_d,
                                            sobja, pred, target, rowmax, mask);
  k2_peranchor <<<NB*BPI, 256, 0, stream>>>(pred, pbox4, meta4, obja, sobja, S0a,
                                            D, use_d, target, rowmax, mask, acc);
  k3_final     <<<1, 64, 0, stream>>>(acc, out);
}

// Round 5
// 251.301 us; speedup vs baseline: 2.9939x; 1.2775x over previous
//
#include <hip/hip_runtime.h>
#include <cfloat>

#pragma clang fp contract(off)

#define NCLS 80
#define PDIM 85
#define NA   8400
#define NB   16
#define NT   128
#define NTOP 10
#define SLOT 11      // LDS stride for merge lists (odd -> free 2-way bank aliasing)
#define APB  64      // anchors per k0/k2 block
#define BPI  132     // ceil(NA/64)
#define LN2  0.6931471805599453f

// fast native sigmoid: rcp(1+exp(-x)). Value-path + stored-once selection inputs.
__device__ __forceinline__ float sigm_fast(float x){
  float e = __expf(-x);
  return __builtin_amdgcn_rcpf(1.0f + e);
}

// fast bce (value path only)
__device__ __forceinline__ float bce_fast(float x, float t){
  float ax = fabsf(x);
  float e  = __expf(-ax);
  return fmaxf(x,0.0f) - x*t + LN2*__builtin_amdgcn_logf(1.0f + e);
}

// Fast-rcp IoU. Used identically in k1 top-k and k2 argmin -> internally consistent.
__device__ __forceinline__ float pair_iou(float tx1,float ty1,float tx2,float ty2,
                                          float px1,float py1,float px2,float py2){
  float w = fminf(tx2,px2) - fmaxf(tx1,px1);
  float h = fminf(ty2,py2) - fmaxf(ty1,py1);
  w = fmaxf(w,0.0f); h = fmaxf(h,0.0f);
  float inter = w*h;
  float at = fmaxf(tx2-tx1,0.0f)*fmaxf(ty2-ty1,0.0f);
  float ap = fmaxf(px2-px1,0.0f)*fmaxf(py2-py1,0.0f);
  float den = at+ap-inter+1e-8f;
  return inter * __builtin_amdgcn_rcpf(den);
}

// dval fallback (use_d==0) — MUST match k0's D formula exactly.
__device__ __forceinline__ float dval_fn(float sobj, float lg){
  float sc = sigm_fast(lg);
  float u  = sobj*sc;
  float p  = sqrtf(u);
  float lp = fmaxf(0.5f*LN2*__builtin_amdgcn_logf(u), -100.0f);
  float l1 = fmaxf(LN2*__builtin_amdgcn_logf(fmaxf(1.0f - p, 0.0f)), -100.0f);
  return lp - l1;
}

// Selection-critical: identical in k1 top-k and k2 argmin (same inline, contract off).
__device__ __forceinline__ float cost_from(float S, float dval, float iou, bool ibc, bool ib){
  float iouc = -LN2 * __builtin_amdgcn_logf(iou + 1e-8f);
  float clsc = -(S + dval);
  float c = clsc + 3.0f*iouc;
  c = c + (ibc ? 0.0f : 100000.0f);
  c = c + (ib  ? 0.0f : 1000000000.0f);
  return c;
}

// ---------------- Kernel 0: transpose + per-anchor precompute ----------------
__global__ __launch_bounds__(256) void k0_precompute(
    const float* __restrict__ pred, const float* __restrict__ target,
    const float* __restrict__ grid, const float* __restrict__ stridev,
    float4* __restrict__ pbox4, float4* __restrict__ meta4,
    float* __restrict__ obja, float* __restrict__ sobja,
    float* __restrict__ S0a, float* __restrict__ D, int use_d)
{
  __shared__ float  tile[APB*PDIM];   // [a][c], stride 85 (odd -> conflict-free)
  __shared__ float4 tb4s[NT];
  __shared__ float  ps_s[4][APB];
  __shared__ float  ps0_s[4][APB];
  __shared__ int    ib_s[4][APB];

  int i  = blockIdx.x / BPI;
  int b  = blockIdx.x % BPI;
  int c0 = b*APB;
  int n  = NA - c0; if (n > APB) n = APB;
  int tid = threadIdx.x;

  const float* src = pred + ((size_t)i*NA + c0)*PDIM;
  int tot = n*PDIM;
  for (int idx = tid; idx < tot; idx += 256) tile[idx] = src[idx];
  for (int idx = tid; idx < NT; idx += 256){
    const float* tg = target + (i*NT + idx)*6;
    tb4s[idx] = make_float4(tg[2],tg[3],tg[4],tg[5]);
  }
  __syncthreads();

  int al = tid & 63, cg = tid >> 6;
  if (al < n){
    int gid = i*NA + c0 + al;
    float sobj = sigm_fast(tile[al*PDIM+4]);
    float ps = 0.0f, ps0 = 0.0f;
    #pragma unroll 4
    for (int k = 0; k < 20; ++k){
      int c = cg*20 + k;
      float x  = tile[al*PDIM+5+c];
      // dval pieces (selection-only; stored once -> consistent everywhere)
      float sc = sigm_fast(x);
      float u  = sobj*sc;
      float p  = sqrtf(u);
      float lp = fmaxf(0.5f*LN2*__builtin_amdgcn_logf(u), -100.0f);
      float l1 = fmaxf(LN2*__builtin_amdgcn_logf(fmaxf(1.0f - p, 0.0f)), -100.0f);
      ps  += l1;
      if (use_d) D[(size_t)c*((size_t)NB*NA) + gid] = lp - l1;
      // bce(x,0) for S0 (value path)
      float e2 = __expf(-fabsf(x));
      ps0 += fmaxf(x,0.0f) + LN2*__builtin_amdgcn_logf(1.0f + e2);
    }
    ps_s[cg][al] = ps; ps0_s[cg][al] = ps0;

    // in-box partial: 32 targets per wave-group
    int ga = c0 + al;
    float xg = grid[2*ga], yg = grid[2*ga+1], sv = stridev[ga];
    float xc = (xg + 0.5f)*sv, yc = (yg + 0.5f)*sv;
    float rc = 2.5f*sv;
    bool ibp = false;
    #pragma unroll 4
    for (int t = cg*32; t < cg*32+32; ++t){
      float4 T = tb4s[t];
      bool inb = (xc-T.x>0.0f)&&(yc-T.y>0.0f)&&(T.z-xc>0.0f)&&(T.w-yc>0.0f);
      float txc=(T.x+T.z)*0.5f, tyc=(T.y+T.w)*0.5f;
      bool inc = fmaxf(fabsf(xc-txc),fabsf(yc-tyc)) < rc;
      ibp = ibp || inb || inc;
    }
    ib_s[cg][al] = ibp ? 1 : 0;
  }
  __syncthreads();

  if (tid < n){
    int a = tid;
    int gid = i*NA + c0 + a;
    float s  = ps_s[0][a]  + ps_s[1][a]  + ps_s[2][a]  + ps_s[3][a];
    float s0 = ps0_s[0][a] + ps0_s[1][a] + ps0_s[2][a] + ps0_s[3][a];
    bool ib  = (ib_s[0][a] | ib_s[1][a] | ib_s[2][a] | ib_s[3][a]) != 0;

    float x1 = tile[a*PDIM+0], y1 = tile[a*PDIM+1];
    float x2 = tile[a*PDIM+2], y2 = tile[a*PDIM+3];
    float ol = tile[a*PDIM+4];
    pbox4[gid] = make_float4(x1,y1,x2,y2);
    obja[gid]  = ol;
    sobja[gid] = sigm_fast(ol);
    S0a[gid]   = s0;

    int ga = c0 + a;
    float xg = grid[2*ga], yg = grid[2*ga+1], sv = stridev[ga];
    float xc = (xg + 0.5f)*sv, yc = (yg + 0.5f)*sv;
    float rc = 2.5f*sv;
    meta4[gid] = make_float4(xc, yc, ib ? rc : -rc, s);  // sign(z) = in_box
  }
}

// ------------- Kernel 1: per (image,target) top-k + match scatter ------------
__global__ __launch_bounds__(256) void k1_pertarget(
    const float4* __restrict__ pbox4, const float4* __restrict__ meta4,
    const float* __restrict__ D, int use_d,
    const float* __restrict__ sobja, const float* __restrict__ pred,
    const float* __restrict__ target,
    float* __restrict__ rowmax, unsigned long long* __restrict__ mask)
{
  __shared__ float fI[128*SLOT];
  __shared__ float fC[128*SLOT];
  __shared__ int   iB[128*SLOT];
  __shared__ int   sh_dynk;

  int i   = blockIdx.x / NT;
  int t   = blockIdx.x % NT;
  int tid = threadIdx.x;
  const size_t BA = (size_t)NB*NA;

  const float* tg = target + (i*NT + t)*6;
  int   cid = (int)tg[1];
  float tx1 = tg[2], ty1 = tg[3], tx2 = tg[4], ty2 = tg[5];
  float txc = (tx1+tx2)*0.5f, tyc = (ty1+ty2)*0.5f;
  const float* Dc = use_d ? (D + (size_t)cid*BA) : nullptr;

  float riou[NTOP]; float rcst[NTOP]; int ridx[NTOP];
  #pragma unroll
  for (int j=0;j<NTOP;++j){ riou[j]=0.0f; rcst[j]=FLT_MAX; ridx[j]=0x7fffffff; }

  int iNA = i*NA;
  int a = tid;
  float4 pb = pbox4[iNA+a];
  float4 mt = meta4[iNA+a];
  float  dv = use_d ? Dc[iNA+a] : 0.0f;

  while (a < NA){
    int a2 = a + 256;
    int ld = (a2 < NA) ? a2 : a;
    float4 pb_n = pbox4[iNA+ld];
    float4 mt_n = meta4[iNA+ld];
    float  dv_n = use_d ? Dc[iNA+ld] : 0.0f;

    // Out-of-box anchors carry +1e9 cost: never selected (and masked by
    // `matching & in_box` anyway) -> skip all cost/top-k work.
    if (mt.z > 0.0f){
      float iou = pair_iou(tx1,ty1,tx2,ty2, pb.x,pb.y,pb.z,pb.w);

      if (iou > riou[NTOP-1]){
        #pragma unroll
        for (int j = NTOP-1; j >= 1; --j){
          bool gj  = iou > riou[j];
          bool gj1 = iou > riou[j-1];
          riou[j] = gj ? (gj1 ? riou[j-1] : iou) : riou[j];
        }
        riou[0] = (iou > riou[0]) ? iou : riou[0];
      }

      float dvv = use_d ? dv : dval_fn(sobja[iNA+a], pred[(size_t)(iNA+a)*PDIM + 5 + cid]);
      bool inb = (mt.x-tx1>0.0f)&&(mt.y-ty1>0.0f)&&(tx2-mt.x>0.0f)&&(ty2-mt.y>0.0f);
      bool inc = fmaxf(fabsf(mt.x-txc),fabsf(mt.y-tyc)) < mt.z;
      float c = cost_from(mt.w, dvv, iou, inb&&inc, true);

      // per-thread candidates arrive in ascending index -> strict < already
      // implements jax's lower-index tie-break.
      if (c < rcst[NTOP-1]){
        #pragma unroll
        for (int j = NTOP-1; j >= 1; --j){
          bool bj  = c < rcst[j];
          bool bj1 = c < rcst[j-1];
          float nc = bj ? (bj1 ? rcst[j-1] : c) : rcst[j];
          int   ni = bj ? (bj1 ? ridx[j-1] : a) : ridx[j];
          rcst[j] = nc; ridx[j] = ni;
        }
        bool b0 = c < rcst[0];
        rcst[0] = b0 ? c : rcst[0];
        ridx[0] = b0 ? a : ridx[0];
      }
    }

    pb = pb_n; mt = mt_n; dv = dv_n; a = a2;
  }

  // ---- fused merge: both lists share the level loop & barriers ----
  if (tid >= 128){
    int base = (tid-128)*SLOT;
    #pragma unroll
    for (int j=0;j<NTOP;++j){ fI[base+j]=riou[j]; fC[base+j]=rcst[j]; iB[base+j]=ridx[j]; }
  }
  __syncthreads();
  if (tid < 128){
    int bB = tid*SLOT;
    {
      float ti[NTOP]; int ia=0, ib2=0;
      #pragma unroll
      for (int k=0;k<NTOP;++k){
        float va=riou[ia], vb=fI[bB+ib2];
        if (va >= vb){ ti[k]=va; ++ia; } else { ti[k]=vb; ++ib2; }
      }
      #pragma unroll
      for (int k=0;k<NTOP;++k) riou[k]=ti[k];
    }
    {
      float tc[NTOP]; int tx[NTOP]; int ia=0, ib2=0;
      #pragma unroll
      for (int k=0;k<NTOP;++k){
        float ca=rcst[ia], cb=fC[bB+ib2];
        int   xa=ridx[ia], xb=iB[bB+ib2];
        bool takeA = (ca < cb) || (ca == cb && xa <= xb);
        if (takeA){ tc[k]=ca; tx[k]=xa; ++ia; } else { tc[k]=cb; tx[k]=xb; ++ib2; }
      }
      #pragma unroll
      for (int k=0;k<NTOP;++k){ rcst[k]=tc[k]; ridx[k]=tx[k]; }
    }
    // write own merged lists back to own slot (same-thread slot, no hazard)
    #pragma unroll
    for (int j=0;j<NTOP;++j){ fI[bB+j]=riou[j]; fC[bB+j]=rcst[j]; iB[bB+j]=ridx[j]; }
  }
  __syncthreads();

  for (int s2 = 64; s2 >= 1; s2 >>= 1){
    if (tid < s2){
      int bA = tid*SLOT, bB = (tid+s2)*SLOT;
      float ti[NTOP];
      { int ia=0, ib2=0;
        #pragma unroll
        for (int k=0;k<NTOP;++k){
          float va=fI[bA+ia], vb=fI[bB+ib2];
          if (va >= vb){ ti[k]=va; ++ia; } else { ti[k]=vb; ++ib2; }
        }
      }
      float tc[NTOP]; int tx[NTOP];
      { int ia=0, ib2=0;
        #pragma unroll
        for (int k=0;k<NTOP;++k){
          float ca=fC[bA+ia], cb=fC[bB+ib2];
          int   xa=iB[bA+ia], xb=iB[bB+ib2];
          bool takeA = (ca < cb) || (ca == cb && xa <= xb);
          if (takeA){ tc[k]=ca; tx[k]=xa; ++ia; } else { tc[k]=cb; tx[k]=xb; ++ib2; }
        }
      }
      #pragma unroll
      for (int k=0;k<NTOP;++k){ fI[bA+k]=ti[k]; fC[bA+k]=tc[k]; iB[bA+k]=tx[k]; }
    }
    __syncthreads();
  }

  if (tid == 0){
    rowmax[i*NT + t] = fI[0];
    float ssum = 0.0f;
    #pragma unroll
    for (int k=0;k<NTOP;++k) ssum += fI[k];   // descending order, like jnp top_k sum
    int dk = (int)ssum;
    if (dk < 1) dk = 1;
    sh_dynk = dk;
  }
  __syncthreads();

  if (tid < NTOP){
    int a1 = iB[tid];
    if (tid < sh_dynk && a1 < NA && meta4[iNA + a1].z > 0.0f){
      atomicOr(&mask[(size_t)(iNA + a1)*2 + (t>>6)], 1ull << (t & 63));
    }
  }
}

// ---------- Kernel 2: per-anchor resolution + loss partial sums --------------
__global__ __launch_bounds__(256) void k2_peranchor(
    const float* __restrict__ pred,
    const float4* __restrict__ pbox4, const float4* __restrict__ meta4,
    const float* __restrict__ obja, const float* __restrict__ sobja,
    const float* __restrict__ S0a,
    const float* __restrict__ D, int use_d,
    const float* __restrict__ target,
    const float* __restrict__ rowmax, const unsigned long long* __restrict__ mask,
    float* __restrict__ acc)
{
  __shared__ float4 tb4[NT];
  __shared__ int    tcid[NT];
  __shared__ float  invm[NT];
  __shared__ float  tarea[NT];
  __shared__ float  sh_obj[4][64];
  __shared__ float  sh_c[4][64];
  __shared__ int    sh_tp[4][64];

  int i  = blockIdx.x / BPI;
  int b  = blockIdx.x % BPI;
  int c0 = b*APB;
  int q  = threadIdx.x & 63;
  int s  = threadIdx.x >> 6;
  int a  = c0 + q;
  const size_t BA = (size_t)NB*NA;

  for (int idx = threadIdx.x; idx < NT; idx += 256){
    const float* tg = target + (i*NT + idx)*6;
    tcid[idx] = (int)tg[1];
    float x1=tg[2], y1=tg[3], x2=tg[4], y2=tg[5];
    tb4[idx]   = make_float4(x1,y1,x2,y2);
    invm[idx]  = 1.0f / (rowmax[i*NT + idx] + 1e-8f);
    tarea[idx] = fmaxf(x2-x1,0.0f)*fmaxf(y2-y1,0.0f);
  }
  __syncthreads();

  bool valid = (a < NA);
  int gid = i*NA + a;
  float4 pb = valid ? pbox4[gid] : make_float4(0,0,0,0);
  float4 mt = valid ? meta4[gid] : make_float4(0,0,-1.0f,0);
  bool ib = valid && (mt.z > 0.0f);
  float rc = fabsf(mt.z);
  float px1=pb.x, py1=pb.y, px2=pb.z, py2=pb.w;
  float ap = fmaxf(px2-px1,0.0f)*fmaxf(py2-py1,0.0f);

  float best = 0.0f;
  if (ib){
    #pragma unroll 4
    for (int t = s*32; t < s*32+32; ++t){
      float4 T = tb4[t];
      float w = fminf(T.z,px2) - fmaxf(T.x,px1);
      float h = fminf(T.w,py2) - fmaxf(T.y,py1);
      w = fmaxf(w,0.0f); h = fmaxf(h,0.0f);
      float inter = w*h;
      float den = tarea[t] + ap - inter + 1e-8f;
      float iou = inter * __builtin_amdgcn_rcpf(den);
      best = fmaxf(best, iou*invm[t]);
    }
  }
  sh_obj[s][q] = best;

  unsigned long long m0=0, m1=0;
  if (valid){ m0 = mask[(size_t)gid*2]; m1 = mask[(size_t)gid*2+1]; }
  int cnt = __popcll(m0) + __popcll(m1);

  float bc = FLT_MAX; int bt = NT;
  if (cnt > 1){
    // selection path: identical helpers as k1 -> consistent cost values
    float sobj = use_d ? 0.0f : sobja[gid];
    float Sg = mt.w;
    for (int t = s*32; t < s*32+32; ++t){
      float4 T = tb4[t];
      float iou = ib ? pair_iou(T.x,T.y,T.z,T.w,px1,py1,px2,py2) : 0.0f;
      bool inb = (mt.x-T.x>0.0f)&&(mt.y-T.y>0.0f)&&(T.z-mt.x>0.0f)&&(T.w-mt.y>0.0f);
      float txc=(T.x+T.z)*0.5f, tyc=(T.y+T.w)*0.5f;
      bool inc = fmaxf(fabsf(mt.x-txc),fabsf(mt.y-tyc)) < rc;
      float dv = use_d ? D[(size_t)tcid[t]*BA + gid]
                       : dval_fn(sobj, pred[(size_t)gid*PDIM + 5 + tcid[t]]);
      float c = cost_from(Sg, dv, iou, inb&&inc, ib);
      if (c < bc){ bc = c; bt = t; }
    }
  }
  sh_c[s][q] = bc; sh_tp[s][q] = bt;
  __syncthreads();

  if (s == 0){
    float m=0.0f, vbox=0.0f, vobj=0.0f, vcls=0.0f;
    if (valid){
      float ob = fmaxf(fmaxf(sh_obj[0][q],sh_obj[1][q]), fmaxf(sh_obj[2][q],sh_obj[3][q]));
      float obj_t = ib ? fminf(fmaxf(ob,0.0f),1.0f) : 0.0f;
      vobj = bce_fast(obja[gid], obj_t);

      float cbest = sh_c[0][q]; int tbest = sh_tp[0][q];
      #pragma unroll
      for (int s2=1; s2<4; ++s2){
        float cs = sh_c[s2][q]; int ts = sh_tp[s2][q];
        if (cs < cbest){ cbest = cs; tbest = ts; }
      }

      int tp = 0; bool mpv = false;
      if (cnt > 1){ tp = tbest; mpv = true; }
      else if (cnt == 1){
        tp = m0 ? (__ffsll(m0)-1) : (64 + __ffsll(m1)-1);
        mpv = true;
      }

      if (mpv){
        m = 1.0f;
        float4 T = tb4[tp];
        float x1=T.x, y1=T.y, x2=T.z, y2=T.w;
        float w = fmaxf(fminf(px2,x2)-fmaxf(px1,x1),0.0f);
        float h = fmaxf(fminf(py2,y2)-fmaxf(py1,y1),0.0f);
        float inter = w*h;
        float wp=px2-px1, hp=py2-py1, wt=x2-x1, ht=y2-y1;
        float iou = inter/(wp*hp + wt*ht - inter + 1e-8f);
        float cw = fmaxf(px2,x2)-fminf(px1,x1);
        float ch = fmaxf(py2,y2)-fminf(py1,y1);
        float c2 = cw*cw + ch*ch + 1e-8f;
        float dx = (px1+px2)-(x1+x2), dy = (py1+py2)-(y1+y2);
        float rho2 = (dx*dx + dy*dy)/4.0f;
        float da = atanf(wt/(ht+1e-8f)) - atanf(wp/(hp+1e-8f));
        float v  = 0.4052847345693511f * da * da;   // 4/pi^2
        float alpha = v/(1.0f - iou + v + 1e-8f);
        vbox = 1.0f - (iou - rho2/c2 - alpha*v);

        int cc = tcid[tp];
        float xcc = pred[(size_t)gid*PDIM + 5 + cc];
        vcls = (S0a[gid] - xcc) * (1.0f/80.0f);   // sum_c bce(x_c, onehot) = S0 - x_cc
      }
    }

    #pragma unroll
    for (int off=32; off>0; off>>=1){
      m    += __shfl_down(m, off);
      vbox += __shfl_down(vbox, off);
      vobj += __shfl_down(vobj, off);
      vcls += __shfl_down(vcls, off);
    }
    if (q == 0){
      int slot = (blockIdx.x & 63)*4;
      atomicAdd(&acc[slot+0], m);
      atomicAdd(&acc[slot+1], vbox);
      atomicAdd(&acc[slot+2], vobj);
      atomicAdd(&acc[slot+3], vcls);
    }
  }
}

// ---------------- Kernel 3: finalize (reduce 64 accumulator slots) -----------
__global__ void k3_final(const float* __restrict__ acc, float* __restrict__ out){
  int l = threadIdx.x;   // 64 threads
  float4 v = ((const float4*)acc)[l];
  #pragma unroll
  for (int off=32; off>0; off>>=1){
    v.x += __shfl_down(v.x, off);
    v.y += __shfl_down(v.y, off);
    v.z += __shfl_down(v.z, off);
    v.w += __shfl_down(v.w, off);
  }
  if (l == 0){
    float n    = fmaxf(v.x, 1.0f);
    float lbox = 0.05f * v.y / n;
    float lobj = v.z / (float)(NB*NA);
    float lcls = 0.5f  * v.w / n;
    out[0] = lbox + lobj + lcls;
    out[1] = lbox; out[2] = lobj; out[3] = lcls;
  }
}

extern "C" void kernel_launch(void* const* d_in, const int* in_sizes, int n_in,
                              void* d_out, int out_size, void* d_ws, size_t ws_size,
                              hipStream_t stream) {
  const float* pred    = (const float*)d_in[0];
  const float* target  = (const float*)d_in[1];
  const float* grid    = (const float*)d_in[2];
  const float* stridev = (const float*)d_in[3];
  float* out = (float*)d_out;

  char* ws = (char*)d_ws;
  const size_t BA = (size_t)NB*NA;   // 134400

  size_t off = 0;
  unsigned long long* mask = (unsigned long long*)(ws + off); off += BA*16;
  float* acc    = (float*)(ws + off); off += 64*4*4;
  const size_t zero_bytes = off;      // mask + acc slots
  float4* pbox4 = (float4*)(ws + off); off += BA*16;
  float4* meta4 = (float4*)(ws + off); off += BA*16;
  float* obja   = (float*)(ws + off); off += BA*4;
  float* sobja  = (float*)(ws + off); off += BA*4;
  float* S0a    = (float*)(ws + off); off += BA*4;
  float* rowmax = (float*)(ws + off); off += (size_t)NB*NT*4;
  float* D      = (float*)(ws + off);
  const size_t need_d = off + (size_t)NCLS*BA*4;
  int use_d = (ws_size >= need_d) ? 1 : 0;

  hipMemsetAsync(d_ws, 0, zero_bytes, stream);

  k0_precompute<<<NB*BPI, 256, 0, stream>>>(pred, target, grid, stridev,
                                            pbox4, meta4, obja, sobja, S0a, D, use_d);
  k1_pertarget <<<NB*NT,  256, 0, stream>>>(pbox4, meta4, D, use_d,
                                            sobja, pred, target, rowmax, mask);
  k2_peranchor <<<NB*BPI, 256, 0, stream>>>(pred, pbox4, meta4, obja, sobja, S0a,
                                            D, use_d, target, rowmax, mask, acc);
  k3_final     <<<1, 64, 0, stream>>>(acc, out);
}

// Round 6
// 240.409 us; speedup vs baseline: 3.1295x; 1.0453x over previous
//
#include <hip/hip_runtime.h>
#include <cfloat>

#pragma clang fp contract(off)

#define NCLS 80
#define PDIM 85
#define NA   8400
#define NB   16
#define NT   128
#define NTOP 10
#define SLOT 11      // LDS stride for merge lists (odd -> free 2-way bank aliasing)
#define APB  64      // anchors per k0/k2 block
#define BPI  132     // ceil(NA/64)
#define LN2  0.6931471805599453f
#define CAP  2048    // compaction capacity (worst-case candidate count ~900)

// fast native sigmoid: rcp(1+exp(-x)). Value-path + stored-once selection inputs.
__device__ __forceinline__ float sigm_fast(float x){
  float e = __expf(-x);
  return __builtin_amdgcn_rcpf(1.0f + e);
}

// fast bce (value path only)
__device__ __forceinline__ float bce_fast(float x, float t){
  float ax = fabsf(x);
  float e  = __expf(-ax);
  return fmaxf(x,0.0f) - x*t + LN2*__builtin_amdgcn_logf(1.0f + e);
}

// Fast-rcp IoU. Used identically in k1 and k2 -> internally consistent.
__device__ __forceinline__ float pair_iou(float tx1,float ty1,float tx2,float ty2,
                                          float px1,float py1,float px2,float py2){
  float w = fminf(tx2,px2) - fmaxf(tx1,px1);
  float h = fminf(ty2,py2) - fmaxf(ty1,py1);
  w = fmaxf(w,0.0f); h = fmaxf(h,0.0f);
  float inter = w*h;
  float at = fmaxf(tx2-tx1,0.0f)*fmaxf(ty2-ty1,0.0f);
  float ap = fmaxf(px2-px1,0.0f)*fmaxf(py2-py1,0.0f);
  float den = at+ap-inter+1e-8f;
  return inter * __builtin_amdgcn_rcpf(den);
}

// dval fallback (use_d==0) — MUST match k0's D formula exactly.
__device__ __forceinline__ float dval_fn(float sobj, float lg){
  float sc = sigm_fast(lg);
  float u  = sobj*sc;
  float p  = sqrtf(u);
  float lp = fmaxf(0.5f*LN2*__builtin_amdgcn_logf(u), -100.0f);
  float l1 = fmaxf(LN2*__builtin_amdgcn_logf(fmaxf(1.0f - p, 0.0f)), -100.0f);
  return lp - l1;
}

// Selection-critical: identical in k1 top-k and k2 argmin (same inline, contract off).
__device__ __forceinline__ float cost_from(float S, float dval, float iou, bool ibc, bool ib){
  float iouc = -LN2 * __builtin_amdgcn_logf(iou + 1e-8f);
  float clsc = -(S + dval);
  float c = clsc + 3.0f*iouc;
  c = c + (ibc ? 0.0f : 100000.0f);
  c = c + (ib  ? 0.0f : 1000000000.0f);
  return c;
}

// sorted-insert helpers (branchless unrolled shift)
__device__ __forceinline__ void ins_iou(float* riou, float iou){
  if (iou > riou[NTOP-1]){
    #pragma unroll
    for (int j = NTOP-1; j >= 1; --j){
      bool gj  = iou > riou[j];
      bool gj1 = iou > riou[j-1];
      riou[j] = gj ? (gj1 ? riou[j-1] : iou) : riou[j];
    }
    riou[0] = (iou > riou[0]) ? iou : riou[0];
  }
}
__device__ __forceinline__ void ins_cost(float* rcst, int* ridx, float c, int a){
  bool ent = (c < rcst[NTOP-1]) || (c == rcst[NTOP-1] && a < ridx[NTOP-1]);
  if (ent){
    #pragma unroll
    for (int j = NTOP-1; j >= 1; --j){
      bool bj  = (c < rcst[j])   || (c == rcst[j]   && a < ridx[j]);
      bool bj1 = (c < rcst[j-1]) || (c == rcst[j-1] && a < ridx[j-1]);
      float nc = bj ? (bj1 ? rcst[j-1] : c) : rcst[j];
      int   ni = bj ? (bj1 ? ridx[j-1] : a) : ridx[j];
      rcst[j] = nc; ridx[j] = ni;
    }
    bool b0 = (c < rcst[0]) || (c == rcst[0] && a < ridx[0]);
    rcst[0] = b0 ? c : rcst[0];
    ridx[0] = b0 ? a : ridx[0];
  }
}

// ---------------- Kernel 0: transpose + per-anchor precompute ----------------
__global__ __launch_bounds__(256) void k0_precompute(
    const float* __restrict__ pred, const float* __restrict__ target,
    const float* __restrict__ grid, const float* __restrict__ stridev,
    float4* __restrict__ pbox4, float4* __restrict__ meta4,
    float* __restrict__ obja, float* __restrict__ sobja,
    float* __restrict__ S0a, float* __restrict__ D, int use_d)
{
  __shared__ float  tile[APB*PDIM];   // [a][c], stride 85 (odd -> conflict-free)
  __shared__ float4 tb4s[NT];
  __shared__ float  ps_s[4][APB];
  __shared__ float  ps0_s[4][APB];
  __shared__ int    ib_s[4][APB];

  int i  = blockIdx.x / BPI;
  int b  = blockIdx.x % BPI;
  int c0 = b*APB;
  int n  = NA - c0; if (n > APB) n = APB;
  int tid = threadIdx.x;

  const float* src = pred + ((size_t)i*NA + c0)*PDIM;
  int tot = n*PDIM;
  for (int idx = tid; idx < tot; idx += 256) tile[idx] = src[idx];
  for (int idx = tid; idx < NT; idx += 256){
    const float* tg = target + (i*NT + idx)*6;
    tb4s[idx] = make_float4(tg[2],tg[3],tg[4],tg[5]);
  }
  __syncthreads();

  int al = tid & 63, cg = tid >> 6;
  if (al < n){
    int gid = i*NA + c0 + al;
    float sobj = sigm_fast(tile[al*PDIM+4]);
    float ps = 0.0f, ps0 = 0.0f;
    #pragma unroll 4
    for (int k = 0; k < 20; ++k){
      int c = cg*20 + k;
      float x  = tile[al*PDIM+5+c];
      float sc = sigm_fast(x);
      float u  = sobj*sc;
      float p  = sqrtf(u);
      float lp = fmaxf(0.5f*LN2*__builtin_amdgcn_logf(u), -100.0f);
      float l1 = fmaxf(LN2*__builtin_amdgcn_logf(fmaxf(1.0f - p, 0.0f)), -100.0f);
      ps  += l1;
      if (use_d) D[(size_t)c*((size_t)NB*NA) + gid] = lp - l1;
      float e2 = __expf(-fabsf(x));
      ps0 += fmaxf(x,0.0f) + LN2*__builtin_amdgcn_logf(1.0f + e2);   // bce(x,0)
    }
    ps_s[cg][al] = ps; ps0_s[cg][al] = ps0;

    int ga = c0 + al;
    float xg = grid[2*ga], yg = grid[2*ga+1], sv = stridev[ga];
    float xc = (xg + 0.5f)*sv, yc = (yg + 0.5f)*sv;
    float rc = 2.5f*sv;
    bool ibp = false;
    #pragma unroll 4
    for (int t = cg*32; t < cg*32+32; ++t){
      float4 T = tb4s[t];
      bool inb = (xc-T.x>0.0f)&&(yc-T.y>0.0f)&&(T.z-xc>0.0f)&&(T.w-yc>0.0f);
      float txc=(T.x+T.z)*0.5f, tyc=(T.y+T.w)*0.5f;
      bool inc = fmaxf(fabsf(xc-txc),fabsf(yc-tyc)) < rc;
      ibp = ibp || inb || inc;
    }
    ib_s[cg][al] = ibp ? 1 : 0;
  }
  __syncthreads();

  if (tid < n){
    int a = tid;
    int gid = i*NA + c0 + a;
    float s  = ps_s[0][a]  + ps_s[1][a]  + ps_s[2][a]  + ps_s[3][a];
    float s0 = ps0_s[0][a] + ps0_s[1][a] + ps0_s[2][a] + ps0_s[3][a];
    bool ib  = (ib_s[0][a] | ib_s[1][a] | ib_s[2][a] | ib_s[3][a]) != 0;

    float x1 = tile[a*PDIM+0], y1 = tile[a*PDIM+1];
    float x2 = tile[a*PDIM+2], y2 = tile[a*PDIM+3];
    float ol = tile[a*PDIM+4];
    pbox4[gid] = make_float4(x1,y1,x2,y2);
    obja[gid]  = ol;
    sobja[gid] = sigm_fast(ol);
    S0a[gid]   = s0;

    int ga = c0 + a;
    float xg = grid[2*ga], yg = grid[2*ga+1], sv = stridev[ga];
    float xc = (xg + 0.5f)*sv, yc = (yg + 0.5f)*sv;
    float rc = 2.5f*sv;
    meta4[gid] = make_float4(xc, yc, ib ? rc : -rc, s);  // sign(z) = in_box
  }
}

// ------------- Kernel 1: per (image,target) compact -> top-k -> scatter ------
__global__ __launch_bounds__(256) void k1_pertarget(
    const float4* __restrict__ pbox4, const float4* __restrict__ meta4,
    const float* __restrict__ D, int use_d,
    const float* __restrict__ sobja, const float* __restrict__ pred,
    const float* __restrict__ target,
    float* __restrict__ rowmax, unsigned long long* __restrict__ mask)
{
  // union: phase1 compact buffers alias the merge-tree buffers (16896 B)
  __shared__ __align__(16) char smem[16896];
  __shared__ int sh_cnt, sh_cntibc, sh_dynk;
  int*   idxC = (int*)smem;            // [CAP]
  float* iouC = (float*)(smem + CAP*4);// [CAP]
  float* fI = (float*)smem;            // [128*SLOT]
  float* fC = (float*)(smem + 128*SLOT*4);
  int*   iB = (int*)  (smem + 128*SLOT*8);

  int i   = blockIdx.x / NT;
  int t   = blockIdx.x % NT;
  int tid = threadIdx.x;
  int lane = tid & 63;
  const size_t BA = (size_t)NB*NA;
  const float* m4f = (const float*)meta4;

  if (tid == 0){ sh_cnt = 0; sh_cntibc = 0; }

  const float* tg = target + (i*NT + t)*6;
  int   cid = (int)tg[1];
  float tx1 = tg[2], ty1 = tg[3], tx2 = tg[4], ty2 = tg[5];
  float txc = (tx1+tx2)*0.5f, tyc = (ty1+ty2)*0.5f;
  const float* Dc = use_d ? (D + (size_t)cid*BA) : nullptr;
  int iNA = i*NA;
  __syncthreads();

  // ---- phase 1: scan all anchors, compact candidates (iou>0 || ibc) ----
  for (int k = 0; k < 33; ++k){
    int a = tid + (k << 8);
    bool in = a < NA;
    float iou = 0.0f; bool ibc = false;
    if (in){
      float4 mt = meta4[iNA+a];
      if (mt.z > 0.0f){        // out-of-box: +1e9 penalty, never selected
        float4 pb = pbox4[iNA+a];
        iou = pair_iou(tx1,ty1,tx2,ty2, pb.x,pb.y,pb.z,pb.w);
        bool inb = (mt.x-tx1>0.0f)&&(mt.y-ty1>0.0f)&&(tx2-mt.x>0.0f)&&(ty2-mt.y>0.0f);
        bool inc = fmaxf(fabsf(mt.x-txc),fabsf(mt.y-tyc)) < mt.z;
        ibc = inb && inc;
      }
    }
    bool cand = (iou > 0.0f) || ibc;
    unsigned long long b  = __ballot(cand);
    unsigned long long b2 = __ballot(ibc);
    if (b){
      int base = 0;
      if (lane == 0){
        base = atomicAdd(&sh_cnt, __popcll(b));
        if (b2) atomicAdd(&sh_cntibc, __popcll(b2));
      }
      base = __shfl(base, 0);
      if (cand){
        int pos = base + __popcll(b & ((1ull << lane) - 1ull));
        if (pos < CAP){ idxC[pos] = a | (ibc ? (1<<15) : 0); iouC[pos] = iou; }
      }
    }
  }
  __syncthreads();

  int count = sh_cnt, cntibc = sh_cntibc;
  bool fastp = (count <= CAP) && (cntibc >= 16);

  float riou[NTOP]; float rcst[NTOP]; int ridx[NTOP];
  #pragma unroll
  for (int j=0;j<NTOP;++j){ riou[j]=0.0f; rcst[j]=FLT_MAX; ridx[j]=0x7fffffff; }

  if (fastp){
    // ---- phase 2: top-k only over compacted candidates ----
    for (int j = tid; j < count; j += 256){
      int pk = idxC[j];
      float iou = iouC[j];
      int a1 = pk & 0x7fff;
      bool ibc = (pk >> 15) != 0;
      ins_iou(riou, iou);
      int gid = iNA + a1;
      float S  = m4f[(size_t)gid*4 + 3];
      float dv = use_d ? Dc[gid] : dval_fn(sobja[gid], pred[(size_t)gid*PDIM + 5 + cid]);
      float c  = cost_from(S, dv, iou, ibc, true);
      ins_cost(rcst, ridx, c, a1);   // (c, idx) lexicographic -> order-independent
    }
  } else {
    // ---- exact fallback: full rescan with inserts (essentially never runs) ----
    for (int k = 0; k < 33; ++k){
      int a = tid + (k << 8);
      if (a >= NA) break;
      float4 mt = meta4[iNA+a];
      if (mt.z > 0.0f){
        float4 pb = pbox4[iNA+a];
        float iou = pair_iou(tx1,ty1,tx2,ty2, pb.x,pb.y,pb.z,pb.w);
        ins_iou(riou, iou);
        bool inb = (mt.x-tx1>0.0f)&&(mt.y-ty1>0.0f)&&(tx2-mt.x>0.0f)&&(ty2-mt.y>0.0f);
        bool inc = fmaxf(fabsf(mt.x-txc),fabsf(mt.y-tyc)) < mt.z;
        float dv = use_d ? Dc[iNA+a] : dval_fn(sobja[iNA+a], pred[(size_t)(iNA+a)*PDIM + 5 + cid]);
        float c = cost_from(mt.w, dv, iou, inb&&inc, true);
        ins_cost(rcst, ridx, c, a);
      }
    }
  }
  __syncthreads();   // compact buffers dead; merge buffers may now overwrite

  // ---- fused merge: fold 256 -> 128 in registers, then LDS tree ----
  if (tid >= 128){
    int base = (tid-128)*SLOT;
    #pragma unroll
    for (int j=0;j<NTOP;++j){ fI[base+j]=riou[j]; fC[base+j]=rcst[j]; iB[base+j]=ridx[j]; }
  }
  __syncthreads();
  if (tid < 128){
    int bB = tid*SLOT;
    {
      float ti[NTOP]; int ia=0, ib2=0;
      #pragma unroll
      for (int k=0;k<NTOP;++k){
        float va=riou[ia], vb=fI[bB+ib2];
        if (va >= vb){ ti[k]=va; ++ia; } else { ti[k]=vb; ++ib2; }
      }
      #pragma unroll
      for (int k=0;k<NTOP;++k) riou[k]=ti[k];
    }
    {
      float tc[NTOP]; int tx[NTOP]; int ia=0, ib2=0;
      #pragma unroll
      for (int k=0;k<NTOP;++k){
        float ca=rcst[ia], cb=fC[bB+ib2];
        int   xa=ridx[ia], xb=iB[bB+ib2];
        bool takeA = (ca < cb) || (ca == cb && xa <= xb);
        if (takeA){ tc[k]=ca; tx[k]=xa; ++ia; } else { tc[k]=cb; tx[k]=xb; ++ib2; }
      }
      #pragma unroll
      for (int k=0;k<NTOP;++k){ rcst[k]=tc[k]; ridx[k]=tx[k]; }
    }
    #pragma unroll
    for (int j=0;j<NTOP;++j){ fI[bB+j]=riou[j]; fC[bB+j]=rcst[j]; iB[bB+j]=ridx[j]; }
  }
  __syncthreads();

  for (int s2 = 64; s2 >= 1; s2 >>= 1){
    if (tid < s2){
      int bA = tid*SLOT, bB = (tid+s2)*SLOT;
      float ti[NTOP];
      { int ia=0, ib2=0;
        #pragma unroll
        for (int k=0;k<NTOP;++k){
          float va=fI[bA+ia], vb=fI[bB+ib2];
          if (va >= vb){ ti[k]=va; ++ia; } else { ti[k]=vb; ++ib2; }
        }
      }
      float tc[NTOP]; int tx[NTOP];
      { int ia=0, ib2=0;
        #pragma unroll
        for (int k=0;k<NTOP;++k){
          float ca=fC[bA+ia], cb=fC[bB+ib2];
          int   xa=iB[bA+ia], xb=iB[bB+ib2];
          bool takeA = (ca < cb) || (ca == cb && xa <= xb);
          if (takeA){ tc[k]=ca; tx[k]=xa; ++ia; } else { tc[k]=cb; tx[k]=xb; ++ib2; }
        }
      }
      #pragma unroll
      for (int k=0;k<NTOP;++k){ fI[bA+k]=ti[k]; fC[bA+k]=tc[k]; iB[bA+k]=tx[k]; }
    }
    __syncthreads();
  }

  if (tid == 0){
    rowmax[i*NT + t] = fI[0];
    float ssum = 0.0f;
    #pragma unroll
    for (int k=0;k<NTOP;++k) ssum += fI[k];   // descending, like jnp top_k sum
    int dk = (int)ssum;
    if (dk < 1) dk = 1;
    sh_dynk = dk;
  }
  __syncthreads();

  if (tid < NTOP){
    int a1 = iB[tid];
    if (tid < sh_dynk && a1 < NA && meta4[iNA + a1].z > 0.0f){
      atomicOr(&mask[(size_t)(iNA + a1)*2 + (t>>6)], 1ull << (t & 63));
    }
  }
}

// ---------- Kernel 2: per-anchor resolution + loss partial sums --------------
__global__ __launch_bounds__(256) void k2_peranchor(
    const float* __restrict__ pred,
    const float4* __restrict__ pbox4, const float4* __restrict__ meta4,
    const float* __restrict__ obja, const float* __restrict__ sobja,
    const float* __restrict__ S0a,
    const float* __restrict__ D, int use_d,
    const float* __restrict__ target,
    const float* __restrict__ rowmax, const unsigned long long* __restrict__ mask,
    float* __restrict__ acc)
{
  __shared__ float4 tb4[NT];
  __shared__ int    tcid[NT];
  __shared__ float  invm[NT];
  __shared__ float  tarea[NT];
  __shared__ float  sh_obj[4][64];
  __shared__ float  sh_c[4][64];
  __shared__ int    sh_tp[4][64];

  int i  = blockIdx.x / BPI;
  int b  = blockIdx.x % BPI;
  int c0 = b*APB;
  int q  = threadIdx.x & 63;
  int s  = threadIdx.x >> 6;
  int a  = c0 + q;
  const size_t BA = (size_t)NB*NA;

  for (int idx = threadIdx.x; idx < NT; idx += 256){
    const float* tg = target + (i*NT + idx)*6;
    tcid[idx] = (int)tg[1];
    float x1=tg[2], y1=tg[3], x2=tg[4], y2=tg[5];
    tb4[idx]   = make_float4(x1,y1,x2,y2);
    invm[idx]  = 1.0f / (rowmax[i*NT + idx] + 1e-8f);
    tarea[idx] = fmaxf(x2-x1,0.0f)*fmaxf(y2-y1,0.0f);
  }
  __syncthreads();

  bool valid = (a < NA);
  int gid = i*NA + a;
  float4 pb = valid ? pbox4[gid] : make_float4(0,0,0,0);
  float4 mt = valid ? meta4[gid] : make_float4(0,0,-1.0f,0);
  bool ib = valid && (mt.z > 0.0f);
  float rc = fabsf(mt.z);
  float px1=pb.x, py1=pb.y, px2=pb.z, py2=pb.w;
  float ap = fmaxf(px2-px1,0.0f)*fmaxf(py2-py1,0.0f);

  float best = 0.0f;
  if (ib){
    #pragma unroll 4
    for (int t = s*32; t < s*32+32; ++t){
      float4 T = tb4[t];
      float w = fminf(T.z,px2) - fmaxf(T.x,px1);
      float h = fminf(T.w,py2) - fmaxf(T.y,py1);
      w = fmaxf(w,0.0f); h = fmaxf(h,0.0f);
      float inter = w*h;
      float den = tarea[t] + ap - inter + 1e-8f;
      float iou = inter * __builtin_amdgcn_rcpf(den);
      best = fmaxf(best, iou*invm[t]);
    }
  }
  sh_obj[s][q] = best;

  unsigned long long m0=0, m1=0;
  if (valid){ m0 = mask[(size_t)gid*2]; m1 = mask[(size_t)gid*2+1]; }
  int cnt = __popcll(m0) + __popcll(m1);

  float bc = FLT_MAX; int bt = NT;
  if (cnt > 1){
    float sobj = use_d ? 0.0f : sobja[gid];
    float Sg = mt.w;
    for (int t = s*32; t < s*32+32; ++t){
      float4 T = tb4[t];
      float iou = ib ? pair_iou(T.x,T.y,T.z,T.w,px1,py1,px2,py2) : 0.0f;
      bool inb = (mt.x-T.x>0.0f)&&(mt.y-T.y>0.0f)&&(T.z-mt.x>0.0f)&&(T.w-mt.y>0.0f);
      float txc=(T.x+T.z)*0.5f, tyc=(T.y+T.w)*0.5f;
      bool inc = fmaxf(fabsf(mt.x-txc),fabsf(mt.y-tyc)) < rc;
      float dv = use_d ? D[(size_t)tcid[t]*BA + gid]
                       : dval_fn(sobj, pred[(size_t)gid*PDIM + 5 + tcid[t]]);
      float c = cost_from(Sg, dv, iou, inb&&inc, ib);
      if (c < bc){ bc = c; bt = t; }
    }
  }
  sh_c[s][q] = bc; sh_tp[s][q] = bt;
  __syncthreads();

  if (s == 0){
    float m=0.0f, vbox=0.0f, vobj=0.0f, vcls=0.0f;
    if (valid){
      float ob = fmaxf(fmaxf(sh_obj[0][q],sh_obj[1][q]), fmaxf(sh_obj[2][q],sh_obj[3][q]));
      float obj_t = ib ? fminf(fmaxf(ob,0.0f),1.0f) : 0.0f;
      vobj = bce_fast(obja[gid], obj_t);

      float cbest = sh_c[0][q]; int tbest = sh_tp[0][q];
      #pragma unroll
      for (int s2=1; s2<4; ++s2){
        float cs = sh_c[s2][q]; int ts = sh_tp[s2][q];
        if (cs < cbest){ cbest = cs; tbest = ts; }
      }

      int tp = 0; bool mpv = false;
      if (cnt > 1){ tp = tbest; mpv = true; }
      else if (cnt == 1){
        tp = m0 ? (__ffsll(m0)-1) : (64 + __ffsll(m1)-1);
        mpv = true;
      }

      if (mpv){
        m = 1.0f;
        float4 T = tb4[tp];
        float x1=T.x, y1=T.y, x2=T.z, y2=T.w;
        float w = fmaxf(fminf(px2,x2)-fmaxf(px1,x1),0.0f);
        float h = fmaxf(fminf(py2,y2)-fmaxf(py1,y1),0.0f);
        float inter = w*h;
        float wp=px2-px1, hp=py2-py1, wt=x2-x1, ht=y2-y1;
        float iou = inter/(wp*hp + wt*ht - inter + 1e-8f);
        float cw = fmaxf(px2,x2)-fminf(px1,x1);
        float ch = fmaxf(py2,y2)-fminf(py1,y1);
        float c2 = cw*cw + ch*ch + 1e-8f;
        float dx = (px1+px2)-(x1+x2), dy = (py1+py2)-(y1+y2);
        float rho2 = (dx*dx + dy*dy)/4.0f;
        float da = atanf(wt/(ht+1e-8f)) - atanf(wp/(hp+1e-8f));
        float v  = 0.4052847345693511f * da * da;   // 4/pi^2
        float alpha = v/(1.0f - iou + v + 1e-8f);
        vbox = 1.0f - (iou - rho2/c2 - alpha*v);

        int cc = tcid[tp];
        float xcc = pred[(size_t)gid*PDIM + 5 + cc];
        vcls = (S0a[gid] - xcc) * (1.0f/80.0f);   // sum_c bce(x_c, onehot) = S0 - x_cc
      }
    }

    #pragma unroll
    for (int off=32; off>0; off>>=1){
      m    += __shfl_down(m, off);
      vbox += __shfl_down(vbox, off);
      vobj += __shfl_down(vobj, off);
      vcls += __shfl_down(vcls, off);
    }
    if (q == 0){
      int slot = (blockIdx.x & 63)*4;
      atomicAdd(&acc[slot+0], m);
      atomicAdd(&acc[slot+1], vbox);
      atomicAdd(&acc[slot+2], vobj);
      atomicAdd(&acc[slot+3], vcls);
    }
  }
}

// ---------------- Kernel 3: finalize (reduce 64 accumulator slots) -----------
__global__ void k3_final(const float* __restrict__ acc, float* __restrict__ out){
  int l = threadIdx.x;   // 64 threads
  float4 v = ((const float4*)acc)[l];
  #pragma unroll
  for (int off=32; off>0; off>>=1){
    v.x += __shfl_down(v.x, off);
    v.y += __shfl_down(v.y, off);
    v.z += __shfl_down(v.z, off);
    v.w += __shfl_down(v.w, off);
  }
  if (l == 0){
    float n    = fmaxf(v.x, 1.0f);
    float lbox = 0.05f * v.y / n;
    float lobj = v.z / (float)(NB*NA);
    float lcls = 0.5f  * v.w / n;
    out[0] = lbox + lobj + lcls;
    out[1] = lbox; out[2] = lobj; out[3] = lcls;
  }
}

extern "C" void kernel_launch(void* const* d_in, const int* in_sizes, int n_in,
                              void* d_out, int out_size, void* d_ws, size_t ws_size,
                              hipStream_t stream) {
  const float* pred    = (const float*)d_in[0];
  const float* target  = (const float*)d_in[1];
  const float* grid    = (const float*)d_in[2];
  const float* stridev = (const float*)d_in[3];
  float* out = (float*)d_out;

  char* ws = (char*)d_ws;
  const size_t BA = (size_t)NB*NA;   // 134400

  size_t off = 0;
  unsigned long long* mask = (unsigned long long*)(ws + off); off += BA*16;
  float* acc    = (float*)(ws + off); off += 64*4*4;
  const size_t zero_bytes = off;      // mask + acc slots
  float4* pbox4 = (float4*)(ws + off); off += BA*16;
  float4* meta4 = (float4*)(ws + off); off += BA*16;
  float* obja   = (float*)(ws + off); off += BA*4;
  float* sobja  = (float*)(ws + off); off += BA*4;
  float* S0a    = (float*)(ws + off); off += BA*4;
  float* rowmax = (float*)(ws + off); off += (size_t)NB*NT*4;
  float* D      = (float*)(ws + off);
  const size_t need_d = off + (size_t)NCLS*BA*4;
  int use_d = (ws_size >= need_d) ? 1 : 0;

  hipMemsetAsync(d_ws, 0, zero_bytes, stream);

  k0_precompute<<<NB*BPI, 256, 0, stream>>>(pred, target, grid, stridev,
                                            pbox4, meta4, obja, sobja, S0a, D, use_d);
  k1_pertarget <<<NB*NT,  256, 0, stream>>>(pbox4, meta4, D, use_d,
                                            sobja, pred, target, rowmax, mask);
  k2_peranchor <<<NB*BPI, 256, 0, stream>>>(pred, pbox4, meta4, obja, sobja, S0a,
                                            D, use_d, target, rowmax, mask, acc);
  k3_final     <<<1, 64, 0, stream>>>(acc, out);
}

// Round 7
// 207.435 us; speedup vs baseline: 3.6270x; 1.1590x over previous
//
#include <hip/hip_runtime.h>
#include <cfloat>

#pragma clang fp contract(off)

#define NCLS 80
#define PDIM 85
#define NA   8400
#define NB   16
#define NT   128
#define NTOP 10
#define SLOT 11      // LDS stride for merge lists (odd -> free 2-way bank aliasing)
#define APB  64      // anchors per k0/k2 block
#define BPI  132     // ceil(NA/64)
#define LN2  0.6931471805599453f
#define CAPW 512     // per-wave compaction capacity (typ ~100-150/wave)

// fast native sigmoid: rcp(1+exp(-x)). Value-path + stored-once selection inputs.
__device__ __forceinline__ float sigm_fast(float x){
  float e = __expf(-x);
  return __builtin_amdgcn_rcpf(1.0f + e);
}

// fast bce (value path only)
__device__ __forceinline__ float bce_fast(float x, float t){
  float ax = fabsf(x);
  float e  = __expf(-ax);
  return fmaxf(x,0.0f) - x*t + LN2*__builtin_amdgcn_logf(1.0f + e);
}

// Fast-rcp IoU. Used identically in k1 and k2 -> internally consistent.
__device__ __forceinline__ float pair_iou(float tx1,float ty1,float tx2,float ty2,
                                          float px1,float py1,float px2,float py2){
  float w = fminf(tx2,px2) - fmaxf(tx1,px1);
  float h = fminf(ty2,py2) - fmaxf(ty1,py1);
  w = fmaxf(w,0.0f); h = fmaxf(h,0.0f);
  float inter = w*h;
  float at = fmaxf(tx2-tx1,0.0f)*fmaxf(ty2-ty1,0.0f);
  float ap = fmaxf(px2-px1,0.0f)*fmaxf(py2-py1,0.0f);
  float den = at+ap-inter+1e-8f;
  return inter * __builtin_amdgcn_rcpf(den);
}

// dval fallback (use_d==0) — MUST match k0's D formula exactly.
__device__ __forceinline__ float dval_fn(float sobj, float lg){
  float sc = sigm_fast(lg);
  float u  = sobj*sc;
  float p  = sqrtf(u);
  float lp = fmaxf(0.5f*LN2*__builtin_amdgcn_logf(u), -100.0f);
  float l1 = fmaxf(LN2*__builtin_amdgcn_logf(fmaxf(1.0f - p, 0.0f)), -100.0f);
  return lp - l1;
}

// Selection-critical: identical in k1 top-k and k2 argmin (same inline, contract off).
__device__ __forceinline__ float cost_from(float S, float dval, float iou, bool ibc, bool ib){
  float iouc = -LN2 * __builtin_amdgcn_logf(iou + 1e-8f);
  float clsc = -(S + dval);
  float c = clsc + 3.0f*iouc;
  c = c + (ibc ? 0.0f : 100000.0f);
  c = c + (ib  ? 0.0f : 1000000000.0f);
  return c;
}

// sorted-insert helpers (branchless unrolled shift)
__device__ __forceinline__ void ins_iou(float* riou, float iou){
  if (iou > riou[NTOP-1]){
    #pragma unroll
    for (int j = NTOP-1; j >= 1; --j){
      bool gj  = iou > riou[j];
      bool gj1 = iou > riou[j-1];
      riou[j] = gj ? (gj1 ? riou[j-1] : iou) : riou[j];
    }
    riou[0] = (iou > riou[0]) ? iou : riou[0];
  }
}
__device__ __forceinline__ void ins_cost(float* rcst, int* ridx, float c, int a){
  bool ent = (c < rcst[NTOP-1]) || (c == rcst[NTOP-1] && a < ridx[NTOP-1]);
  if (ent){
    #pragma unroll
    for (int j = NTOP-1; j >= 1; --j){
      bool bj  = (c < rcst[j])   || (c == rcst[j]   && a < ridx[j]);
      bool bj1 = (c < rcst[j-1]) || (c == rcst[j-1] && a < ridx[j-1]);
      float nc = bj ? (bj1 ? rcst[j-1] : c) : rcst[j];
      int   ni = bj ? (bj1 ? ridx[j-1] : a) : ridx[j];
      rcst[j] = nc; ridx[j] = ni;
    }
    bool b0 = (c < rcst[0]) || (c == rcst[0] && a < ridx[0]);
    rcst[0] = b0 ? c : rcst[0];
    ridx[0] = b0 ? a : ridx[0];
  }
}

// ---------------- Kernel 0: transpose + per-anchor precompute ----------------
__global__ __launch_bounds__(256) void k0_precompute(
    const float* __restrict__ pred, const float* __restrict__ target,
    const float* __restrict__ grid, const float* __restrict__ stridev,
    float4* __restrict__ pbox4, float4* __restrict__ meta4,
    float* __restrict__ obja, float* __restrict__ sobja,
    float* __restrict__ S0a, float* __restrict__ D, int use_d)
{
  __shared__ float  tile[APB*PDIM];   // [a][c], stride 85 (odd -> conflict-free)
  __shared__ float4 tb4s[NT];
  __shared__ float  ps_s[4][APB];
  __shared__ float  ps0_s[4][APB];
  __shared__ int    ib_s[4][APB];

  int i  = blockIdx.x / BPI;
  int b  = blockIdx.x % BPI;
  int c0 = b*APB;
  int n  = NA - c0; if (n > APB) n = APB;
  int tid = threadIdx.x;

  const float* src = pred + ((size_t)i*NA + c0)*PDIM;
  int tot = n*PDIM;
  for (int idx = tid; idx < tot; idx += 256) tile[idx] = src[idx];
  for (int idx = tid; idx < NT; idx += 256){
    const float* tg = target + (i*NT + idx)*6;
    tb4s[idx] = make_float4(tg[2],tg[3],tg[4],tg[5]);
  }
  __syncthreads();

  int al = tid & 63, cg = tid >> 6;
  if (al < n){
    int gid = i*NA + c0 + al;
    float sobj = sigm_fast(tile[al*PDIM+4]);
    float ps = 0.0f, ps0 = 0.0f;
    #pragma unroll 4
    for (int k = 0; k < 20; ++k){
      int c = cg*20 + k;
      float x  = tile[al*PDIM+5+c];
      float sc = sigm_fast(x);
      float u  = sobj*sc;
      float p  = sqrtf(u);
      float lp = fmaxf(0.5f*LN2*__builtin_amdgcn_logf(u), -100.0f);
      float l1 = fmaxf(LN2*__builtin_amdgcn_logf(fmaxf(1.0f - p, 0.0f)), -100.0f);
      ps  += l1;
      if (use_d) D[(size_t)c*((size_t)NB*NA) + gid] = lp - l1;
      float e2 = __expf(-fabsf(x));
      ps0 += fmaxf(x,0.0f) + LN2*__builtin_amdgcn_logf(1.0f + e2);   // bce(x,0)
    }
    ps_s[cg][al] = ps; ps0_s[cg][al] = ps0;

    int ga = c0 + al;
    float xg = grid[2*ga], yg = grid[2*ga+1], sv = stridev[ga];
    float xc = (xg + 0.5f)*sv, yc = (yg + 0.5f)*sv;
    float rc = 2.5f*sv;
    bool ibp = false;
    #pragma unroll 4
    for (int t = cg*32; t < cg*32+32; ++t){
      float4 T = tb4s[t];
      bool inb = (xc-T.x>0.0f)&&(yc-T.y>0.0f)&&(T.z-xc>0.0f)&&(T.w-yc>0.0f);
      float txc=(T.x+T.z)*0.5f, tyc=(T.y+T.w)*0.5f;
      bool inc = fmaxf(fabsf(xc-txc),fabsf(yc-tyc)) < rc;
      ibp = ibp || inb || inc;
    }
    ib_s[cg][al] = ibp ? 1 : 0;
  }
  __syncthreads();

  if (tid < n){
    int a = tid;
    int gid = i*NA + c0 + a;
    float s  = ps_s[0][a]  + ps_s[1][a]  + ps_s[2][a]  + ps_s[3][a];
    float s0 = ps0_s[0][a] + ps0_s[1][a] + ps0_s[2][a] + ps0_s[3][a];
    bool ib  = (ib_s[0][a] | ib_s[1][a] | ib_s[2][a] | ib_s[3][a]) != 0;

    float x1 = tile[a*PDIM+0], y1 = tile[a*PDIM+1];
    float x2 = tile[a*PDIM+2], y2 = tile[a*PDIM+3];
    float ol = tile[a*PDIM+4];
    pbox4[gid] = make_float4(x1,y1,x2,y2);
    obja[gid]  = ol;
    sobja[gid] = sigm_fast(ol);
    S0a[gid]   = s0;

    int ga = c0 + a;
    float xg = grid[2*ga], yg = grid[2*ga+1], sv = stridev[ga];
    float xc = (xg + 0.5f)*sv, yc = (yg + 0.5f)*sv;
    float rc = 2.5f*sv;
    meta4[gid] = make_float4(xc, yc, ib ? rc : -rc, s);  // sign(z) = in_box
  }
}

// ------------- Kernel 1: per-target scan/compact (4 waves) -> wave-0 top-k ---
__global__ __launch_bounds__(256) void k1_pertarget(
    const float4* __restrict__ pbox4, const float4* __restrict__ meta4,
    const float* __restrict__ D, int use_d,
    const float* __restrict__ sobja, const float* __restrict__ pred,
    const float* __restrict__ target,
    float* __restrict__ rowmax, unsigned long long* __restrict__ mask)
{
  __shared__ __align__(16) int2 seg[4][CAPW];   // 16 KB; merge bufs alias this
  __shared__ int cnts[4], cibc[4];

  int i   = blockIdx.x / NT;
  int t   = blockIdx.x % NT;
  int tid = threadIdx.x;
  int lane = tid & 63, w = tid >> 6;
  const size_t BA = (size_t)NB*NA;
  const float* m4f = (const float*)meta4;

  const float* tg = target + (i*NT + t)*6;
  int   cid = (int)tg[1];
  float tx1 = tg[2], ty1 = tg[3], tx2 = tg[4], ty2 = tg[5];
  float txc = (tx1+tx2)*0.5f, tyc = (ty1+ty2)*0.5f;
  const float* Dc = use_d ? (D + (size_t)cid*BA) : nullptr;
  int iNA = i*NA;

  // ---- phase 1: prefetched scan, per-wave scalar-counter compaction ----
  int cnt = 0, ci = 0;
  int a = tid;
  float4 pb = pbox4[iNA+a];
  float4 mt = meta4[iNA+a];
  for (int k = 0; k < 33; ++k){
    int a2 = a + 256;
    int ld = (a2 < NA) ? a2 : a;
    float4 pb_n = pbox4[iNA+ld];
    float4 mt_n = meta4[iNA+ld];

    bool in = a < NA;
    float iou = 0.0f; bool ibc = false;
    if (in && mt.z > 0.0f){    // out-of-box: +1e9 penalty, never selected
      iou = pair_iou(tx1,ty1,tx2,ty2, pb.x,pb.y,pb.z,pb.w);
      bool inb = (mt.x-tx1>0.0f)&&(mt.y-ty1>0.0f)&&(tx2-mt.x>0.0f)&&(ty2-mt.y>0.0f);
      bool inc = fmaxf(fabsf(mt.x-txc),fabsf(mt.y-tyc)) < mt.z;
      ibc = inb && inc;
    }
    bool cand = (iou > 0.0f) || ibc;
    unsigned long long b  = __ballot(cand);
    unsigned long long b2 = __ballot(ibc);
    if (cand){
      int pos = cnt + __popcll(b & ((1ull << lane) - 1ull));
      if (pos < CAPW) seg[w][pos] = make_int2(a | (ibc ? (1<<15) : 0), __float_as_int(iou));
    }
    cnt += __popcll(b);       // uniform -> stays scalar
    ci  += __popcll(b2);

    pb = pb_n; mt = mt_n; a = a2;
  }
  if (lane == 0){ cnts[w] = cnt; cibc[w] = ci; }
  __syncthreads();
  if (w != 0) return;          // waves 1-3 free their SIMD slots

  // ---- wave 0: phase 2 over compacted candidates ----
  int total_ibc = cibc[0]+cibc[1]+cibc[2]+cibc[3];
  bool ovf = (cnts[0]>CAPW)||(cnts[1]>CAPW)||(cnts[2]>CAPW)||(cnts[3]>CAPW);
  bool fastp = !ovf && (total_ibc >= 16);

  float riou[NTOP]; float rcst[NTOP]; int ridx[NTOP];
  #pragma unroll
  for (int j=0;j<NTOP;++j){ riou[j]=0.0f; rcst[j]=FLT_MAX; ridx[j]=0x7fffffff; }

  if (fastp){
    for (int s = 0; s < 4; ++s){
      int cw = cnts[s];
      for (int j = lane; j < cw; j += 64){
        int2 e = seg[s][j];
        int a1 = e.x & 0x7fff;
        bool ibc = (e.x >> 15) != 0;
        float iou = __int_as_float(e.y);
        ins_iou(riou, iou);
        int gid = iNA + a1;
        float S  = m4f[(size_t)gid*4 + 3];
        float dv = use_d ? Dc[gid] : dval_fn(sobja[gid], pred[(size_t)gid*PDIM + 5 + cid]);
        float c  = cost_from(S, dv, iou, ibc, true);
        ins_cost(rcst, ridx, c, a1);   // (c, idx) lexicographic -> order-independent
      }
    }
  } else {
    // exact fallback: full rescan on wave 0 (essentially never runs)
    for (int a1 = lane; a1 < NA; a1 += 64){
      float4 mt2 = meta4[iNA+a1];
      if (mt2.z > 0.0f){
        float4 pb2 = pbox4[iNA+a1];
        float iou = pair_iou(tx1,ty1,tx2,ty2, pb2.x,pb2.y,pb2.z,pb2.w);
        ins_iou(riou, iou);
        bool inb = (mt2.x-tx1>0.0f)&&(mt2.y-ty1>0.0f)&&(tx2-mt2.x>0.0f)&&(ty2-mt2.y>0.0f);
        bool inc = fmaxf(fabsf(mt2.x-txc),fabsf(mt2.y-tyc)) < mt2.z;
        float dv = use_d ? Dc[iNA+a1] : dval_fn(sobja[iNA+a1], pred[(size_t)(iNA+a1)*PDIM + 5 + cid]);
        float c = cost_from(mt2.w, dv, iou, inb&&inc, true);
        ins_cost(rcst, ridx, c, a1);
      }
    }
  }

  // ---- intra-wave 6-level LDS merge (no __syncthreads; wave-synchronous) ----
  char* sm = (char*)&seg[0][0];           // compact buffers dead past this point
  float* fI = (float*)sm;                 // [64*SLOT]
  float* fC = (float*)(sm + 64*SLOT*4);
  int*   iB = (int*)  (sm + 64*SLOT*8);
  {
    int base = lane*SLOT;
    #pragma unroll
    for (int j=0;j<NTOP;++j){ fI[base+j]=riou[j]; fC[base+j]=rcst[j]; iB[base+j]=ridx[j]; }
  }
  __builtin_amdgcn_wave_barrier();

  for (int s2 = 32; s2 >= 1; s2 >>= 1){
    if (lane < s2){
      int bA = lane*SLOT, bB = (lane+s2)*SLOT;
      float ti[NTOP];
      { int ia=0, ib2=0;
        #pragma unroll
        for (int k=0;k<NTOP;++k){
          float va=fI[bA+ia], vb=fI[bB+ib2];
          if (va >= vb){ ti[k]=va; ++ia; } else { ti[k]=vb; ++ib2; }
        }
      }
      float tc[NTOP]; int tx[NTOP];
      { int ia=0, ib2=0;
        #pragma unroll
        for (int k=0;k<NTOP;++k){
          float ca=fC[bA+ia], cb=fC[bB+ib2];
          int   xa=iB[bA+ia], xb=iB[bB+ib2];
          bool takeA = (ca < cb) || (ca == cb && xa <= xb);
          if (takeA){ tc[k]=ca; tx[k]=xa; ++ia; } else { tc[k]=cb; tx[k]=xb; ++ib2; }
        }
      }
      #pragma unroll
      for (int k=0;k<NTOP;++k){ fI[bA+k]=ti[k]; fC[bA+k]=tc[k]; iB[bA+k]=tx[k]; }
    }
    __builtin_amdgcn_wave_barrier();
  }

  // ---- tail: rowmax, dyn_k, scatter (wave 0 only, no barriers) ----
  float ssum = 0.0f;
  #pragma unroll
  for (int k=0;k<NTOP;++k) ssum += fI[k];   // descending, like jnp top_k sum
  int dk = (int)ssum;
  if (dk < 1) dk = 1;

  if (lane == 0) rowmax[i*NT + t] = fI[0];
  if (lane < NTOP){
    int a1 = iB[lane];
    if (lane < dk && a1 < NA && meta4[iNA + a1].z > 0.0f){
      atomicOr(&mask[(size_t)(iNA + a1)*2 + (t>>6)], 1ull << (t & 63));
    }
  }
}

// ---------- Kernel 2: per-anchor resolution + loss partial sums --------------
__global__ __launch_bounds__(256) void k2_peranchor(
    const float* __restrict__ pred,
    const float4* __restrict__ pbox4, const float4* __restrict__ meta4,
    const float* __restrict__ obja, const float* __restrict__ sobja,
    const float* __restrict__ S0a,
    const float* __restrict__ D, int use_d,
    const float* __restrict__ target,
    const float* __restrict__ rowmax, const unsigned long long* __restrict__ mask,
    float* __restrict__ acc)
{
  __shared__ float4 tb4[NT];
  __shared__ int    tcid[NT];
  __shared__ float  invm[NT];
  __shared__ float  tarea[NT];
  __shared__ float  sh_obj[4][64];
  __shared__ float  sh_c[4][64];
  __shared__ int    sh_tp[4][64];

  int i  = blockIdx.x / BPI;
  int b  = blockIdx.x % BPI;
  int c0 = b*APB;
  int q  = threadIdx.x & 63;
  int s  = threadIdx.x >> 6;
  int a  = c0 + q;
  const size_t BA = (size_t)NB*NA;

  for (int idx = threadIdx.x; idx < NT; idx += 256){
    const float* tg = target + (i*NT + idx)*6;
    tcid[idx] = (int)tg[1];
    float x1=tg[2], y1=tg[3], x2=tg[4], y2=tg[5];
    tb4[idx]   = make_float4(x1,y1,x2,y2);
    invm[idx]  = 1.0f / (rowmax[i*NT + idx] + 1e-8f);
    tarea[idx] = fmaxf(x2-x1,0.0f)*fmaxf(y2-y1,0.0f);
  }
  __syncthreads();

  bool valid = (a < NA);
  int gid = i*NA + a;
  float4 pb = valid ? pbox4[gid] : make_float4(0,0,0,0);
  float4 mt = valid ? meta4[gid] : make_float4(0,0,-1.0f,0);
  bool ib = valid && (mt.z > 0.0f);
  float rc = fabsf(mt.z);
  float px1=pb.x, py1=pb.y, px2=pb.z, py2=pb.w;
  float ap = fmaxf(px2-px1,0.0f)*fmaxf(py2-py1,0.0f);

  float best = 0.0f;
  if (ib){
    #pragma unroll 4
    for (int t = s*32; t < s*32+32; ++t){
      float4 T = tb4[t];
      float w = fminf(T.z,px2) - fmaxf(T.x,px1);
      float h = fminf(T.w,py2) - fmaxf(T.y,py1);
      w = fmaxf(w,0.0f); h = fmaxf(h,0.0f);
      float inter = w*h;
      float den = tarea[t] + ap - inter + 1e-8f;
      float iou = inter * __builtin_amdgcn_rcpf(den);
      best = fmaxf(best, iou*invm[t]);
    }
  }
  sh_obj[s][q] = best;

  unsigned long long m0=0, m1=0;
  if (valid){ m0 = mask[(size_t)gid*2]; m1 = mask[(size_t)gid*2+1]; }
  int cnt = __popcll(m0) + __popcll(m1);

  float bc = FLT_MAX; int bt = NT;
  if (cnt > 1){
    float sobj = use_d ? 0.0f : sobja[gid];
    float Sg = mt.w;
    for (int t = s*32; t < s*32+32; ++t){
      float4 T = tb4[t];
      float iou = ib ? pair_iou(T.x,T.y,T.z,T.w,px1,py1,px2,py2) : 0.0f;
      bool inb = (mt.x-T.x>0.0f)&&(mt.y-T.y>0.0f)&&(T.z-mt.x>0.0f)&&(T.w-mt.y>0.0f);
      float txc=(T.x+T.z)*0.5f, tyc=(T.y+T.w)*0.5f;
      bool inc = fmaxf(fabsf(mt.x-txc),fabsf(mt.y-tyc)) < rc;
      float dv = use_d ? D[(size_t)tcid[t]*BA + gid]
                       : dval_fn(sobj, pred[(size_t)gid*PDIM + 5 + tcid[t]]);
      float c = cost_from(Sg, dv, iou, inb&&inc, ib);
      if (c < bc){ bc = c; bt = t; }
    }
  }
  sh_c[s][q] = bc; sh_tp[s][q] = bt;
  __syncthreads();

  if (s == 0){
    float m=0.0f, vbox=0.0f, vobj=0.0f, vcls=0.0f;
    if (valid){
      float ob = fmaxf(fmaxf(sh_obj[0][q],sh_obj[1][q]), fmaxf(sh_obj[2][q],sh_obj[3][q]));
      float obj_t = ib ? fminf(fmaxf(ob,0.0f),1.0f) : 0.0f;
      vobj = bce_fast(obja[gid], obj_t);

      float cbest = sh_c[0][q]; int tbest = sh_tp[0][q];
      #pragma unroll
      for (int s2=1; s2<4; ++s2){
        float cs = sh_c[s2][q]; int ts = sh_tp[s2][q];
        if (cs < cbest){ cbest = cs; tbest = ts; }
      }

      int tp = 0; bool mpv = false;
      if (cnt > 1){ tp = tbest; mpv = true; }
      else if (cnt == 1){
        tp = m0 ? (__ffsll(m0)-1) : (64 + __ffsll(m1)-1);
        mpv = true;
      }

      if (mpv){
        m = 1.0f;
        float4 T = tb4[tp];
        float x1=T.x, y1=T.y, x2=T.z, y2=T.w;
        float w = fmaxf(fminf(px2,x2)-fmaxf(px1,x1),0.0f);
        float h = fmaxf(fminf(py2,y2)-fmaxf(py1,y1),0.0f);
        float inter = w*h;
        float wp=px2-px1, hp=py2-py1, wt=x2-x1, ht=y2-y1;
        float iou = inter/(wp*hp + wt*ht - inter + 1e-8f);
        float cw = fmaxf(px2,x2)-fminf(px1,x1);
        float ch = fmaxf(py2,y2)-fminf(py1,y1);
        float c2 = cw*cw + ch*ch + 1e-8f;
        float dx = (px1+px2)-(x1+x2), dy = (py1+py2)-(y1+y2);
        float rho2 = (dx*dx + dy*dy)/4.0f;
        float da = atanf(wt/(ht+1e-8f)) - atanf(wp/(hp+1e-8f));
        float v  = 0.4052847345693511f * da * da;   // 4/pi^2
        float alpha = v/(1.0f - iou + v + 1e-8f);
        vbox = 1.0f - (iou - rho2/c2 - alpha*v);

        int cc = tcid[tp];
        float xcc = pred[(size_t)gid*PDIM + 5 + cc];
        vcls = (S0a[gid] - xcc) * (1.0f/80.0f);   // sum_c bce(x_c, onehot) = S0 - x_cc
      }
    }

    #pragma unroll
    for (int off=32; off>0; off>>=1){
      m    += __shfl_down(m, off);
      vbox += __shfl_down(vbox, off);
      vobj += __shfl_down(vobj, off);
      vcls += __shfl_down(vcls, off);
    }
    if (q == 0){
      int slot = (blockIdx.x & 63)*4;
      atomicAdd(&acc[slot+0], m);
      atomicAdd(&acc[slot+1], vbox);
      atomicAdd(&acc[slot+2], vobj);
      atomicAdd(&acc[slot+3], vcls);
    }
  }
}

// ---------------- Kernel 3: finalize (reduce 64 accumulator slots) -----------
__global__ void k3_final(const float* __restrict__ acc, float* __restrict__ out){
  int l = threadIdx.x;   // 64 threads
  float4 v = ((const float4*)acc)[l];
  #pragma unroll
  for (int off=32; off>0; off>>=1){
    v.x += __shfl_down(v.x, off);
    v.y += __shfl_down(v.y, off);
    v.z += __shfl_down(v.z, off);
    v.w += __shfl_down(v.w, off);
  }
  if (l == 0){
    float n    = fmaxf(v.x, 1.0f);
    float lbox = 0.05f * v.y / n;
    float lobj = v.z / (float)(NB*NA);
    float lcls = 0.5f  * v.w / n;
    out[0] = lbox + lobj + lcls;
    out[1] = lbox; out[2] = lobj; out[3] = lcls;
  }
}

extern "C" void kernel_launch(void* const* d_in, const int* in_sizes, int n_in,
                              void* d_out, int out_size, void* d_ws, size_t ws_size,
                              hipStream_t stream) {
  const float* pred    = (const float*)d_in[0];
  const float* target  = (const float*)d_in[1];
  const float* grid    = (const float*)d_in[2];
  const float* stridev = (const float*)d_in[3];
  float* out = (float*)d_out;

  char* ws = (char*)d_ws;
  const size_t BA = (size_t)NB*NA;   // 134400

  size_t off = 0;
  unsigned long long* mask = (unsigned long long*)(ws + off); off += BA*16;
  float* acc    = (float*)(ws + off); off += 64*4*4;
  const size_t zero_bytes = off;      // mask + acc slots
  float4* pbox4 = (float4*)(ws + off); off += BA*16;
  float4* meta4 = (float4*)(ws + off); off += BA*16;
  float* obja   = (float*)(ws + off); off += BA*4;
  float* sobja  = (float*)(ws + off); off += BA*4;
  float* S0a    = (float*)(ws + off); off += BA*4;
  float* rowmax = (float*)(ws + off); off += (size_t)NB*NT*4;
  float* D      = (float*)(ws + off);
  const size_t need_d = off + (size_t)NCLS*BA*4;
  int use_d = (ws_size >= need_d) ? 1 : 0;

  hipMemsetAsync(d_ws, 0, zero_bytes, stream);

  k0_precompute<<<NB*BPI, 256, 0, stream>>>(pred, target, grid, stridev,
                                            pbox4, meta4, obja, sobja, S0a, D, use_d);
  k1_pertarget <<<NB*NT,  256, 0, stream>>>(pbox4, meta4, D, use_d,
                                            sobja, pred, target, rowmax, mask);
  k2_peranchor <<<NB*BPI, 256, 0, stream>>>(pred, pbox4, meta4, obja, sobja, S0a,
                                            D, use_d, target, rowmax, mask, acc);
  k3_final     <<<1, 64, 0, stream>>>(acc, out);
}

// Round 8
// 202.625 us; speedup vs baseline: 3.7131x; 1.0237x over previous
//
#include <hip/hip_runtime.h>
#include <cfloat>

#pragma clang fp contract(off)

#define NCLS 80
#define PDIM 85
#define NA   8400
#define NB   16
#define NT   128
#define NTOP 10
#define SLOT 11      // LDS stride for merge lists (odd -> free 2-way bank aliasing)
#define APB  64      // anchors per k0/k2 block
#define BPI  132     // ceil(NA/64)
#define LN2  0.6931471805599453f
#define CAPW 448     // per-(target,wave) compaction capacity (worst case ~330)

// fast native sigmoid: rcp(1+exp(-x)).
__device__ __forceinline__ float sigm_fast(float x){
  float e = __expf(-x);
  return __builtin_amdgcn_rcpf(1.0f + e);
}

// fast bce (value path only)
__device__ __forceinline__ float bce_fast(float x, float t){
  float ax = fabsf(x);
  float e  = __expf(-ax);
  return fmaxf(x,0.0f) - x*t + LN2*__builtin_amdgcn_logf(1.0f + e);
}

// Fast-rcp IoU. Used identically in k1 and k2 -> internally consistent.
__device__ __forceinline__ float pair_iou(float tx1,float ty1,float tx2,float ty2,
                                          float px1,float py1,float px2,float py2){
  float w = fminf(tx2,px2) - fmaxf(tx1,px1);
  float h = fminf(ty2,py2) - fmaxf(ty1,py1);
  w = fmaxf(w,0.0f); h = fmaxf(h,0.0f);
  float inter = w*h;
  float at = fmaxf(tx2-tx1,0.0f)*fmaxf(ty2-ty1,0.0f);
  float ap = fmaxf(px2-px1,0.0f)*fmaxf(py2-py1,0.0f);
  float den = at+ap-inter+1e-8f;
  return inter * __builtin_amdgcn_rcpf(den);
}

// dval fallback (use_d==0 only; normally D table is used)
__device__ __forceinline__ float dval_fn(float sobj, float lg){
  float ln_sobj = LN2*__builtin_amdgcn_logf(sobj);
  float e = __expf(-fabsf(lg));
  float L = LN2*__builtin_amdgcn_logf(1.0f + e);
  float ln_sc = -(fmaxf(-lg,0.0f) + L);
  float lph = 0.5f*(ln_sobj + ln_sc);
  float p = __expf(lph);
  float lp = fmaxf(lph, -100.0f);
  float l1 = fmaxf(LN2*__builtin_amdgcn_logf(fmaxf(1.0f - p, 0.0f)), -100.0f);
  return lp - l1;
}

// Selection-critical: identical in k1 top-k and k2 argmin (same inline, contract off).
__device__ __forceinline__ float cost_from(float S, float dval, float iou, bool ibc, bool ib){
  float iouc = -LN2 * __builtin_amdgcn_logf(iou + 1e-8f);
  float clsc = -(S + dval);
  float c = clsc + 3.0f*iouc;
  c = c + (ibc ? 0.0f : 100000.0f);
  c = c + (ib  ? 0.0f : 1000000000.0f);
  return c;
}

// sorted-insert helpers (branchless unrolled shift)
__device__ __forceinline__ void ins_iou(float* riou, float iou){
  if (iou > riou[NTOP-1]){
    #pragma unroll
    for (int j = NTOP-1; j >= 1; --j){
      bool gj  = iou > riou[j];
      bool gj1 = iou > riou[j-1];
      riou[j] = gj ? (gj1 ? riou[j-1] : iou) : riou[j];
    }
    riou[0] = (iou > riou[0]) ? iou : riou[0];
  }
}
__device__ __forceinline__ void ins_cost(float* rcst, int* ridx, float c, int a){
  bool ent = (c < rcst[NTOP-1]) || (c == rcst[NTOP-1] && a < ridx[NTOP-1]);
  if (ent){
    #pragma unroll
    for (int j = NTOP-1; j >= 1; --j){
      bool bj  = (c < rcst[j])   || (c == rcst[j]   && a < ridx[j]);
      bool bj1 = (c < rcst[j-1]) || (c == rcst[j-1] && a < ridx[j-1]);
      float nc = bj ? (bj1 ? rcst[j-1] : c) : rcst[j];
      int   ni = bj ? (bj1 ? ridx[j-1] : a) : ridx[j];
      rcst[j] = nc; ridx[j] = ni;
    }
    bool b0 = (c < rcst[0]) || (c == rcst[0] && a < ridx[0]);
    rcst[0] = b0 ? c : rcst[0];
    ridx[0] = b0 ? a : ridx[0];
  }
}

// ---------------- Kernel 0: transpose + per-anchor precompute ----------------
__global__ __launch_bounds__(256) void k0_precompute(
    const float* __restrict__ pred, const float* __restrict__ target,
    const float* __restrict__ grid, const float* __restrict__ stridev,
    float4* __restrict__ pbox4, float4* __restrict__ meta4,
    float* __restrict__ obja, float* __restrict__ sobja,
    float* __restrict__ S0a, float* __restrict__ D, int use_d,
    unsigned long long* __restrict__ mask, float* __restrict__ acc)
{
  __shared__ float  tile[APB*PDIM];   // [a][c], stride 85 (odd -> conflict-free)
  __shared__ float4 tb4s[NT];
  __shared__ float  ps_s[4][APB];
  __shared__ float  ps0_s[4][APB];
  __shared__ int    ib_s[4][APB];

  int i  = blockIdx.x / BPI;
  int b  = blockIdx.x % BPI;
  int c0 = b*APB;
  int n  = NA - c0; if (n > APB) n = APB;
  int tid = threadIdx.x;

  if (blockIdx.x == 0) acc[tid] = 0.0f;   // 256 slots

  const float* src = pred + ((size_t)i*NA + c0)*PDIM;
  int tot = n*PDIM;
  for (int idx = tid; idx < tot; idx += 256) tile[idx] = src[idx];
  for (int idx = tid; idx < NT; idx += 256){
    const float* tg = target + (i*NT + idx)*6;
    tb4s[idx] = make_float4(tg[2],tg[3],tg[4],tg[5]);
  }
  __syncthreads();

  int al = tid & 63, cg = tid >> 6;
  if (al < n){
    int gid = i*NA + c0 + al;
    // softplus identity: ln sigm(x) = -(max(-x,0)+L), L = ln(1+exp(-|x|))
    float x4 = tile[al*PDIM+4];
    float e4 = __expf(-fabsf(x4));
    float L4 = LN2*__builtin_amdgcn_logf(1.0f + e4);
    float ln_sobj = -(fmaxf(-x4,0.0f) + L4);
    float ps = 0.0f, ps0 = 0.0f;
    #pragma unroll 4
    for (int k = 0; k < 20; ++k){
      int c = cg*20 + k;
      float x  = tile[al*PDIM+5+c];
      float e  = __expf(-fabsf(x));
      float L  = LN2*__builtin_amdgcn_logf(1.0f + e);
      float ln_sc = -(fmaxf(-x,0.0f) + L);
      float lph = 0.5f*(ln_sobj + ln_sc);     // ln p = 0.5 ln(sobj*sc)
      float p   = __expf(lph);
      float lp  = fmaxf(lph, -100.0f);
      float l1  = fmaxf(LN2*__builtin_amdgcn_logf(fmaxf(1.0f - p, 0.0f)), -100.0f);
      ps  += l1;
      if (use_d) D[(size_t)c*((size_t)NB*NA) + gid] = lp - l1;
      ps0 += fmaxf(x,0.0f) + L;               // bce(x,0) reuses L
    }
    ps_s[cg][al] = ps; ps0_s[cg][al] = ps0;

    int ga = c0 + al;
    float xg = grid[2*ga], yg = grid[2*ga+1], sv = stridev[ga];
    float xc = (xg + 0.5f)*sv, yc = (yg + 0.5f)*sv;
    float rc = 2.5f*sv;
    bool ibp = false;
    #pragma unroll 4
    for (int t = cg*32; t < cg*32+32; ++t){
      float4 T = tb4s[t];
      bool inb = (xc-T.x>0.0f)&&(yc-T.y>0.0f)&&(T.z-xc>0.0f)&&(T.w-yc>0.0f);
      float txc=(T.x+T.z)*0.5f, tyc=(T.y+T.w)*0.5f;
      bool inc = fmaxf(fabsf(xc-txc),fabsf(yc-tyc)) < rc;
      ibp = ibp || inb || inc;
    }
    ib_s[cg][al] = ibp ? 1 : 0;
  }
  __syncthreads();

  if (tid < n){
    int a = tid;
    int gid = i*NA + c0 + a;
    float s  = ps_s[0][a]  + ps_s[1][a]  + ps_s[2][a]  + ps_s[3][a];
    float s0 = ps0_s[0][a] + ps0_s[1][a] + ps0_s[2][a] + ps0_s[3][a];
    bool ib  = (ib_s[0][a] | ib_s[1][a] | ib_s[2][a] | ib_s[3][a]) != 0;

    float x1 = tile[a*PDIM+0], y1 = tile[a*PDIM+1];
    float x2 = tile[a*PDIM+2], y2 = tile[a*PDIM+3];
    float ol = tile[a*PDIM+4];
    pbox4[gid] = make_float4(x1,y1,x2,y2);
    obja[gid]  = ol;
    sobja[gid] = sigm_fast(ol);
    S0a[gid]   = s0;
    mask[(size_t)gid*2]   = 0ull;   // replaces host-side memset
    mask[(size_t)gid*2+1] = 0ull;

    int ga = c0 + a;
    float xg = grid[2*ga], yg = grid[2*ga+1], sv = stridev[ga];
    float xc = (xg + 0.5f)*sv, yc = (yg + 0.5f)*sv;
    float rc = 2.5f*sv;
    meta4[gid] = make_float4(xc, yc, ib ? rc : -rc, s);  // sign(z) = in_box
  }
}

// ------- Kernel 1: block = 4 targets (1 image); scan once, eval 4 targets ----
__global__ __launch_bounds__(256) void k1_pertarget(
    const float4* __restrict__ pbox4, const float4* __restrict__ meta4,
    const float* __restrict__ D, int use_d,
    const float* __restrict__ sobja, const float* __restrict__ pred,
    const float* __restrict__ target,
    float* __restrict__ rowmax, unsigned long long* __restrict__ mask)
{
  __shared__ __align__(16) int2 seg[16*CAPW];   // [t][v] segments, 56 KB
  __shared__ int cnts_s[4][4];                  // [scan-wave v][target t]
  __shared__ int cibc_s[4][4];

  int tid  = threadIdx.x;
  int lane = tid & 63, w = tid >> 6;
  int g0   = blockIdx.x * 4;          // 4 consecutive flattened targets, same image
  int i    = g0 / NT;
  int iNA  = i*NA;
  const size_t BA = (size_t)NB*NA;
  const float* m4f = (const float*)meta4;

  float tx1[4],ty1[4],tx2[4],ty2[4],txc[4],tyc[4]; int cid[4];
  #pragma unroll
  for (int t=0;t<4;++t){
    const float* tg = target + (size_t)(g0+t)*6;
    cid[t]=(int)tg[1]; tx1[t]=tg[2]; ty1[t]=tg[3]; tx2[t]=tg[4]; ty2[t]=tg[5];
    txc[t]=(tx1[t]+tx2[t])*0.5f; tyc[t]=(ty1[t]+ty2[t])*0.5f;
  }

  // ---- phase 1: each wave scans its stripe ONCE, evaluates all 4 targets ----
  int cnt[4] = {0,0,0,0}; int ci[4] = {0,0,0,0};
  int a = w*64 + lane;
  float4 pb = pbox4[iNA+a];
  float4 mt = meta4[iNA+a];
  for (int k = 0; k < 33; ++k){
    int a2 = a + 256;
    int ld = (a2 < NA) ? a2 : a;
    float4 pb_n = pbox4[iNA+ld];
    float4 mt_n = meta4[iNA+ld];

    bool act = (a < NA) && (mt.z > 0.0f);   // out-of-box never selectable
    #pragma unroll
    for (int t = 0; t < 4; ++t){
      float iou = 0.0f; bool ibc = false;
      if (act){
        iou = pair_iou(tx1[t],ty1[t],tx2[t],ty2[t], pb.x,pb.y,pb.z,pb.w);
        bool inb = (mt.x-tx1[t]>0.0f)&&(mt.y-ty1[t]>0.0f)&&(tx2[t]-mt.x>0.0f)&&(ty2[t]-mt.y>0.0f);
        bool inc = fmaxf(fabsf(mt.x-txc[t]),fabsf(mt.y-tyc[t])) < mt.z;
        ibc = inb && inc;
      }
      bool cand = (iou > 0.0f) || ibc;
      unsigned long long bb  = __ballot(cand);
      unsigned long long bb2 = __ballot(ibc);
      if (cand){
        int pos = cnt[t] + __popcll(bb & ((1ull << lane) - 1ull));
        if (pos < CAPW) seg[(t*4+w)*CAPW + pos] =
            make_int2(a | (ibc ? (1<<15) : 0), __float_as_int(iou));
      }
      cnt[t] += __popcll(bb);
      ci[t]  += __popcll(bb2);
    }
    pb = pb_n; mt = mt_n; a = a2;
  }
  if (lane < 4){ cnts_s[w][lane] = cnt[lane]; cibc_s[w][lane] = ci[lane]; }
  __syncthreads();   // the ONLY block barrier

  // ---- phase 2: wave w owns target w ----
  int myg = g0 + w;
  int myt = myg - i*NT;
  const float* Dc = use_d ? (D + (size_t)cid[w]*BA) : nullptr;
  int totibc = 0; bool ovf = false;
  #pragma unroll
  for (int v=0;v<4;++v){ int c1 = cnts_s[v][w]; totibc += cibc_s[v][w]; ovf |= (c1 > CAPW); }
  bool fastp = !ovf && (totibc >= 16);

  float riou[NTOP]; float rcst[NTOP]; int ridx[NTOP];
  #pragma unroll
  for (int j=0;j<NTOP;++j){ riou[j]=0.0f; rcst[j]=FLT_MAX; ridx[j]=0x7fffffff; }

  if (fastp){
    #pragma unroll
    for (int v = 0; v < 4; ++v){
      int cw = cnts_s[v][w];
      for (int j = lane; j < cw; j += 64){
        int2 e = seg[(w*4+v)*CAPW + j];
        int a1 = e.x & 0x7fff;
        bool ibc = (e.x >> 15) != 0;
        float iou = __int_as_float(e.y);
        ins_iou(riou, iou);
        int gid = iNA + a1;
        float S  = m4f[(size_t)gid*4 + 3];
        float dv = use_d ? Dc[gid] : dval_fn(sobja[gid], pred[(size_t)gid*PDIM + 5 + cid[w]]);
        float c  = cost_from(S, dv, iou, ibc, true);
        ins_cost(rcst, ridx, c, a1);   // (c, idx) lexicographic -> order-independent
      }
    }
  } else {
    // exact fallback: full rescan for target w by this wave (rare)
    for (int a1 = lane; a1 < NA; a1 += 64){
      float4 mt2 = meta4[iNA+a1];
      if (mt2.z > 0.0f){
        float4 pb2 = pbox4[iNA+a1];
        float iou = pair_iou(tx1[w],ty1[w],tx2[w],ty2[w], pb2.x,pb2.y,pb2.z,pb2.w);
        ins_iou(riou, iou);
        bool inb = (mt2.x-tx1[w]>0.0f)&&(mt2.y-ty1[w]>0.0f)&&(tx2[w]-mt2.x>0.0f)&&(ty2[w]-mt2.y>0.0f);
        bool inc = fmaxf(fabsf(mt2.x-txc[w]),fabsf(mt2.y-tyc[w])) < mt2.z;
        float dv = use_d ? Dc[iNA+a1] : dval_fn(sobja[iNA+a1], pred[(size_t)(iNA+a1)*PDIM + 5 + cid[w]]);
        float c = cost_from(mt2.w, dv, iou, inb&&inc, true);
        ins_cost(rcst, ridx, c, a1);
      }
    }
  }

  // ---- intra-wave 6-level LDS merge in own region (no block barriers) ----
  char* sm = (char*)&seg[(w*4)*CAPW];   // own 14336-B region; reads above are done
  float* fI = (float*)sm;               // [64*SLOT]
  float* fC = (float*)(sm + 64*SLOT*4);
  int*   iB = (int*)  (sm + 64*SLOT*8);
  __builtin_amdgcn_wave_barrier();
  {
    int base = lane*SLOT;
    #pragma unroll
    for (int j=0;j<NTOP;++j){ fI[base+j]=riou[j]; fC[base+j]=rcst[j]; iB[base+j]=ridx[j]; }
  }
  __builtin_amdgcn_wave_barrier();

  for (int s2 = 32; s2 >= 1; s2 >>= 1){
    if (lane < s2){
      int bA = lane*SLOT, bB = (lane+s2)*SLOT;
      float ti[NTOP];
      { int ia=0, ib2=0;
        #pragma unroll
        for (int k=0;k<NTOP;++k){
          float va=fI[bA+ia], vb=fI[bB+ib2];
          if (va >= vb){ ti[k]=va; ++ia; } else { ti[k]=vb; ++ib2; }
        }
      }
      float tc[NTOP]; int tx[NTOP];
      { int ia=0, ib2=0;
        #pragma unroll
        for (int k=0;k<NTOP;++k){
          float ca=fC[bA+ia], cb=fC[bB+ib2];
          int   xa=iB[bA+ia], xb=iB[bB+ib2];
          bool takeA = (ca < cb) || (ca == cb && xa <= xb);
          if (takeA){ tc[k]=ca; tx[k]=xa; ++ia; } else { tc[k]=cb; tx[k]=xb; ++ib2; }
        }
      }
      #pragma unroll
      for (int k=0;k<NTOP;++k){ fI[bA+k]=ti[k]; fC[bA+k]=tc[k]; iB[bA+k]=tx[k]; }
    }
    __builtin_amdgcn_wave_barrier();
  }

  // ---- tail: rowmax, dyn_k, scatter ----
  float ssum = 0.0f;
  #pragma unroll
  for (int k=0;k<NTOP;++k) ssum += fI[k];   // descending, like jnp top_k sum
  int dk = (int)ssum;
  if (dk < 1) dk = 1;

  if (lane == 0) rowmax[myg] = fI[0];
  if (lane < NTOP){
    int a1 = iB[lane];
    if (lane < dk && a1 < NA && meta4[iNA + a1].z > 0.0f){
      atomicOr(&mask[(size_t)(iNA + a1)*2 + (myt>>6)], 1ull << (myt & 63));
    }
  }
}

// ---------- Kernel 2: per-anchor resolution + loss partial sums --------------
__global__ __launch_bounds__(256) void k2_peranchor(
    const float* __restrict__ pred,
    const float4* __restrict__ pbox4, const float4* __restrict__ meta4,
    const float* __restrict__ obja, const float* __restrict__ sobja,
    const float* __restrict__ S0a,
    const float* __restrict__ D, int use_d,
    const float* __restrict__ target,
    const float* __restrict__ rowmax, const unsigned long long* __restrict__ mask,
    float* __restrict__ acc)
{
  __shared__ float4 tb4[NT];
  __shared__ int    tcid[NT];
  __shared__ float  invm[NT];
  __shared__ float  tarea[NT];
  __shared__ float  sh_obj[4][64];
  __shared__ float  sh_c[4][64];
  __shared__ int    sh_tp[4][64];

  int i  = blockIdx.x / BPI;
  int b  = blockIdx.x % BPI;
  int c0 = b*APB;
  int q  = threadIdx.x & 63;
  int s  = threadIdx.x >> 6;
  int a  = c0 + q;
  const size_t BA = (size_t)NB*NA;

  for (int idx = threadIdx.x; idx < NT; idx += 256){
    const float* tg = target + (i*NT + idx)*6;
    tcid[idx] = (int)tg[1];
    float x1=tg[2], y1=tg[3], x2=tg[4], y2=tg[5];
    tb4[idx]   = make_float4(x1,y1,x2,y2);
    invm[idx]  = 1.0f / (rowmax[i*NT + idx] + 1e-8f);
    tarea[idx] = fmaxf(x2-x1,0.0f)*fmaxf(y2-y1,0.0f);
  }
  __syncthreads();

  bool valid = (a < NA);
  int gid = i*NA + a;
  float4 pb = valid ? pbox4[gid] : make_float4(0,0,0,0);
  float4 mt = valid ? meta4[gid] : make_float4(0,0,-1.0f,0);
  bool ib = valid && (mt.z > 0.0f);
  float rc = fabsf(mt.z);
  float px1=pb.x, py1=pb.y, px2=pb.z, py2=pb.w;
  float ap = fmaxf(px2-px1,0.0f)*fmaxf(py2-py1,0.0f);

  float best = 0.0f;
  if (ib){
    #pragma unroll 4
    for (int t = s*32; t < s*32+32; ++t){
      float4 T = tb4[t];
      float w = fminf(T.z,px2) - fmaxf(T.x,px1);
      float h = fminf(T.w,py2) - fmaxf(T.y,py1);
      w = fmaxf(w,0.0f); h = fmaxf(h,0.0f);
      float inter = w*h;
      float den = tarea[t] + ap - inter + 1e-8f;
      float iou = inter * __builtin_amdgcn_rcpf(den);
      best = fmaxf(best, iou*invm[t]);
    }
  }
  sh_obj[s][q] = best;

  unsigned long long m0=0, m1=0;
  if (valid){ m0 = mask[(size_t)gid*2]; m1 = mask[(size_t)gid*2+1]; }
  int cnt = __popcll(m0) + __popcll(m1);

  float bc = FLT_MAX; int bt = NT;
  if (cnt > 1){
    float sobj = use_d ? 0.0f : sobja[gid];
    float Sg = mt.w;
    for (int t = s*32; t < s*32+32; ++t){
      float4 T = tb4[t];
      float iou = ib ? pair_iou(T.x,T.y,T.z,T.w,px1,py1,px2,py2) : 0.0f;
      bool inb = (mt.x-T.x>0.0f)&&(mt.y-T.y>0.0f)&&(T.z-mt.x>0.0f)&&(T.w-mt.y>0.0f);
      float txc=(T.x+T.z)*0.5f, tyc=(T.y+T.w)*0.5f;
      bool inc = fmaxf(fabsf(mt.x-txc),fabsf(mt.y-tyc)) < rc;
      float dv = use_d ? D[(size_t)tcid[t]*BA + gid]
                       : dval_fn(sobj, pred[(size_t)gid*PDIM + 5 + tcid[t]]);
      float c = cost_from(Sg, dv, iou, inb&&inc, ib);
      if (c < bc){ bc = c; bt = t; }
    }
  }
  sh_c[s][q] = bc; sh_tp[s][q] = bt;
  __syncthreads();

  if (s == 0){
    float m=0.0f, vbox=0.0f, vobj=0.0f, vcls=0.0f;
    if (valid){
      float ob = fmaxf(fmaxf(sh_obj[0][q],sh_obj[1][q]), fmaxf(sh_obj[2][q],sh_obj[3][q]));
      float obj_t = ib ? fminf(fmaxf(ob,0.0f),1.0f) : 0.0f;
      vobj = bce_fast(obja[gid], obj_t);

      float cbest = sh_c[0][q]; int tbest = sh_tp[0][q];
      #pragma unroll
      for (int s2=1; s2<4; ++s2){
        float cs = sh_c[s2][q]; int ts = sh_tp[s2][q];
        if (cs < cbest){ cbest = cs; tbest = ts; }
      }

      int tp = 0; bool mpv = false;
      if (cnt > 1){ tp = tbest; mpv = true; }
      else if (cnt == 1){
        tp = m0 ? (__ffsll(m0)-1) : (64 + __ffsll(m1)-1);
        mpv = true;
      }

      if (mpv){
        m = 1.0f;
        float4 T = tb4[tp];
        float x1=T.x, y1=T.y, x2=T.z, y2=T.w;
        float w = fmaxf(fminf(px2,x2)-fmaxf(px1,x1),0.0f);
        float h = fmaxf(fminf(py2,y2)-fmaxf(py1,y1),0.0f);
        float inter = w*h;
        float wp=px2-px1, hp=py2-py1, wt=x2-x1, ht=y2-y1;
        float iou = inter/(wp*hp + wt*ht - inter + 1e-8f);
        float cw = fmaxf(px2,x2)-fminf(px1,x1);
        float ch = fmaxf(py2,y2)-fminf(py1,y1);
        float c2 = cw*cw + ch*ch + 1e-8f;
        float dx = (px1+px2)-(x1+x2), dy = (py1+py2)-(y1+y2);
        float rho2 = (dx*dx + dy*dy)/4.0f;
        float da = atanf(wt/(ht+1e-8f)) - atanf(wp/(hp+1e-8f));
        float v  = 0.4052847345693511f * da * da;   // 4/pi^2
        float alpha = v/(1.0f - iou + v + 1e-8f);
        vbox = 1.0f - (iou - rho2/c2 - alpha*v);

        int cc = tcid[tp];
        float xcc = pred[(size_t)gid*PDIM + 5 + cc];
        vcls = (S0a[gid] - xcc) * (1.0f/80.0f);   // sum_c bce(x_c, onehot) = S0 - x_cc
      }
    }

    #pragma unroll
    for (int off=32; off>0; off>>=1){
      m    += __shfl_down(m, off);
      vbox += __shfl_down(vbox, off);
      vobj += __shfl_down(vobj, off);
      vcls += __shfl_down(vcls, off);
    }
    if (q == 0){
      int slot = (blockIdx.x & 63)*4;
      atomicAdd(&acc[slot+0], m);
      atomicAdd(&acc[slot+1], vbox);
      atomicAdd(&acc[slot+2], vobj);
      atomicAdd(&acc[slot+3], vcls);
    }
  }
}

// ---------------- Kernel 3: finalize (reduce 64 accumulator slots) -----------
__global__ void k3_final(const float* __restrict__ acc, float* __restrict__ out){
  int l = threadIdx.x;   // 64 threads
  float4 v = ((const float4*)acc)[l];
  #pragma unroll
  for (int off=32; off>0; off>>=1){
    v.x += __shfl_down(v.x, off);
    v.y += __shfl_down(v.y, off);
    v.z += __shfl_down(v.z, off);
    v.w += __shfl_down(v.w, off);
  }
  if (l == 0){
    float n    = fmaxf(v.x, 1.0f);
    float lbox = 0.05f * v.y / n;
    float lobj = v.z / (float)(NB*NA);
    float lcls = 0.5f  * v.w / n;
    out[0] = lbox + lobj + lcls;
    out[1] = lbox; out[2] = lobj; out[3] = lcls;
  }
}

extern "C" void kernel_launch(void* const* d_in, const int* in_sizes, int n_in,
                              void* d_out, int out_size, void* d_ws, size_t ws_size,
                              hipStream_t stream) {
  const float* pred    = (const float*)d_in[0];
  const float* target  = (const float*)d_in[1];
  const float* grid    = (const float*)d_in[2];
  const float* stridev = (const float*)d_in[3];
  float* out = (float*)d_out;

  char* ws = (char*)d_ws;
  const size_t BA = (size_t)NB*NA;   // 134400

  size_t off = 0;
  unsigned long long* mask = (unsigned long long*)(ws + off); off += BA*16;
  float* acc    = (float*)(ws + off); off += 64*4*4;
  float4* pbox4 = (float4*)(ws + off); off += BA*16;
  float4* meta4 = (float4*)(ws + off); off += BA*16;
  float* obja   = (float*)(ws + off); off += BA*4;
  float* sobja  = (float*)(ws + off); off += BA*4;
  float* S0a    = (float*)(ws + off); off += BA*4;
  float* rowmax = (float*)(ws + off); off += (size_t)NB*NT*4;
  float* D      = (float*)(ws + off);
  const size_t need_d = off + (size_t)NCLS*BA*4;
  int use_d = (ws_size >= need_d) ? 1 : 0;

  // mask+acc zeroed inside k0 (no memset dispatch)
  k0_precompute<<<NB*BPI, 256, 0, stream>>>(pred, target, grid, stridev,
                                            pbox4, meta4, obja, sobja, S0a, D, use_d,
                                            mask, acc);
  k1_pertarget <<<NB*NT/4, 256, 0, stream>>>(pbox4, meta4, D, use_d,
                                             sobja, pred, target, rowmax, mask);
  k2_peranchor <<<NB*BPI, 256, 0, stream>>>(pred, pbox4, meta4, obja, sobja, S0a,
                                            D, use_d, target, rowmax, mask, acc);
  k3_final     <<<1, 64, 0, stream>>>(acc, out);
}

// Round 9
// 185.947 us; speedup vs baseline: 4.0461x; 1.0897x over previous
//
#include <hip/hip_runtime.h>
#include <cfloat>

#pragma clang fp contract(off)

#define NCLS 80
#define PDIM 85
#define NA   8400
#define NB   16
#define NT   128
#define NTOP 10
#define APB  64      // anchors per k0/k2 block
#define BPI  132     // ceil(NA/64)
#define LN2  0.6931471805599453f
#define CAPW 512     // per-wave compaction capacity (worst case ~300)

#define KSENT 0xFFFFFFFF7FFFFFFFull   // sentinel key: huge cost, idx 0x7FFFFFFF

// fast native sigmoid: rcp(1+exp(-x)).
__device__ __forceinline__ float sigm_fast(float x){
  float e = __expf(-x);
  return __builtin_amdgcn_rcpf(1.0f + e);
}

// fast bce (value path only)
__device__ __forceinline__ float bce_fast(float x, float t){
  float ax = fabsf(x);
  float e  = __expf(-ax);
  return fmaxf(x,0.0f) - x*t + LN2*__builtin_amdgcn_logf(1.0f + e);
}

// Fast-rcp IoU. Used identically in k1 and k2 -> internally consistent.
__device__ __forceinline__ float pair_iou(float tx1,float ty1,float tx2,float ty2,
                                          float px1,float py1,float px2,float py2){
  float w = fminf(tx2,px2) - fmaxf(tx1,px1);
  float h = fminf(ty2,py2) - fmaxf(ty1,py1);
  w = fmaxf(w,0.0f); h = fmaxf(h,0.0f);
  float inter = w*h;
  float at = fmaxf(tx2-tx1,0.0f)*fmaxf(ty2-ty1,0.0f);
  float ap = fmaxf(px2-px1,0.0f)*fmaxf(py2-py1,0.0f);
  float den = at+ap-inter+1e-8f;
  return inter * __builtin_amdgcn_rcpf(den);
}

// dval fallback (use_d==0 only; normally D table is used)
__device__ __forceinline__ float dval_fn(float sobj, float lg){
  float ln_sobj = LN2*__builtin_amdgcn_logf(sobj);
  float e = __expf(-fabsf(lg));
  float L = LN2*__builtin_amdgcn_logf(1.0f + e);
  float ln_sc = -(fmaxf(-lg,0.0f) + L);
  float lph = 0.5f*(ln_sobj + ln_sc);
  float p = __expf(lph);
  float lp = fmaxf(lph, -100.0f);
  float l1 = fmaxf(LN2*__builtin_amdgcn_logf(fmaxf(1.0f - p, 0.0f)), -100.0f);
  return lp - l1;
}

// Selection-critical: identical in k1 top-k and k2 argmin (same inline, contract off).
__device__ __forceinline__ float cost_from(float S, float dval, float iou, bool ibc, bool ib){
  float iouc = -LN2 * __builtin_amdgcn_logf(iou + 1e-8f);
  float clsc = -(S + dval);
  float c = clsc + 3.0f*iouc;
  c = c + (ibc ? 0.0f : 100000.0f);
  c = c + (ib  ? 0.0f : 1000000000.0f);
  return c;
}

// sortable u64 key: ascending key order == ascending (cost, idx) lexicographic
__device__ __forceinline__ unsigned long long key_of(float c, int idx){
  unsigned int u = __float_as_uint(c);
  u ^= (u & 0x80000000u) ? 0xFFFFFFFFu : 0x80000000u;
  return ((unsigned long long)u << 32) | (unsigned int)idx;
}

// sorted-insert helpers (branchless unrolled shift; order-independent)
__device__ __forceinline__ void ins_iou(float* riou, float iou){
  if (iou > riou[NTOP-1]){
    #pragma unroll
    for (int j = NTOP-1; j >= 1; --j){
      bool gj  = iou > riou[j];
      bool gj1 = iou > riou[j-1];
      riou[j] = gj ? (gj1 ? riou[j-1] : iou) : riou[j];
    }
    riou[0] = (iou > riou[0]) ? iou : riou[0];
  }
}
__device__ __forceinline__ void ins_key(unsigned long long* rk, unsigned long long key){
  if (key < rk[NTOP-1]){
    #pragma unroll
    for (int j = NTOP-1; j >= 1; --j){
      bool bj  = key < rk[j];
      bool bj1 = key < rk[j-1];
      rk[j] = bj ? (bj1 ? rk[j-1] : key) : rk[j];
    }
    rk[0] = (key < rk[0]) ? key : rk[0];
  }
}

// ---------------- Kernel 0: transpose + per-anchor precompute ----------------
__global__ __launch_bounds__(256) void k0_precompute(
    const float* __restrict__ pred, const float* __restrict__ target,
    const float* __restrict__ grid, const float* __restrict__ stridev,
    float4* __restrict__ pbox4, float4* __restrict__ meta4,
    float* __restrict__ obja, float* __restrict__ sobja,
    float* __restrict__ S0a, float* __restrict__ D, int use_d,
    unsigned long long* __restrict__ mask, float* __restrict__ acc)
{
  __shared__ float  tile[APB*PDIM];   // [a][c], stride 85 (odd -> conflict-free)
  __shared__ float4 tb4s[NT];
  __shared__ float  ps_s[4][APB];
  __shared__ float  ps0_s[4][APB];
  __shared__ int    ib_s[4][APB];

  int i  = blockIdx.x / BPI;
  int b  = blockIdx.x % BPI;
  int c0 = b*APB;
  int n  = NA - c0; if (n > APB) n = APB;
  int tid = threadIdx.x;

  if (blockIdx.x == 0) acc[tid] = 0.0f;   // 256 slots

  const float* src = pred + ((size_t)i*NA + c0)*PDIM;
  int tot = n*PDIM;
  for (int idx = tid; idx < tot; idx += 256) tile[idx] = src[idx];
  for (int idx = tid; idx < NT; idx += 256){
    const float* tg = target + (i*NT + idx)*6;
    tb4s[idx] = make_float4(tg[2],tg[3],tg[4],tg[5]);
  }
  __syncthreads();

  int al = tid & 63, cg = tid >> 6;
  if (al < n){
    int gid = i*NA + c0 + al;
    // softplus identity: ln sigm(x) = -(max(-x,0)+L), L = ln(1+exp(-|x|))
    float x4 = tile[al*PDIM+4];
    float e4 = __expf(-fabsf(x4));
    float L4 = LN2*__builtin_amdgcn_logf(1.0f + e4);
    float ln_sobj = -(fmaxf(-x4,0.0f) + L4);
    float ps = 0.0f, ps0 = 0.0f;
    #pragma unroll 4
    for (int k = 0; k < 20; ++k){
      int c = cg*20 + k;
      float x  = tile[al*PDIM+5+c];
      float e  = __expf(-fabsf(x));
      float L  = LN2*__builtin_amdgcn_logf(1.0f + e);
      float ln_sc = -(fmaxf(-x,0.0f) + L);
      float lph = 0.5f*(ln_sobj + ln_sc);     // ln p = 0.5 ln(sobj*sc)
      float p   = __expf(lph);
      float lp  = fmaxf(lph, -100.0f);
      float l1  = fmaxf(LN2*__builtin_amdgcn_logf(fmaxf(1.0f - p, 0.0f)), -100.0f);
      ps  += l1;
      if (use_d) D[(size_t)c*((size_t)NB*NA) + gid] = lp - l1;
      ps0 += fmaxf(x,0.0f) + L;               // bce(x,0) reuses L
    }
    ps_s[cg][al] = ps; ps0_s[cg][al] = ps0;

    int ga = c0 + al;
    float xg = grid[2*ga], yg = grid[2*ga+1], sv = stridev[ga];
    float xc = (xg + 0.5f)*sv, yc = (yg + 0.5f)*sv;
    float rc = 2.5f*sv;
    bool ibp = false;
    #pragma unroll 4
    for (int t = cg*32; t < cg*32+32; ++t){
      float4 T = tb4s[t];
      bool inb = (xc-T.x>0.0f)&&(yc-T.y>0.0f)&&(T.z-xc>0.0f)&&(T.w-yc>0.0f);
      float txc=(T.x+T.z)*0.5f, tyc=(T.y+T.w)*0.5f;
      bool inc = fmaxf(fabsf(xc-txc),fabsf(yc-tyc)) < rc;
      ibp = ibp || inb || inc;
    }
    ib_s[cg][al] = ibp ? 1 : 0;
  }
  __syncthreads();

  if (tid < n){
    int a = tid;
    int gid = i*NA + c0 + a;
    float s  = ps_s[0][a]  + ps_s[1][a]  + ps_s[2][a]  + ps_s[3][a];
    float s0 = ps0_s[0][a] + ps0_s[1][a] + ps0_s[2][a] + ps0_s[3][a];
    bool ib  = (ib_s[0][a] | ib_s[1][a] | ib_s[2][a] | ib_s[3][a]) != 0;

    float x1 = tile[a*PDIM+0], y1 = tile[a*PDIM+1];
    float x2 = tile[a*PDIM+2], y2 = tile[a*PDIM+3];
    float ol = tile[a*PDIM+4];
    pbox4[gid] = make_float4(x1,y1,x2,y2);
    obja[gid]  = ol;
    sobja[gid] = sigm_fast(ol);
    S0a[gid]   = s0;
    mask[(size_t)gid*2]   = 0ull;   // replaces host-side memset
    mask[(size_t)gid*2+1] = 0ull;

    int ga = c0 + a;
    float xg = grid[2*ga], yg = grid[2*ga+1], sv = stridev[ga];
    float xc = (xg + 0.5f)*sv, yc = (yg + 0.5f)*sv;
    float rc = 2.5f*sv;
    meta4[gid] = make_float4(xc, yc, ib ? rc : -rc, s);  // sign(z) = in_box
  }
}

// ---- Kernel 1: per-target compact scan + register tournament top-k ----------
__global__ __launch_bounds__(256) void k1_pertarget(
    const float4* __restrict__ pbox4, const float4* __restrict__ meta4,
    const float* __restrict__ D, int use_d,
    const float* __restrict__ sobja, const float* __restrict__ pred,
    const float* __restrict__ target,
    float* __restrict__ rowmax, unsigned long long* __restrict__ mask)
{
  __shared__ __align__(16) int2 seg[4*CAPW];         // 16 KB
  __shared__ int   cnts_s[4], cibc_s[4];
  __shared__ float wiou[4][NTOP];                    // per-wave desc iou
  __shared__ unsigned long long wkey[4][NTOP];       // per-wave asc cost keys

  int tid = threadIdx.x, lane = tid & 63, w = tid >> 6;
  int g = blockIdx.x;
  int i = g / NT, t = g - i*NT;
  int iNA = i*NA;
  const size_t BA = (size_t)NB*NA;
  const float* m4f = (const float*)meta4;

  const float* tg = target + (size_t)g*6;
  int   cid = (int)tg[1];
  float tx1 = tg[2], ty1 = tg[3], tx2 = tg[4], ty2 = tg[5];
  float txc = (tx1+tx2)*0.5f, tyc = (ty1+ty2)*0.5f;
  const float* Dc = use_d ? (D + (size_t)cid*BA) : nullptr;

  // ---- phase 1: prefetched scan, per-wave scalar-counter compaction ----
  int cnt = 0, ci = 0;
  int a = w*64 + lane;
  float4 pb = pbox4[iNA+a];
  float4 mt = meta4[iNA+a];
  for (int k = 0; k < 33; ++k){
    int a2 = a + 256;
    int ld = (a2 < NA) ? a2 : a;
    float4 pbn = pbox4[iNA+ld];
    float4 mtn = meta4[iNA+ld];

    bool act = (a < NA) && (mt.z > 0.0f);   // out-of-box never selectable
    float iou = 0.0f; bool ibc = false;
    if (act){
      iou = pair_iou(tx1,ty1,tx2,ty2, pb.x,pb.y,pb.z,pb.w);
      bool inb = (mt.x-tx1>0.0f)&&(mt.y-ty1>0.0f)&&(tx2-mt.x>0.0f)&&(ty2-mt.y>0.0f);
      bool inc = fmaxf(fabsf(mt.x-txc),fabsf(mt.y-tyc)) < mt.z;
      ibc = inb && inc;
    }
    bool cand = (iou > 0.0f) || ibc;
    unsigned long long bb  = __ballot(cand);
    unsigned long long bb2 = __ballot(ibc);
    if (cand){
      int pos = cnt + __popcll(bb & ((1ull << lane) - 1ull));
      if (pos < CAPW) seg[w*CAPW + pos] = make_int2(a | (ibc ? (1<<15) : 0), __float_as_int(iou));
    }
    cnt += __popcll(bb);
    ci  += __popcll(bb2);
    pb = pbn; mt = mtn; a = a2;
  }
  if (lane == 0){ cnts_s[w] = cnt; cibc_s[w] = ci; }
  __syncthreads();

  int tibc = cibc_s[0]+cibc_s[1]+cibc_s[2]+cibc_s[3];
  bool ovf = (cnts_s[0]>CAPW)||(cnts_s[1]>CAPW)||(cnts_s[2]>CAPW)||(cnts_s[3]>CAPW);
  bool fastp = !ovf && (tibc >= 16);

  float riou[NTOP]; unsigned long long rk[NTOP];
  #pragma unroll
  for (int j=0;j<NTOP;++j){ riou[j]=0.0f; rk[j]=KSENT; }

  if (fastp){
    int cw = cnts_s[w];
    for (int j = lane; j < cw; j += 64){
      int2 e = seg[w*CAPW + j];
      int a1 = e.x & 0x7fff;
      bool ibc = (e.x >> 15) != 0;
      float iou = __int_as_float(e.y);
      ins_iou(riou, iou);
      int gid = iNA + a1;
      float S  = m4f[(size_t)gid*4 + 3];
      float dv = use_d ? Dc[gid] : dval_fn(sobja[gid], pred[(size_t)gid*PDIM + 5 + cid]);
      float c  = cost_from(S, dv, iou, ibc, true);
      ins_key(rk, key_of(c, a1));
    }
  } else {
    // exact fallback: full rescan by all 256 threads (rare)
    for (int a1 = tid; a1 < NA; a1 += 256){
      float4 mt2 = meta4[iNA+a1];
      if (mt2.z > 0.0f){
        float4 pb2 = pbox4[iNA+a1];
        float iou = pair_iou(tx1,ty1,tx2,ty2, pb2.x,pb2.y,pb2.z,pb2.w);
        ins_iou(riou, iou);
        bool inb = (mt2.x-tx1>0.0f)&&(mt2.y-ty1>0.0f)&&(tx2-mt2.x>0.0f)&&(ty2-mt2.y>0.0f);
        bool inc = fmaxf(fabsf(mt2.x-txc),fabsf(mt2.y-tyc)) < mt2.z;
        float dv = use_d ? Dc[iNA+a1] : dval_fn(sobja[iNA+a1], pred[(size_t)(iNA+a1)*PDIM + 5 + cid]);
        float c = cost_from(mt2.w, dv, iou, inb&&inc, true);
        ins_key(rk, key_of(c, a1));
      }
    }
  }

  // ---- per-wave tournament pop: 10 rounds wave-reduce + winner-pop ----
  #pragma unroll
  for (int r = 0; r < NTOP; ++r){
    float gm = riou[0];
    #pragma unroll
    for (int m = 1; m < 64; m <<= 1) gm = fmaxf(gm, __shfl_xor(gm, m));
    unsigned long long bb = __ballot(riou[0] == gm);
    int win = __ffsll(bb) - 1;
    if (lane == win){
      #pragma unroll
      for (int j=0;j<NTOP-1;++j) riou[j] = riou[j+1];
      riou[NTOP-1] = 0.0f;
    }
    if (lane == 0) wiou[w][r] = gm;
  }
  #pragma unroll
  for (int r = 0; r < NTOP; ++r){
    unsigned long long gk = rk[0];
    #pragma unroll
    for (int m = 1; m < 64; m <<= 1){
      unsigned long long o = __shfl_xor(gk, m);
      gk = (o < gk) ? o : gk;
    }
    unsigned long long bb = __ballot(rk[0] == gk);
    int win = __ffsll(bb) - 1;
    if (lane == win){
      #pragma unroll
      for (int j=0;j<NTOP-1;++j) rk[j] = rk[j+1];
      rk[NTOP-1] = KSENT;
    }
    if (lane == 0) wkey[w][r] = gk;
  }
  __syncthreads();

  // ---- wave 0: 4-way pointer merge (global desc iou sum; asc cost keys) ----
  if (w == 0){
    int p0=0,p1=0,p2=0,p3=0;
    float ssum = 0.0f, rmax = 0.0f;
    #pragma unroll
    for (int r = 0; r < NTOP; ++r){
      float v0=wiou[0][p0], v1=wiou[1][p1], v2=wiou[2][p2], v3=wiou[3][p3];
      float mx = fmaxf(fmaxf(v0,v1), fmaxf(v2,v3));
      if (r == 0) rmax = mx;
      ssum += mx;                                   // global desc order, like jnp
      if      (mx == v0) ++p0;
      else if (mx == v1) ++p1;
      else if (mx == v2) ++p2;
      else               ++p3;
    }
    int dk = (int)ssum;
    if (dk < 1) dk = 1;

    int q0=0,q1=0,q2=0,q3=0;
    int myidx = 0x7fffffff;
    #pragma unroll
    for (int r = 0; r < NTOP; ++r){
      unsigned long long k0=wkey[0][q0], k1=wkey[1][q1], k2=wkey[2][q2], k3=wkey[3][q3];
      unsigned long long mn = k0;
      mn = (k1 < mn) ? k1 : mn;
      mn = (k2 < mn) ? k2 : mn;
      mn = (k3 < mn) ? k3 : mn;
      if (lane == r) myidx = (int)(mn & 0xFFFFFFFFull);
      if      (mn == k0) ++q0;
      else if (mn == k1) ++q1;
      else if (mn == k2) ++q2;
      else               ++q3;
    }

    if (lane == 0) rowmax[g] = rmax;
    if (lane < NTOP && lane < dk){
      int a1 = myidx;
      if (a1 >= 0 && a1 < NA){     // sentinel idx = 0x7FFFFFFF skipped
        atomicOr(&mask[(size_t)(iNA + a1)*2 + (t>>6)], 1ull << (t & 63));
      }
    }
  }
}

// ---------- Kernel 2: per-anchor resolution + loss partial sums --------------
__global__ __launch_bounds__(256) void k2_peranchor(
    const float* __restrict__ pred,
    const float4* __restrict__ pbox4, const float4* __restrict__ meta4,
    const float* __restrict__ obja, const float* __restrict__ sobja,
    const float* __restrict__ S0a,
    const float* __restrict__ D, int use_d,
    const float* __restrict__ target,
    const float* __restrict__ rowmax, const unsigned long long* __restrict__ mask,
    float* __restrict__ acc)
{
  __shared__ float4 tb4[NT];
  __shared__ int    tcid[NT];
  __shared__ float  invm[NT];
  __shared__ float  tarea[NT];
  __shared__ float  sh_obj[4][64];
  __shared__ float  sh_c[4][64];
  __shared__ int    sh_tp[4][64];

  int i  = blockIdx.x / BPI;
  int b  = blockIdx.x % BPI;
  int c0 = b*APB;
  int q  = threadIdx.x & 63;
  int s  = threadIdx.x >> 6;
  int a  = c0 + q;
  const size_t BA = (size_t)NB*NA;

  for (int idx = threadIdx.x; idx < NT; idx += 256){
    const float* tg = target + (i*NT + idx)*6;
    tcid[idx] = (int)tg[1];
    float x1=tg[2], y1=tg[3], x2=tg[4], y2=tg[5];
    tb4[idx]   = make_float4(x1,y1,x2,y2);
    invm[idx]  = 1.0f / (rowmax[i*NT + idx] + 1e-8f);
    tarea[idx] = fmaxf(x2-x1,0.0f)*fmaxf(y2-y1,0.0f);
  }
  __syncthreads();

  bool valid = (a < NA);
  int gid = i*NA + a;
  float4 pb = valid ? pbox4[gid] : make_float4(0,0,0,0);
  float4 mt = valid ? meta4[gid] : make_float4(0,0,-1.0f,0);
  bool ib = valid && (mt.z > 0.0f);
  float rc = fabsf(mt.z);
  float px1=pb.x, py1=pb.y, px2=pb.z, py2=pb.w;
  float ap = fmaxf(px2-px1,0.0f)*fmaxf(py2-py1,0.0f);

  float best = 0.0f;
  if (ib){
    #pragma unroll 4
    for (int t = s*32; t < s*32+32; ++t){
      float4 T = tb4[t];
      float w = fminf(T.z,px2) - fmaxf(T.x,px1);
      float h = fminf(T.w,py2) - fmaxf(T.y,py1);
      w = fmaxf(w,0.0f); h = fmaxf(h,0.0f);
      float inter = w*h;
      float den = tarea[t] + ap - inter + 1e-8f;
      float iou = inter * __builtin_amdgcn_rcpf(den);
      best = fmaxf(best, iou*invm[t]);
    }
  }
  sh_obj[s][q] = best;

  unsigned long long m0=0, m1=0;
  if (valid){ m0 = mask[(size_t)gid*2]; m1 = mask[(size_t)gid*2+1]; }
  int cnt = __popcll(m0) + __popcll(m1);

  float bc = FLT_MAX; int bt = NT;
  if (cnt > 1){
    float sobj = use_d ? 0.0f : sobja[gid];
    float Sg = mt.w;
    for (int t = s*32; t < s*32+32; ++t){
      float4 T = tb4[t];
      float iou = ib ? pair_iou(T.x,T.y,T.z,T.w,px1,py1,px2,py2) : 0.0f;
      bool inb = (mt.x-T.x>0.0f)&&(mt.y-T.y>0.0f)&&(T.z-mt.x>0.0f)&&(T.w-mt.y>0.0f);
      float txc=(T.x+T.z)*0.5f, tyc=(T.y+T.w)*0.5f;
      bool inc = fmaxf(fabsf(mt.x-txc),fabsf(mt.y-tyc)) < rc;
      float dv = use_d ? D[(size_t)tcid[t]*BA + gid]
                       : dval_fn(sobj, pred[(size_t)gid*PDIM + 5 + tcid[t]]);
      float c = cost_from(Sg, dv, iou, inb&&inc, ib);
      if (c < bc){ bc = c; bt = t; }
    }
  }
  sh_c[s][q] = bc; sh_tp[s][q] = bt;
  __syncthreads();

  if (s == 0){
    float m=0.0f, vbox=0.0f, vobj=0.0f, vcls=0.0f;
    if (valid){
      float ob = fmaxf(fmaxf(sh_obj[0][q],sh_obj[1][q]), fmaxf(sh_obj[2][q],sh_obj[3][q]));
      float obj_t = ib ? fminf(fmaxf(ob,0.0f),1.0f) : 0.0f;
      vobj = bce_fast(obja[gid], obj_t);

      float cbest = sh_c[0][q]; int tbest = sh_tp[0][q];
      #pragma unroll
      for (int s2=1; s2<4; ++s2){
        float cs = sh_c[s2][q]; int ts = sh_tp[s2][q];
        if (cs < cbest){ cbest = cs; tbest = ts; }
      }

      int tp = 0; bool mpv = false;
      if (cnt > 1){ tp = tbest; mpv = true; }
      else if (cnt == 1){
        tp = m0 ? (__ffsll(m0)-1) : (64 + __ffsll(m1)-1);
        mpv = true;
      }

      if (mpv){
        m = 1.0f;
        float4 T = tb4[tp];
        float x1=T.x, y1=T.y, x2=T.z, y2=T.w;
        float w = fmaxf(fminf(px2,x2)-fmaxf(px1,x1),0.0f);
        float h = fmaxf(fminf(py2,y2)-fmaxf(py1,y1),0.0f);
        float inter = w*h;
        float wp=px2-px1, hp=py2-py1, wt=x2-x1, ht=y2-y1;
        float iou = inter/(wp*hp + wt*ht - inter + 1e-8f);
        float cw = fmaxf(px2,x2)-fminf(px1,x1);
        float ch = fmaxf(py2,y2)-fminf(py1,y1);
        float c2 = cw*cw + ch*ch + 1e-8f;
        float dx = (px1+px2)-(x1+x2), dy = (py1+py2)-(y1+y2);
        float rho2 = (dx*dx + dy*dy)/4.0f;
        float da = atanf(wt/(ht+1e-8f)) - atanf(wp/(hp+1e-8f));
        float v  = 0.4052847345693511f * da * da;   // 4/pi^2
        float alpha = v/(1.0f - iou + v + 1e-8f);
        vbox = 1.0f - (iou - rho2/c2 - alpha*v);

        int cc = tcid[tp];
        float xcc = pred[(size_t)gid*PDIM + 5 + cc];
        vcls = (S0a[gid] - xcc) * (1.0f/80.0f);   // sum_c bce(x_c, onehot) = S0 - x_cc
      }
    }

    #pragma unroll
    for (int off=32; off>0; off>>=1){
      m    += __shfl_down(m, off);
      vbox += __shfl_down(vbox, off);
      vobj += __shfl_down(vobj, off);
      vcls += __shfl_down(vcls, off);
    }
    if (q == 0){
      int slot = (blockIdx.x & 63)*4;
      atomicAdd(&acc[slot+0], m);
      atomicAdd(&acc[slot+1], vbox);
      atomicAdd(&acc[slot+2], vobj);
      atomicAdd(&acc[slot+3], vcls);
    }
  }
}

// ---------------- Kernel 3: finalize (reduce 64 accumulator slots) -----------
__global__ void k3_final(const float* __restrict__ acc, float* __restrict__ out){
  int l = threadIdx.x;   // 64 threads
  float4 v = ((const float4*)acc)[l];
  #pragma unroll
  for (int off=32; off>0; off>>=1){
    v.x += __shfl_down(v.x, off);
    v.y += __shfl_down(v.y, off);
    v.z += __shfl_down(v.z, off);
    v.w += __shfl_down(v.w, off);
  }
  if (l == 0){
    float n    = fmaxf(v.x, 1.0f);
    float lbox = 0.05f * v.y / n;
    float lobj = v.z / (float)(NB*NA);
    float lcls = 0.5f  * v.w / n;
    out[0] = lbox + lobj + lcls;
    out[1] = lbox; out[2] = lobj; out[3] = lcls;
  }
}

extern "C" void kernel_launch(void* const* d_in, const int* in_sizes, int n_in,
                              void* d_out, int out_size, void* d_ws, size_t ws_size,
                              hipStream_t stream) {
  const float* pred    = (const float*)d_in[0];
  const float* target  = (const float*)d_in[1];
  const float* grid    = (const float*)d_in[2];
  const float* stridev = (const float*)d_in[3];
  float* out = (float*)d_out;

  char* ws = (char*)d_ws;
  const size_t BA = (size_t)NB*NA;   // 134400

  size_t off = 0;
  unsigned long long* mask = (unsigned long long*)(ws + off); off += BA*16;
  float* acc    = (float*)(ws + off); off += 64*4*4;
  float4* pbox4 = (float4*)(ws + off); off += BA*16;
  float4* meta4 = (float4*)(ws + off); off += BA*16;
  float* obja   = (float*)(ws + off); off += BA*4;
  float* sobja  = (float*)(ws + off); off += BA*4;
  float* S0a    = (float*)(ws + off); off += BA*4;
  float* rowmax = (float*)(ws + off); off += (size_t)NB*NT*4;
  float* D      = (float*)(ws + off);
  const size_t need_d = off + (size_t)NCLS*BA*4;
  int use_d = (ws_size >= need_d) ? 1 : 0;

  // mask+acc zeroed inside k0 (no memset dispatch)
  k0_precompute<<<NB*BPI, 256, 0, stream>>>(pred, target, grid, stridev,
                                            pbox4, meta4, obja, sobja, S0a, D, use_d,
                                            mask, acc);
  k1_pertarget <<<NB*NT,  256, 0, stream>>>(pbox4, meta4, D, use_d,
                                            sobja, pred, target, rowmax, mask);
  k2_peranchor <<<NB*BPI, 256, 0, stream>>>(pred, pbox4, meta4, obja, sobja, S0a,
                                            D, use_d, target, rowmax, mask, acc);
  k3_final     <<<1, 64, 0, stream>>>(acc, out);
}